// Round 12
// baseline (363.679 us; speedup 1.0000x reference)
//
#include <hip/hip_runtime.h>
#include <hip/hip_cooperative_groups.h>

namespace cg = cooperative_groups;

#define HH 192
#define WW 256
#define NPIX (HH*WW)   // 49152
#define NSEG (NPIX/64) // 768

__device__ __forceinline__ float lrelu(float v) { return v > 0.0f ? v : 0.01f * v; }

// ============================================================================
// k_fused1: EXACT R6 text (56.5-63.9us clock-dependent, 72 VGPR). CLOSED —
// ledger: R7 dbuf spill 670us; R9 mask-fusion -6us; R10 bounds-4 -5us; R12
// global_load_lds spill 313us; R13 BK=32 bank conflicts 61us. Do not touch.
// ============================================================================
__global__ __launch_bounds__(256, 3) void k_fused1(
    const float* __restrict__ X,
    const float* __restrict__ Wcl1, const float* __restrict__ bcl1,
    const float* __restrict__ Wr1,  const float* __restrict__ br1,
    const float* __restrict__ Wm1,  const float* __restrict__ bm1,
    const float* __restrict__ Wm2,  const float* __restrict__ bm2,
    const float* __restrict__ Wm3,  const float* __restrict__ bm3,
    float* __restrict__ x_t, float* __restrict__ r_t,
    float* __restrict__ out)
{
    __shared__ float As[16][132];
    __shared__ float Ws[16][132];
    __shared__ float m1buf[128][33];
    const int tid = threadIdx.x;
    const int q0  = blockIdx.x * 128;

    if (blockIdx.y == 2) {
        const int tc = tid & 31;
        const int tr = tid >> 5;
        float acc[4][4];
        #pragma unroll
        for (int i = 0; i < 4; ++i)
            #pragma unroll
            for (int j = 0; j < 4; ++j)
                acc[i][j] = bm1[tr * 4 + j];

        for (int k0 = 0; k0 < 128; k0 += 16) {
            #pragma unroll
            for (int p = 0; p < 2; ++p) {
                int lin = p * 1024 + tid * 4;
                int kk = lin >> 7, px = lin & 127;
                float4 v = *(const float4*)(X + (k0 + kk) * NPIX + q0 + px);
                *(float4*)(&As[kk][px]) = v;
            }
            if (tid < 128) {
                int row = tid >> 2, kc = (tid & 3) * 4;
                float4 v = *(const float4*)(Wm1 + row * 128 + k0 + kc);
                Ws[kc + 0][row] = v.x; Ws[kc + 1][row] = v.y;
                Ws[kc + 2][row] = v.z; Ws[kc + 3][row] = v.w;
            }
            __syncthreads();
            #pragma unroll
            for (int kk = 0; kk < 16; ++kk) {
                float4 a = *(const float4*)(&As[kk][tc * 4]);
                float4 w = *(const float4*)(&Ws[kk][tr * 4]);
                float av[4] = {a.x,a.y,a.z,a.w};
                float wv[4] = {w.x,w.y,w.z,w.w};
                #pragma unroll
                for (int i = 0; i < 4; ++i)
                    #pragma unroll
                    for (int j = 0; j < 4; ++j)
                        acc[i][j] = fmaf(av[i], wv[j], acc[i][j]);
            }
            __syncthreads();
        }
        #pragma unroll
        for (int i = 0; i < 4; ++i)
            #pragma unroll
            for (int j = 0; j < 4; ++j)
                m1buf[tc * 4 + i][tr * 4 + j] = lrelu(acc[i][j]);
        __syncthreads();
        if (tid < 128) {
            float m3 = bm3[0];
            #pragma unroll 2
            for (int j = 0; j < 16; ++j) {
                float s = bm2[j];
                #pragma unroll
                for (int k = 0; k < 32; ++k)
                    s = fmaf(Wm2[j * 32 + k], m1buf[tid][k], s);
                m3 = fmaf(Wm3[j], lrelu(s), m3);
            }
            out[NPIX + q0 + tid] = lrelu(m3);
        }
        return;
    }

    const float* __restrict__ W    = (blockIdx.y == 0) ? Wcl1 : Wr1;
    const float* __restrict__ bias = (blockIdx.y == 0) ? bcl1 : br1;
    float* __restrict__ outp       = (blockIdx.y == 0) ? x_t : r_t;

    const int tc = tid & 15;
    const int tr = tid >> 4;

    float acc[8][8];
    #pragma unroll
    for (int i = 0; i < 8; ++i)
        #pragma unroll
        for (int j = 0; j < 8; ++j)
            acc[i][j] = bias[(j >> 2) * 64 + tr * 4 + (j & 3)];

    for (int k0 = 0; k0 < 128; k0 += 16) {
        #pragma unroll
        for (int p = 0; p < 2; ++p) {
            int lin = p * 1024 + tid * 4;
            int kk = lin >> 7, px = lin & 127;
            float4 v = *(const float4*)(X + (k0 + kk) * NPIX + q0 + px);
            *(float4*)(&As[kk][px]) = v;
        }
        #pragma unroll
        for (int p = 0; p < 2; ++p) {
            int lin = p * 1024 + tid * 4;
            int row = lin >> 4, kc = lin & 15;
            float4 v = *(const float4*)(W + row * 128 + k0 + kc);
            Ws[kc + 0][row] = v.x; Ws[kc + 1][row] = v.y;
            Ws[kc + 2][row] = v.z; Ws[kc + 3][row] = v.w;
        }
        __syncthreads();
        #pragma unroll
        for (int kk = 0; kk < 16; ++kk) {
            float4 a0 = *(const float4*)(&As[kk][tc * 4]);
            float4 a1 = *(const float4*)(&As[kk][64 + tc * 4]);
            float4 w0 = *(const float4*)(&Ws[kk][tr * 4]);
            float4 w1 = *(const float4*)(&Ws[kk][64 + tr * 4]);
            float av[8] = {a0.x,a0.y,a0.z,a0.w,a1.x,a1.y,a1.z,a1.w};
            float wv[8] = {w0.x,w0.y,w0.z,w0.w,w1.x,w1.y,w1.z,w1.w};
            #pragma unroll
            for (int i = 0; i < 8; ++i)
                #pragma unroll
                for (int j = 0; j < 8; ++j)
                    acc[i][j] = fmaf(av[i], wv[j], acc[i][j]);
        }
        __syncthreads();
    }

    #pragma unroll
    for (int i = 0; i < 8; ++i) {
        int px = (i >> 2) * 64 + tc * 4 + (i & 3);
        int q  = q0 + px;
        int np = (q & 255) * 192 + (q >> 8);
        float* op = outp + (size_t)np * 128;
        #pragma unroll
        for (int jg = 0; jg < 2; ++jg) {
            float4 o;
            o.x = lrelu(acc[i][jg*4+0]); o.y = lrelu(acc[i][jg*4+1]);
            o.z = lrelu(acc[i][jg*4+2]); o.w = lrelu(acc[i][jg*4+3]);
            *(float4*)(op + jg * 64 + tr * 4) = o;
        }
    }
}

// ============================================================================
// k1b (R16, kept — part of the 240.5us best): 64-px tiles, grid 768 = 3/CU.
// ============================================================================
__global__ __launch_bounds__(256, 3) void k1b(
    const float* __restrict__ x_t,
    const float* __restrict__ Wcl21, const float* __restrict__ bcl21,
    const float* __restrict__ Wcl31, const float* __restrict__ bcl31,
    int* __restrict__ inds1_q)
{
    __shared__ float smem[8576];                        // 34304 B
    float (*As)[132]    = (float(*)[132])smem;          // [16][132] cols 0..63 used
    float (*Ws)[132]    = (float(*)[132])(smem + 2112); // [16][132]
    float (*W31)[132]   = (float(*)[132])smem;          // [32][132] aliases As+Ws
    float (*x2t)[68]    = (float(*)[68])(smem + 4224);  // [64][68]
    float (*cl1buf)[33] = (float(*)[33])(smem + 4224);  // [64][33] aliases x2t

    const int tid = threadIdx.x;
    const int n0  = blockIdx.x * 64;
    const int tcA = tid & 15, trA = tid >> 4;

    float acc[4][8];
    #pragma unroll
    for (int i = 0; i < 4; ++i)
        #pragma unroll
        for (int j = 0; j < 8; ++j)
            acc[i][j] = bcl21[(j >> 2) * 64 + trA * 4 + (j & 3)];

    for (int k0 = 0; k0 < 128; k0 += 16) {
        {
            int lin = tid * 4;
            int px = lin >> 4, kc = lin & 15;
            float4 v = *(const float4*)(x_t + (size_t)(n0 + px) * 128 + k0 + kc);
            As[kc + 0][px] = v.x; As[kc + 1][px] = v.y;
            As[kc + 2][px] = v.z; As[kc + 3][px] = v.w;
        }
        #pragma unroll
        for (int p = 0; p < 2; ++p) {
            int lin = p * 256 + tid;
            int r = lin >> 2, kc = (lin & 3) * 4;
            float4 v = *(const float4*)(Wcl21 + r * 128 + k0 + kc);
            Ws[kc + 0][r] = v.x; Ws[kc + 1][r] = v.y;
            Ws[kc + 2][r] = v.z; Ws[kc + 3][r] = v.w;
        }
        __syncthreads();
        #pragma unroll
        for (int kk = 0; kk < 16; ++kk) {
            float4 a  = *(const float4*)(&As[kk][tcA * 4]);
            float4 w0 = *(const float4*)(&Ws[kk][trA * 4]);
            float4 w1 = *(const float4*)(&Ws[kk][64 + trA * 4]);
            float av[4] = {a.x,a.y,a.z,a.w};
            float wv[8] = {w0.x,w0.y,w0.z,w0.w,w1.x,w1.y,w1.z,w1.w};
            #pragma unroll
            for (int i = 0; i < 4; ++i)
                #pragma unroll
                for (int j = 0; j < 8; ++j)
                    acc[i][j] = fmaf(av[i], wv[j], acc[i][j]);
        }
        __syncthreads();
    }

    const int tcB = tid & 15;
    const int trB = tid >> 4;
    float accB[4][2];
    #pragma unroll
    for (int i = 0; i < 4; ++i)
        #pragma unroll
        for (int j = 0; j < 2; ++j)
            accB[i][j] = bcl31[trB * 2 + j];

    #pragma unroll
    for (int p = 0; p < 4; ++p) {
        int lin = p * 1024 + tid * 4;
        int row = lin >> 7, kc = lin & 127;
        *(float4*)(&W31[row][kc]) = *(const float4*)(Wcl31 + row * 128 + kc);
    }
    #pragma unroll
    for (int j = 0; j < 4; ++j) {
        float4 o;
        o.x = lrelu(acc[0][j]); o.y = lrelu(acc[1][j]);
        o.z = lrelu(acc[2][j]); o.w = lrelu(acc[3][j]);
        *(float4*)(&x2t[trA * 4 + j][tcA * 4]) = o;
    }
    __syncthreads();
    for (int k = 0; k < 64; ++k) {
        float4 a = *(const float4*)(&x2t[k][tcB * 4]);
        float av[4] = {a.x,a.y,a.z,a.w};
        float w0 = W31[trB * 2 + 0][k];
        float w1 = W31[trB * 2 + 1][k];
        #pragma unroll
        for (int i = 0; i < 4; ++i) {
            accB[i][0] = fmaf(av[i], w0, accB[i][0]);
            accB[i][1] = fmaf(av[i], w1, accB[i][1]);
        }
    }
    __syncthreads();
    #pragma unroll
    for (int j = 0; j < 4; ++j) {
        float4 o;
        o.x = lrelu(acc[0][4+j]); o.y = lrelu(acc[1][4+j]);
        o.z = lrelu(acc[2][4+j]); o.w = lrelu(acc[3][4+j]);
        *(float4*)(&x2t[trA * 4 + j][tcA * 4]) = o;
    }
    __syncthreads();
    for (int k = 0; k < 64; ++k) {
        float4 a = *(const float4*)(&x2t[k][tcB * 4]);
        float av[4] = {a.x,a.y,a.z,a.w};
        float w0 = W31[trB * 2 + 0][64 + k];
        float w1 = W31[trB * 2 + 1][64 + k];
        #pragma unroll
        for (int i = 0; i < 4; ++i) {
            accB[i][0] = fmaf(av[i], w0, accB[i][0]);
            accB[i][1] = fmaf(av[i], w1, accB[i][1]);
        }
    }
    __syncthreads();

    #pragma unroll
    for (int i = 0; i < 4; ++i)
        #pragma unroll
        for (int j = 0; j < 2; ++j)
            cl1buf[tcB * 4 + i][trB * 2 + j] = accB[i][j];
    __syncthreads();
    if (tid < 64) {
        float bv = cl1buf[tid][0]; int bi = 0;
        #pragma unroll
        for (int c = 1; c < 32; ++c) {
            float v = cl1buf[tid][c];
            if (v > bv) { bv = v; bi = c; }
        }
        int n = n0 + tid;
        int w = n / 192, hh = n - w * 192;
        inds1_q[hh * 256 + w] = bi;
    }
}

// ============================================================================
// k_tail (R18): ONE cooperative kernel replacing 5 launches (hist, scanA,
// scatter2, k2h, k2r) — bodies are the verified texts verbatim, early
// returns converted to block-uniform guards, grid.sync() between phases.
// Removes 4 launch overheads (~5-10us each per rocprof guide).
// 224 blocks x 256 thr, ~22KB LDS -> trivially co-resident (224 < 256 CUs).
// Ledger: R15 (800-blk k2h) -8us: weight re-staging. R17 (2-thr/px) -8us.
// k2h/k2r BODIES are closed; only launch structure changes here.
// ============================================================================
__global__ __launch_bounds__(256) void k_tail(
    const int* __restrict__ inds1_q, int* __restrict__ bh,
    int* __restrict__ ebb, int* __restrict__ total, int* __restrict__ order,
    const float* __restrict__ x_t,
    const float* __restrict__ Wcl22, const float* __restrict__ bcl22,
    const float* __restrict__ Wcl32, const float* __restrict__ bcl32,
    int* __restrict__ ind_ord,
    const float* __restrict__ r_t,
    const float* __restrict__ Wr2,  const float* __restrict__ br2,
    const float* __restrict__ Wr3,  const float* __restrict__ br3,
    float* __restrict__ out)
{
    cg::grid_group grid = cg::this_grid();
    const int tid = threadIdx.x;
    const int bid = blockIdx.x;

    __shared__ int s[256];          // scan
    __shared__ int ttot[32];
    __shared__ int cpre[33];
    __shared__ int cbase[33];
    __shared__ float Wbuf[4096];    // k2h Was / k2r Wcs (16KB, reused)
    __shared__ float Wbs[1024];     // k2h only

    // ---------------- phase 1: hist (blocks 0..191) ----------------
    if (bid < 192) {
        int n = bid * 256 + tid;
        int key = inds1_q[n];
        int lane = tid & 63;
        int cnt = 0;
        for (int k = 0; k < 32; ++k) {
            unsigned long long m = __ballot(key == k);
            if (lane == k) cnt = __popcll(m);
        }
        if (lane < 32) bh[(n >> 6) * 32 + lane] = cnt;
    }
    grid.sync();

    // ---------------- phase 2: scanA (blocks 0..31) ----------------
    if (bid < 32) {
        const int k = bid, t = tid;
        int v0 = bh[(t * 3 + 0) * 32 + k];
        int v1 = bh[(t * 3 + 1) * 32 + k];
        int v2 = bh[(t * 3 + 2) * 32 + k];
        int sum = v0 + v1 + v2;
        s[t] = sum; __syncthreads();
        for (int d = 1; d < 256; d <<= 1) {
            int x = (t >= d) ? s[t - d] : 0;
            __syncthreads();
            s[t] += x;
            __syncthreads();
        }
        int ex = s[t] - sum;
        ebb[(t * 3 + 0) * 32 + k] = ex;
        ebb[(t * 3 + 1) * 32 + k] = ex + v0;
        ebb[(t * 3 + 2) * 32 + k] = ex + v0 + v1;
        if (t == 255) total[k] = s[255];
    }
    grid.sync();

    // ---------------- phase 3: scatter2 (blocks 0..191) ----------------
    if (bid < 192) {
        if (tid < 32) ttot[tid] = total[tid];
        __syncthreads();
        int n = bid * 256 + tid;
        int key = inds1_q[n];
        int lane = tid & 63;
        unsigned long long peers = 0;
        for (int k = 0; k < 32; ++k) {
            unsigned long long m = __ballot(key == k);
            if (key == k) peers = m;
        }
        int rank = __popcll(peers & ((1ull << lane) - 1ull));
        int cbs = 0;
        #pragma unroll
        for (int k = 0; k < 32; ++k) cbs += (k < key) ? ttot[k] : 0;
        order[cbs + ebb[(n >> 6) * 32 + key] + rank] = n;
    }
    grid.sync();

    // ---------------- common decode for phases 4/5 (256-px chunks) --------
    if (tid < 32) ttot[tid] = total[tid];
    __syncthreads();
    if (tid == 0) {
        int sc = 0, cb = 0;
        for (int k = 0; k < 32; ++k) {
            cpre[k] = sc; cbase[k] = cb;
            int c = ttot[k];
            sc += (c + 255) >> 8;
            cb += c;
        }
        cpre[32] = sc; cbase[32] = cb;
    }
    __syncthreads();
    const bool act = (bid < cpre[32]);
    int cls = 0, st = 0, npx = 1, base = 0;
    if (act) {
        while (cpre[cls + 1] <= bid) ++cls;
        st   = (bid - cpre[cls]) * 256;
        npx  = min(256, ttot[cls] - st);
        base = cbase[cls] + st;
    }
    const int sup = cls >> 2;

    // ---------------- phase 4: k2h (verbatim body) ----------------
    if (act) {
        {
            const float4* ws = (const float4*)(Wcl22 + cls * 4096);
            #pragma unroll
            for (int j = 0; j < 4; ++j) ((float4*)Wbuf)[j * 256 + tid] = ws[j * 256 + tid];
            ((float4*)Wbs)[tid] = ((const float4*)(Wcl32 + cls * 1024))[tid];
        }
        __syncthreads();

        const int m = order[base + min(tid, npx - 1)];
        const float4* xp = (const float4*)(x_t + (size_t)m * 128);

        float h[32];
        #pragma unroll
        for (int j = 0; j < 32; ++j) h[j] = bcl22[cls * 32 + j];
        #pragma unroll 2
        for (int c4 = 0; c4 < 32; ++c4) {
            float4 xv = xp[c4];
            float xa[4] = {xv.x, xv.y, xv.z, xv.w};
            #pragma unroll
            for (int cc = 0; cc < 4; ++cc) {
                const float* wr = &Wbuf[(c4 * 4 + cc) * 32];
                #pragma unroll
                for (int j = 0; j < 32; ++j) h[j] = fmaf(xa[cc], wr[j], h[j]);
            }
        }
        #pragma unroll
        for (int j = 0; j < 32; ++j) h[j] = lrelu(h[j]);

        float g[32];
        #pragma unroll
        for (int j = 0; j < 32; ++j) g[j] = bcl32[cls * 32 + j];
        #pragma unroll 2
        for (int c = 0; c < 32; ++c) {
            float hv = h[c];
            const float* wr = &Wbs[c * 32];
            #pragma unroll
            for (int j = 0; j < 32; ++j) g[j] = fmaf(hv, wr[j], g[j]);
        }
        float bv = g[0]; int bi = 0;
        #pragma unroll
        for (int j = 1; j < 32; ++j)
            if (g[j] > bv) { bv = g[j]; bi = j; }   // strict > = first-max (np.argmax)
        if (tid < npx) ind_ord[base + tid] = cls * 32 + bi;
    }
    grid.sync();

    // ---------------- phase 5: k2r (verbatim body; Wbuf reused) ----------
    if (act) {
        {
            const float4* ws = (const float4*)(Wr2 + sup * 4096);
            #pragma unroll
            for (int j = 0; j < 4; ++j) ((float4*)Wbuf)[j * 256 + tid] = ws[j * 256 + tid];
        }
        __syncthreads();

        const int li  = min(tid, npx - 1);
        const int m   = order[base + li];
        const int ind = ind_ord[base + li];
        const float4* rp = (const float4*)(r_t + (size_t)m * 128);

        float r2[32];
        #pragma unroll
        for (int j = 0; j < 32; ++j) r2[j] = br2[sup * 32 + j];
        #pragma unroll 2
        for (int c4 = 0; c4 < 32; ++c4) {
            float4 rv = rp[c4];
            float ra[4] = {rv.x, rv.y, rv.z, rv.w};
            #pragma unroll
            for (int cc = 0; cc < 4; ++cc) {
                const float* wr = &Wbuf[(c4 * 4 + cc) * 32];
                #pragma unroll
                for (int j = 0; j < 32; ++j) r2[j] = fmaf(ra[cc], wr[j], r2[j]);
            }
        }

        float reg = br3[ind];
        const float* __restrict__ w3 = Wr3 + ind * 32;
        #pragma unroll
        for (int j = 0; j < 32; ++j) reg = fmaf(lrelu(r2[j]), w3[j], reg);

        if (tid < npx) out[m] = ((float)ind + reg) * (1.0f / 1024.0f);
    }
}

extern "C" void kernel_launch(void* const* d_in, const int* in_sizes, int n_in,
                              void* d_out, int out_size, void* d_ws, size_t ws_size,
                              hipStream_t stream)
{
    const float* X     = (const float*)d_in[0];
    const float* Wm1   = (const float*)d_in[1];
    const float* bm1   = (const float*)d_in[2];
    const float* Wm2   = (const float*)d_in[3];
    const float* bm2   = (const float*)d_in[4];
    const float* Wm3   = (const float*)d_in[5];
    const float* bm3   = (const float*)d_in[6];
    const float* Wcl1  = (const float*)d_in[7];
    const float* bcl1  = (const float*)d_in[8];
    const float* Wcl21 = (const float*)d_in[9];
    const float* bcl21 = (const float*)d_in[10];
    const float* Wcl31 = (const float*)d_in[11];
    const float* bcl31 = (const float*)d_in[12];
    const float* Wcl22 = (const float*)d_in[13];
    const float* bcl22 = (const float*)d_in[14];
    const float* Wcl32 = (const float*)d_in[15];
    const float* bcl32 = (const float*)d_in[16];
    const float* Wr1   = (const float*)d_in[17];
    const float* br1   = (const float*)d_in[18];
    const float* Wr2   = (const float*)d_in[19];
    const float* br2   = (const float*)d_in[20];
    const float* Wr3   = (const float*)d_in[21];
    const float* br3   = (const float*)d_in[22];
    float* out = (float*)d_out;

    float* x_t   = (float*)d_ws;
    float* r_t   = x_t + (size_t)NPIX * 128;
    int* inds1_q = (int*)(r_t + (size_t)NPIX * 128);
    int* order   = inds1_q + NPIX;
    int* ind_ord = order + NPIX;
    int* bh      = ind_ord + NPIX;      // [768][32]
    int* ebb     = bh + NSEG * 32;      // [768][32]
    int* total   = ebb + NSEG * 32;     // [32]

    k_fused1<<<dim3(NPIX / 128, 3), 256, 0, stream>>>(X, Wcl1, bcl1, Wr1, br1,
                                                      Wm1, bm1, Wm2, bm2, Wm3, bm3,
                                                      x_t, r_t, out);
    k1b<<<NPIX / 64, 256, 0, stream>>>(x_t, Wcl21, bcl21, Wcl31, bcl31, inds1_q);

    void* args[] = {
        (void*)&inds1_q, (void*)&bh, (void*)&ebb, (void*)&total, (void*)&order,
        (void*)&x_t, (void*)&Wcl22, (void*)&bcl22, (void*)&Wcl32, (void*)&bcl32,
        (void*)&ind_ord, (void*)&r_t, (void*)&Wr2, (void*)&br2, (void*)&Wr3,
        (void*)&br3, (void*)&out
    };
    hipLaunchCooperativeKernel(reinterpret_cast<void*>(k_tail),
                               dim3(224), dim3(256), args, 0, stream);
}

// Round 13
// 233.844 us; speedup vs baseline: 1.5552x; 1.5552x over previous
//
#include <hip/hip_runtime.h>

#define HH 192
#define WW 256
#define NPIX (HH*WW)   // 49152
#define NSEG (NPIX/64) // 768

__device__ __forceinline__ float lrelu(float v) { return v > 0.0f ? v : 0.01f * v; }

// ============================================================================
// k_fused1: EXACT R6 text (56.5-63.9us clock-dependent, 72 VGPR). CLOSED —
// ledger: R7 dbuf spill 670us; R9 mask-fusion -6us; R10 bounds-4 -5us; R12
// global_load_lds spill 313us; R13 BK=32 bank conflicts 61us. Do not touch.
// ============================================================================
__global__ __launch_bounds__(256, 3) void k_fused1(
    const float* __restrict__ X,
    const float* __restrict__ Wcl1, const float* __restrict__ bcl1,
    const float* __restrict__ Wr1,  const float* __restrict__ br1,
    const float* __restrict__ Wm1,  const float* __restrict__ bm1,
    const float* __restrict__ Wm2,  const float* __restrict__ bm2,
    const float* __restrict__ Wm3,  const float* __restrict__ bm3,
    float* __restrict__ x_t, float* __restrict__ r_t,
    float* __restrict__ out)
{
    __shared__ float As[16][132];
    __shared__ float Ws[16][132];
    __shared__ float m1buf[128][33];
    const int tid = threadIdx.x;
    const int q0  = blockIdx.x * 128;

    if (blockIdx.y == 2) {
        const int tc = tid & 31;
        const int tr = tid >> 5;
        float acc[4][4];
        #pragma unroll
        for (int i = 0; i < 4; ++i)
            #pragma unroll
            for (int j = 0; j < 4; ++j)
                acc[i][j] = bm1[tr * 4 + j];

        for (int k0 = 0; k0 < 128; k0 += 16) {
            #pragma unroll
            for (int p = 0; p < 2; ++p) {
                int lin = p * 1024 + tid * 4;
                int kk = lin >> 7, px = lin & 127;
                float4 v = *(const float4*)(X + (k0 + kk) * NPIX + q0 + px);
                *(float4*)(&As[kk][px]) = v;
            }
            if (tid < 128) {
                int row = tid >> 2, kc = (tid & 3) * 4;
                float4 v = *(const float4*)(Wm1 + row * 128 + k0 + kc);
                Ws[kc + 0][row] = v.x; Ws[kc + 1][row] = v.y;
                Ws[kc + 2][row] = v.z; Ws[kc + 3][row] = v.w;
            }
            __syncthreads();
            #pragma unroll
            for (int kk = 0; kk < 16; ++kk) {
                float4 a = *(const float4*)(&As[kk][tc * 4]);
                float4 w = *(const float4*)(&Ws[kk][tr * 4]);
                float av[4] = {a.x,a.y,a.z,a.w};
                float wv[4] = {w.x,w.y,w.z,w.w};
                #pragma unroll
                for (int i = 0; i < 4; ++i)
                    #pragma unroll
                    for (int j = 0; j < 4; ++j)
                        acc[i][j] = fmaf(av[i], wv[j], acc[i][j]);
            }
            __syncthreads();
        }
        #pragma unroll
        for (int i = 0; i < 4; ++i)
            #pragma unroll
            for (int j = 0; j < 4; ++j)
                m1buf[tc * 4 + i][tr * 4 + j] = lrelu(acc[i][j]);
        __syncthreads();
        if (tid < 128) {
            float m3 = bm3[0];
            #pragma unroll 2
            for (int j = 0; j < 16; ++j) {
                float s = bm2[j];
                #pragma unroll
                for (int k = 0; k < 32; ++k)
                    s = fmaf(Wm2[j * 32 + k], m1buf[tid][k], s);
                m3 = fmaf(Wm3[j], lrelu(s), m3);
            }
            out[NPIX + q0 + tid] = lrelu(m3);
        }
        return;
    }

    const float* __restrict__ W    = (blockIdx.y == 0) ? Wcl1 : Wr1;
    const float* __restrict__ bias = (blockIdx.y == 0) ? bcl1 : br1;
    float* __restrict__ outp       = (blockIdx.y == 0) ? x_t : r_t;

    const int tc = tid & 15;
    const int tr = tid >> 4;

    float acc[8][8];
    #pragma unroll
    for (int i = 0; i < 8; ++i)
        #pragma unroll
        for (int j = 0; j < 8; ++j)
            acc[i][j] = bias[(j >> 2) * 64 + tr * 4 + (j & 3)];

    for (int k0 = 0; k0 < 128; k0 += 16) {
        #pragma unroll
        for (int p = 0; p < 2; ++p) {
            int lin = p * 1024 + tid * 4;
            int kk = lin >> 7, px = lin & 127;
            float4 v = *(const float4*)(X + (k0 + kk) * NPIX + q0 + px);
            *(float4*)(&As[kk][px]) = v;
        }
        #pragma unroll
        for (int p = 0; p < 2; ++p) {
            int lin = p * 1024 + tid * 4;
            int row = lin >> 4, kc = lin & 15;
            float4 v = *(const float4*)(W + row * 128 + k0 + kc);
            Ws[kc + 0][row] = v.x; Ws[kc + 1][row] = v.y;
            Ws[kc + 2][row] = v.z; Ws[kc + 3][row] = v.w;
        }
        __syncthreads();
        #pragma unroll
        for (int kk = 0; kk < 16; ++kk) {
            float4 a0 = *(const float4*)(&As[kk][tc * 4]);
            float4 a1 = *(const float4*)(&As[kk][64 + tc * 4]);
            float4 w0 = *(const float4*)(&Ws[kk][tr * 4]);
            float4 w1 = *(const float4*)(&Ws[kk][64 + tr * 4]);
            float av[8] = {a0.x,a0.y,a0.z,a0.w,a1.x,a1.y,a1.z,a1.w};
            float wv[8] = {w0.x,w0.y,w0.z,w0.w,w1.x,w1.y,w1.z,w1.w};
            #pragma unroll
            for (int i = 0; i < 8; ++i)
                #pragma unroll
                for (int j = 0; j < 8; ++j)
                    acc[i][j] = fmaf(av[i], wv[j], acc[i][j]);
        }
        __syncthreads();
    }

    #pragma unroll
    for (int i = 0; i < 8; ++i) {
        int px = (i >> 2) * 64 + tc * 4 + (i & 3);
        int q  = q0 + px;
        int np = (q & 255) * 192 + (q >> 8);
        float* op = outp + (size_t)np * 128;
        #pragma unroll
        for (int jg = 0; jg < 2; ++jg) {
            float4 o;
            o.x = lrelu(acc[i][jg*4+0]); o.y = lrelu(acc[i][jg*4+1]);
            o.z = lrelu(acc[i][jg*4+2]); o.w = lrelu(acc[i][jg*4+3]);
            *(float4*)(op + jg * 64 + tr * 4) = o;
        }
    }
}

// ============================================================================
// k1b (R16, part of the 240.5us best): 64-px tiles, grid 768 = 3 blocks/CU.
// ============================================================================
__global__ __launch_bounds__(256, 3) void k1b(
    const float* __restrict__ x_t,
    const float* __restrict__ Wcl21, const float* __restrict__ bcl21,
    const float* __restrict__ Wcl31, const float* __restrict__ bcl31,
    int* __restrict__ inds1_q)
{
    __shared__ float smem[8576];                        // 34304 B
    float (*As)[132]    = (float(*)[132])smem;          // [16][132] cols 0..63 used
    float (*Ws)[132]    = (float(*)[132])(smem + 2112); // [16][132]
    float (*W31)[132]   = (float(*)[132])smem;          // [32][132] aliases As+Ws
    float (*x2t)[68]    = (float(*)[68])(smem + 4224);  // [64][68]
    float (*cl1buf)[33] = (float(*)[33])(smem + 4224);  // [64][33] aliases x2t

    const int tid = threadIdx.x;
    const int n0  = blockIdx.x * 64;
    const int tcA = tid & 15, trA = tid >> 4;

    float acc[4][8];
    #pragma unroll
    for (int i = 0; i < 4; ++i)
        #pragma unroll
        for (int j = 0; j < 8; ++j)
            acc[i][j] = bcl21[(j >> 2) * 64 + trA * 4 + (j & 3)];

    for (int k0 = 0; k0 < 128; k0 += 16) {
        {
            int lin = tid * 4;
            int px = lin >> 4, kc = lin & 15;
            float4 v = *(const float4*)(x_t + (size_t)(n0 + px) * 128 + k0 + kc);
            As[kc + 0][px] = v.x; As[kc + 1][px] = v.y;
            As[kc + 2][px] = v.z; As[kc + 3][px] = v.w;
        }
        #pragma unroll
        for (int p = 0; p < 2; ++p) {
            int lin = p * 256 + tid;
            int r = lin >> 2, kc = (lin & 3) * 4;
            float4 v = *(const float4*)(Wcl21 + r * 128 + k0 + kc);
            Ws[kc + 0][r] = v.x; Ws[kc + 1][r] = v.y;
            Ws[kc + 2][r] = v.z; Ws[kc + 3][r] = v.w;
        }
        __syncthreads();
        #pragma unroll
        for (int kk = 0; kk < 16; ++kk) {
            float4 a  = *(const float4*)(&As[kk][tcA * 4]);
            float4 w0 = *(const float4*)(&Ws[kk][trA * 4]);
            float4 w1 = *(const float4*)(&Ws[kk][64 + trA * 4]);
            float av[4] = {a.x,a.y,a.z,a.w};
            float wv[8] = {w0.x,w0.y,w0.z,w0.w,w1.x,w1.y,w1.z,w1.w};
            #pragma unroll
            for (int i = 0; i < 4; ++i)
                #pragma unroll
                for (int j = 0; j < 8; ++j)
                    acc[i][j] = fmaf(av[i], wv[j], acc[i][j]);
        }
        __syncthreads();
    }

    const int tcB = tid & 15;
    const int trB = tid >> 4;
    float accB[4][2];
    #pragma unroll
    for (int i = 0; i < 4; ++i)
        #pragma unroll
        for (int j = 0; j < 2; ++j)
            accB[i][j] = bcl31[trB * 2 + j];

    #pragma unroll
    for (int p = 0; p < 4; ++p) {
        int lin = p * 1024 + tid * 4;
        int row = lin >> 7, kc = lin & 127;
        *(float4*)(&W31[row][kc]) = *(const float4*)(Wcl31 + row * 128 + kc);
    }
    #pragma unroll
    for (int j = 0; j < 4; ++j) {
        float4 o;
        o.x = lrelu(acc[0][j]); o.y = lrelu(acc[1][j]);
        o.z = lrelu(acc[2][j]); o.w = lrelu(acc[3][j]);
        *(float4*)(&x2t[trA * 4 + j][tcA * 4]) = o;
    }
    __syncthreads();
    for (int k = 0; k < 64; ++k) {
        float4 a = *(const float4*)(&x2t[k][tcB * 4]);
        float av[4] = {a.x,a.y,a.z,a.w};
        float w0 = W31[trB * 2 + 0][k];
        float w1 = W31[trB * 2 + 1][k];
        #pragma unroll
        for (int i = 0; i < 4; ++i) {
            accB[i][0] = fmaf(av[i], w0, accB[i][0]);
            accB[i][1] = fmaf(av[i], w1, accB[i][1]);
        }
    }
    __syncthreads();
    #pragma unroll
    for (int j = 0; j < 4; ++j) {
        float4 o;
        o.x = lrelu(acc[0][4+j]); o.y = lrelu(acc[1][4+j]);
        o.z = lrelu(acc[2][4+j]); o.w = lrelu(acc[3][4+j]);
        *(float4*)(&x2t[trA * 4 + j][tcA * 4]) = o;
    }
    __syncthreads();
    for (int k = 0; k < 64; ++k) {
        float4 a = *(const float4*)(&x2t[k][tcB * 4]);
        float av[4] = {a.x,a.y,a.z,a.w};
        float w0 = W31[trB * 2 + 0][64 + k];
        float w1 = W31[trB * 2 + 1][64 + k];
        #pragma unroll
        for (int i = 0; i < 4; ++i) {
            accB[i][0] = fmaf(av[i], w0, accB[i][0]);
            accB[i][1] = fmaf(av[i], w1, accB[i][1]);
        }
    }
    __syncthreads();

    #pragma unroll
    for (int i = 0; i < 4; ++i)
        #pragma unroll
        for (int j = 0; j < 2; ++j)
            cl1buf[tcB * 4 + i][trB * 2 + j] = accB[i][j];
    __syncthreads();
    if (tid < 64) {
        float bv = cl1buf[tid][0]; int bi = 0;
        #pragma unroll
        for (int c = 1; c < 32; ++c) {
            float v = cl1buf[tid][c];
            if (v > bv) { bv = v; bi = c; }
        }
        int n = n0 + tid;
        int w = n / 192, hh = n - w * 192;
        inds1_q[hh * 256 + w] = bi;
    }
}

// ============================================================================
// k_hist / k_scanA / k_scatter2 (R0 text — R18's coop merge was +123us,
// reverted; launch gaps are cheaper than grid.sync serialization)
// ============================================================================
__global__ void k_hist(const int* __restrict__ inds1_q, int* __restrict__ bh) {
    int tid = threadIdx.x;
    int n = blockIdx.x * 256 + tid;
    int key = inds1_q[n];
    int lane = tid & 63;
    int cnt = 0;
    for (int k = 0; k < 32; ++k) {
        unsigned long long m = __ballot(key == k);
        if (lane == k) cnt = __popcll(m);
    }
    if (lane < 32) bh[(n >> 6) * 32 + lane] = cnt;
}

__global__ void k_scanA(const int* __restrict__ bh, int* __restrict__ ebb,
                        int* __restrict__ total) {
    __shared__ int s[256];
    const int k = blockIdx.x, t = threadIdx.x;
    int v0 = bh[(t * 3 + 0) * 32 + k];
    int v1 = bh[(t * 3 + 1) * 32 + k];
    int v2 = bh[(t * 3 + 2) * 32 + k];
    int sum = v0 + v1 + v2;
    s[t] = sum; __syncthreads();
    for (int d = 1; d < 256; d <<= 1) {
        int x = (t >= d) ? s[t - d] : 0;
        __syncthreads();
        s[t] += x;
        __syncthreads();
    }
    int ex = s[t] - sum;
    ebb[(t * 3 + 0) * 32 + k] = ex;
    ebb[(t * 3 + 1) * 32 + k] = ex + v0;
    ebb[(t * 3 + 2) * 32 + k] = ex + v0 + v1;
    if (t == 255) total[k] = s[255];
}

__global__ void k_scatter2(const int* __restrict__ inds1_q,
                           const int* __restrict__ ebb,
                           const int* __restrict__ total,
                           int* __restrict__ order)
{
    __shared__ int ttot[32];
    const int tid = threadIdx.x;
    if (tid < 32) ttot[tid] = total[tid];
    __syncthreads();
    int n = blockIdx.x * 256 + tid;
    int key = inds1_q[n];
    int lane = tid & 63;
    unsigned long long peers = 0;
    for (int k = 0; k < 32; ++k) {
        unsigned long long m = __ballot(key == k);
        if (key == k) peers = m;
    }
    int rank = __popcll(peers & ((1ull << lane) - 1ull));
    int cbase = 0;
    #pragma unroll
    for (int k = 0; k < 32; ++k) cbase += (k < key) ? ttot[k] : 0;
    order[cbase + ebb[(n >> 6) * 32 + key] + rank] = n;
}

// ============================================================================
// k2h: stage-2 first half (R0 text — ledger: R15 800-blk -8us; R17 2-thr/px
// -8us; R18 coop +123us. CLOSED.)
// ============================================================================
__global__ __launch_bounds__(256, 4) void k2h(
    const float* __restrict__ x_t,
    const float* __restrict__ Wcl22, const float* __restrict__ bcl22,
    const float* __restrict__ Wcl32, const float* __restrict__ bcl32,
    const int* __restrict__ total, const int* __restrict__ order,
    int* __restrict__ ind_ord)
{
    __shared__ float Was[4096];
    __shared__ float Wbs[1024];
    __shared__ int cpre[33];
    __shared__ int cbase[33];
    __shared__ int ttot[32];

    const int tid = threadIdx.x;
    if (tid < 32) ttot[tid] = total[tid];
    __syncthreads();
    if (tid == 0) {
        int s = 0, cb = 0;
        for (int k = 0; k < 32; ++k) {
            cpre[k] = s; cbase[k] = cb;
            int c = ttot[k];
            s += (c + 255) >> 8;
            cb += c;
        }
        cpre[32] = s; cbase[32] = cb;
    }
    __syncthreads();
    const int ci = blockIdx.x;
    if (ci >= cpre[32]) return;
    int cls = 0;
    while (cpre[cls + 1] <= ci) ++cls;
    const int st   = (ci - cpre[cls]) * 256;
    const int npx  = min(256, ttot[cls] - st);
    const int base = cbase[cls] + st;

    {
        const float4* ws = (const float4*)(Wcl22 + cls * 4096);
        #pragma unroll
        for (int j = 0; j < 4; ++j) ((float4*)Was)[j * 256 + tid] = ws[j * 256 + tid];
        ((float4*)Wbs)[tid] = ((const float4*)(Wcl32 + cls * 1024))[tid];
    }
    __syncthreads();

    const int m = order[base + min(tid, npx - 1)];
    const float4* xp = (const float4*)(x_t + (size_t)m * 128);

    float h[32];
    #pragma unroll
    for (int j = 0; j < 32; ++j) h[j] = bcl22[cls * 32 + j];
    #pragma unroll 2
    for (int c4 = 0; c4 < 32; ++c4) {
        float4 xv = xp[c4];
        float xa[4] = {xv.x, xv.y, xv.z, xv.w};
        #pragma unroll
        for (int cc = 0; cc < 4; ++cc) {
            const float* wr = &Was[(c4 * 4 + cc) * 32];
            #pragma unroll
            for (int j = 0; j < 32; ++j) h[j] = fmaf(xa[cc], wr[j], h[j]);
        }
    }
    #pragma unroll
    for (int j = 0; j < 32; ++j) h[j] = lrelu(h[j]);

    float g[32];
    #pragma unroll
    for (int j = 0; j < 32; ++j) g[j] = bcl32[cls * 32 + j];
    #pragma unroll 2
    for (int c = 0; c < 32; ++c) {
        float hv = h[c];
        const float* wr = &Wbs[c * 32];
        #pragma unroll
        for (int j = 0; j < 32; ++j) g[j] = fmaf(hv, wr[j], g[j]);
    }
    float bv = g[0]; int bi = 0;
    #pragma unroll
    for (int j = 1; j < 32; ++j)
        if (g[j] > bv) { bv = g[j]; bi = j; }     // strict > = first-max (np.argmax)
    if (tid < npx) ind_ord[base + tid] = cls * 32 + bi;
}

// ============================================================================
// k2r: stage-2 second half (R0 text)
// ============================================================================
__global__ __launch_bounds__(256, 4) void k2r(
    const float* __restrict__ r_t,
    const float* __restrict__ Wr2,  const float* __restrict__ br2,
    const float* __restrict__ Wr3,  const float* __restrict__ br3,
    const int* __restrict__ total, const int* __restrict__ order,
    const int* __restrict__ ind_ord,
    float* __restrict__ out)
{
    __shared__ float Wcs[4096];
    __shared__ int cpre[33];
    __shared__ int cbase[33];
    __shared__ int ttot[32];

    const int tid = threadIdx.x;
    if (tid < 32) ttot[tid] = total[tid];
    __syncthreads();
    if (tid == 0) {
        int s = 0, cb = 0;
        for (int k = 0; k < 32; ++k) {
            cpre[k] = s; cbase[k] = cb;
            int c = ttot[k];
            s += (c + 255) >> 8;
            cb += c;
        }
        cpre[32] = s; cbase[32] = cb;
    }
    __syncthreads();
    const int ci = blockIdx.x;
    if (ci >= cpre[32]) return;
    int cls = 0;
    while (cpre[cls + 1] <= ci) ++cls;
    const int st   = (ci - cpre[cls]) * 256;
    const int npx  = min(256, ttot[cls] - st);
    const int base = cbase[cls] + st;
    const int sup  = cls >> 2;

    {
        const float4* ws = (const float4*)(Wr2 + sup * 4096);
        #pragma unroll
        for (int j = 0; j < 4; ++j) ((float4*)Wcs)[j * 256 + tid] = ws[j * 256 + tid];
    }
    __syncthreads();

    const int li  = min(tid, npx - 1);
    const int m   = order[base + li];
    const int ind = ind_ord[base + li];
    const float4* rp = (const float4*)(r_t + (size_t)m * 128);

    float r2[32];
    #pragma unroll
    for (int j = 0; j < 32; ++j) r2[j] = br2[sup * 32 + j];
    #pragma unroll 2
    for (int c4 = 0; c4 < 32; ++c4) {
        float4 rv = rp[c4];
        float ra[4] = {rv.x, rv.y, rv.z, rv.w};
        #pragma unroll
        for (int cc = 0; cc < 4; ++cc) {
            const float* wr = &Wcs[(c4 * 4 + cc) * 32];
            #pragma unroll
            for (int j = 0; j < 32; ++j) r2[j] = fmaf(ra[cc], wr[j], r2[j]);
        }
    }

    float reg = br3[ind];
    const float* __restrict__ w3 = Wr3 + ind * 32;
    #pragma unroll
    for (int j = 0; j < 32; ++j) reg = fmaf(lrelu(r2[j]), w3[j], reg);

    if (tid < npx) out[m] = ((float)ind + reg) * (1.0f / 1024.0f);
}

extern "C" void kernel_launch(void* const* d_in, const int* in_sizes, int n_in,
                              void* d_out, int out_size, void* d_ws, size_t ws_size,
                              hipStream_t stream)
{
    const float* X     = (const float*)d_in[0];
    const float* Wm1   = (const float*)d_in[1];
    const float* bm1   = (const float*)d_in[2];
    const float* Wm2   = (const float*)d_in[3];
    const float* bm2   = (const float*)d_in[4];
    const float* Wm3   = (const float*)d_in[5];
    const float* bm3   = (const float*)d_in[6];
    const float* Wcl1  = (const float*)d_in[7];
    const float* bcl1  = (const float*)d_in[8];
    const float* Wcl21 = (const float*)d_in[9];
    const float* bcl21 = (const float*)d_in[10];
    const float* Wcl31 = (const float*)d_in[11];
    const float* bcl31 = (const float*)d_in[12];
    const float* Wcl22 = (const float*)d_in[13];
    const float* bcl22 = (const float*)d_in[14];
    const float* Wcl32 = (const float*)d_in[15];
    const float* bcl32 = (const float*)d_in[16];
    const float* Wr1   = (const float*)d_in[17];
    const float* br1   = (const float*)d_in[18];
    const float* Wr2   = (const float*)d_in[19];
    const float* br2   = (const float*)d_in[20];
    const float* Wr3   = (const float*)d_in[21];
    const float* br3   = (const float*)d_in[22];
    float* out = (float*)d_out;

    float* x_t   = (float*)d_ws;
    float* r_t   = x_t + (size_t)NPIX * 128;
    int* inds1_q = (int*)(r_t + (size_t)NPIX * 128);
    int* order   = inds1_q + NPIX;
    int* ind_ord = order + NPIX;
    int* bh      = ind_ord + NPIX;      // [768][32]
    int* ebb     = bh + NSEG * 32;      // [768][32]
    int* total   = ebb + NSEG * 32;     // [32]

    k_fused1<<<dim3(NPIX / 128, 3), 256, 0, stream>>>(X, Wcl1, bcl1, Wr1, br1,
                                                      Wm1, bm1, Wm2, bm2, Wm3, bm3,
                                                      x_t, r_t, out);
    k1b<<<NPIX / 64, 256, 0, stream>>>(x_t, Wcl21, bcl21, Wcl31, bcl31, inds1_q);
    k_hist<<<NPIX / 256, 256, 0, stream>>>(inds1_q, bh);
    k_scanA<<<32, 256, 0, stream>>>(bh, ebb, total);
    k_scatter2<<<NPIX / 256, 256, 0, stream>>>(inds1_q, ebb, total, order);
    // 256-px chunks: worst case sum ceil = 192 + 31 = 223 -> grid 224 covers all
    k2h<<<224, 256, 0, stream>>>(x_t, Wcl22, bcl22, Wcl32, bcl32, total, order, ind_ord);
    k2r<<<224, 256, 0, stream>>>(r_t, Wr2, br2, Wr3, br3, total, order, ind_ord, out);
}

// Round 14
// 230.672 us; speedup vs baseline: 1.5766x; 1.0137x over previous
//
#include <hip/hip_runtime.h>

#define HH 192
#define WW 256
#define NPIX (HH*WW)   // 49152
#define NSEG (NPIX/64) // 768

__device__ __forceinline__ float lrelu(float v) { return v > 0.0f ? v : 0.01f * v; }

// bf16 hi/lo split helpers (RNE via round-half-up on guard bit)
__device__ __forceinline__ unsigned short bfhi(float x) {
    unsigned b = __float_as_uint(x);
    return (unsigned short)((b + 0x7FFFu + ((b >> 16) & 1u)) >> 16);
}
__device__ __forceinline__ float bff(unsigned short u) {
    return __uint_as_float(((unsigned)u) << 16);
}

typedef __attribute__((ext_vector_type(8))) short short8v;  // 8 bf16 = 4 VGPR
typedef __attribute__((ext_vector_type(4))) float f32x4;    // MFMA acc

// ============================================================================
// k_fused1 (R20): y=0 (x_t) and y=2 (mask) EXACT R6 text — CLOSED (ledger:
// R7 dbuf spill; R9 fusion; R10 bounds-4; R12 gload_lds spill; R13 BK=32).
// y=1 (r_t) REWRITTEN with bf16 hi/lo-split MFMA (W.X ~ WhiXhi+WhiXlo+WloXhi):
// precision-safe because r_t feeds NO argmax — its error enters out scaled
// by 1/1024 (~1e-8). x_t/cl1 paths stay fp32 (argmax-flip risk).
// LDS union 40960B (bf16 tiles stride-40 = 16B-aligned frags, 2-way banks);
// still 3 blocks/CU.
// ============================================================================
__global__ __launch_bounds__(256, 3) void k_fused1(
    const float* __restrict__ X,
    const float* __restrict__ Wcl1, const float* __restrict__ bcl1,
    const float* __restrict__ Wr1,  const float* __restrict__ br1,
    const float* __restrict__ Wm1,  const float* __restrict__ bm1,
    const float* __restrict__ Wm2,  const float* __restrict__ bm2,
    const float* __restrict__ Wm3,  const float* __restrict__ bm3,
    float* __restrict__ x_t, float* __restrict__ r_t,
    float* __restrict__ out)
{
    __shared__ float smem[10240];                      // 40960 B
    float (*As)[132]   = (float(*)[132])smem;          // y0/y2: [16][132]
    float (*Ws)[132]   = (float(*)[132])(smem + 2112);
    float (*m1buf)[33] = (float(*)[33])(smem + 4224);  // y2 epilogue

    const int tid = threadIdx.x;
    const int q0  = blockIdx.x * 128;

    if (blockIdx.y == 2) {
        // ---- mask branch: EXACT R6 text ----
        const int tc = tid & 31;
        const int tr = tid >> 5;
        float acc[4][4];
        #pragma unroll
        for (int i = 0; i < 4; ++i)
            #pragma unroll
            for (int j = 0; j < 4; ++j)
                acc[i][j] = bm1[tr * 4 + j];

        for (int k0 = 0; k0 < 128; k0 += 16) {
            #pragma unroll
            for (int p = 0; p < 2; ++p) {
                int lin = p * 1024 + tid * 4;
                int kk = lin >> 7, px = lin & 127;
                float4 v = *(const float4*)(X + (k0 + kk) * NPIX + q0 + px);
                *(float4*)(&As[kk][px]) = v;
            }
            if (tid < 128) {
                int row = tid >> 2, kc = (tid & 3) * 4;
                float4 v = *(const float4*)(Wm1 + row * 128 + k0 + kc);
                Ws[kc + 0][row] = v.x; Ws[kc + 1][row] = v.y;
                Ws[kc + 2][row] = v.z; Ws[kc + 3][row] = v.w;
            }
            __syncthreads();
            #pragma unroll
            for (int kk = 0; kk < 16; ++kk) {
                float4 a = *(const float4*)(&As[kk][tc * 4]);
                float4 w = *(const float4*)(&Ws[kk][tr * 4]);
                float av[4] = {a.x,a.y,a.z,a.w};
                float wv[4] = {w.x,w.y,w.z,w.w};
                #pragma unroll
                for (int i = 0; i < 4; ++i)
                    #pragma unroll
                    for (int j = 0; j < 4; ++j)
                        acc[i][j] = fmaf(av[i], wv[j], acc[i][j]);
            }
            __syncthreads();
        }
        #pragma unroll
        for (int i = 0; i < 4; ++i)
            #pragma unroll
            for (int j = 0; j < 4; ++j)
                m1buf[tc * 4 + i][tr * 4 + j] = lrelu(acc[i][j]);
        __syncthreads();
        if (tid < 128) {
            float m3 = bm3[0];
            #pragma unroll 2
            for (int j = 0; j < 16; ++j) {
                float s = bm2[j];
                #pragma unroll
                for (int k = 0; k < 32; ++k)
                    s = fmaf(Wm2[j * 32 + k], m1buf[tid][k], s);
                m3 = fmaf(Wm3[j], lrelu(s), m3);
            }
            out[NPIX + q0 + tid] = lrelu(m3);
        }
        return;
    }

    if (blockIdx.y == 1) {
        // ---- y=1: r_t via bf16 hi/lo-split MFMA ----
        unsigned short* Whi  = (unsigned short*)smem;            // [128][40]
        unsigned short* Wlo  = Whi  + 5120;                      // [128][40]
        unsigned short* Xthi = Wlo  + 5120;                      // [128px][40]
        unsigned short* Xtlo = Xthi + 5120;                      // [128px][40]

        const int l = tid & 63;           // lane
        const int w = tid >> 6;           // wave 0..3
        const int c = l & 15;
        const int g = l >> 4;
        const int o0 = w * 32;            // wave's 32 output channels

        // bias: acc elem r of tile ot -> o = o0 + ot*16 + g*4 + r
        float bv[2][4];
        #pragma unroll
        for (int ot = 0; ot < 2; ++ot)
            #pragma unroll
            for (int r = 0; r < 4; ++r)
                bv[ot][r] = br1[o0 + ot * 16 + g * 4 + r];

        f32x4 acc[2][8];
        #pragma unroll
        for (int ot = 0; ot < 2; ++ot)
            #pragma unroll
            for (int pt = 0; pt < 8; ++pt) {
                acc[ot][pt][0] = bv[ot][0]; acc[ot][pt][1] = bv[ot][1];
                acc[ot][pt][2] = bv[ot][2]; acc[ot][pt][3] = bv[ot][3];
            }

        for (int k0 = 0; k0 < 128; k0 += 32) {
            // stage X tile (32k x 128px) transposed -> Xt[px][k], hi/lo
            #pragma unroll
            for (int p = 0; p < 4; ++p) {
                int lin = p * 1024 + tid * 4;
                int kk = lin >> 7, px = lin & 127;
                float4 v = *(const float4*)(X + (size_t)(k0 + kk) * NPIX + q0 + px);
                float xv[4] = {v.x, v.y, v.z, v.w};
                #pragma unroll
                for (int i = 0; i < 4; ++i) {
                    unsigned short h = bfhi(xv[i]);
                    int idx = (px + i) * 40 + kk;
                    Xthi[idx] = h;
                    Xtlo[idx] = bfhi(xv[i] - bff(h));
                }
            }
            // stage W tile (128o x 32k) -> Whi/Wlo[o][k]
            #pragma unroll
            for (int p = 0; p < 4; ++p) {
                int lin = p * 1024 + tid * 4;
                int o = lin >> 5, kc = lin & 31;
                float4 v = *(const float4*)(Wr1 + o * 128 + k0 + kc);
                float wv[4] = {v.x, v.y, v.z, v.w};
                #pragma unroll
                for (int i = 0; i < 4; ++i) {
                    unsigned short h = bfhi(wv[i]);
                    int idx = o * 40 + kc + i;
                    Whi[idx] = h;
                    Wlo[idx] = bfhi(wv[i] - bff(h));
                }
            }
            __syncthreads();

            // A-frags for this wave's 2 o-tiles (hi/lo)
            short8v ahi[2], alo[2];
            #pragma unroll
            for (int ot = 0; ot < 2; ++ot) {
                int ao = (o0 + ot * 16 + c) * 40 + g * 8;
                ahi[ot] = *(const short8v*)(Whi + ao);
                alo[ot] = *(const short8v*)(Wlo + ao);
            }
            #pragma unroll
            for (int pt = 0; pt < 8; ++pt) {
                int bo = (pt * 16 + c) * 40 + g * 8;
                short8v bhi = *(const short8v*)(Xthi + bo);
                short8v blo = *(const short8v*)(Xtlo + bo);
                #pragma unroll
                for (int ot = 0; ot < 2; ++ot) {
                    acc[ot][pt] = __builtin_amdgcn_mfma_f32_16x16x32_bf16(
                        ahi[ot], bhi, acc[ot][pt], 0, 0, 0);
                    acc[ot][pt] = __builtin_amdgcn_mfma_f32_16x16x32_bf16(
                        ahi[ot], blo, acc[ot][pt], 0, 0, 0);
                    acc[ot][pt] = __builtin_amdgcn_mfma_f32_16x16x32_bf16(
                        alo[ot], bhi, acc[ot][pt], 0, 0, 0);
                }
            }
            __syncthreads();
        }

        // epilogue: D[row=(l>>4)*4+r][col=c] -> o = o0+ot*16+g*4+r, px = pt*16+c
        #pragma unroll
        for (int pt = 0; pt < 8; ++pt) {
            int px = pt * 16 + c;
            int q  = q0 + px;
            int np = (q & 255) * 192 + (q >> 8);
            float* op = r_t + (size_t)np * 128;
            #pragma unroll
            for (int ot = 0; ot < 2; ++ot) {
                float4 o4;
                o4.x = lrelu(acc[ot][pt][0]); o4.y = lrelu(acc[ot][pt][1]);
                o4.z = lrelu(acc[ot][pt][2]); o4.w = lrelu(acc[ot][pt][3]);
                *(float4*)(op + o0 + ot * 16 + g * 4) = o4;
            }
        }
        return;
    }

    // ---- y=0: x_t via fp32 VALU — EXACT R6 text (argmax-safe path) ----
    const float* __restrict__ W    = Wcl1;
    const float* __restrict__ bias = bcl1;
    float* __restrict__ outp       = x_t;

    const int tc = tid & 15;
    const int tr = tid >> 4;

    float acc[8][8];
    #pragma unroll
    for (int i = 0; i < 8; ++i)
        #pragma unroll
        for (int j = 0; j < 8; ++j)
            acc[i][j] = bias[(j >> 2) * 64 + tr * 4 + (j & 3)];

    for (int k0 = 0; k0 < 128; k0 += 16) {
        #pragma unroll
        for (int p = 0; p < 2; ++p) {
            int lin = p * 1024 + tid * 4;
            int kk = lin >> 7, px = lin & 127;
            float4 v = *(const float4*)(X + (k0 + kk) * NPIX + q0 + px);
            *(float4*)(&As[kk][px]) = v;
        }
        #pragma unroll
        for (int p = 0; p < 2; ++p) {
            int lin = p * 1024 + tid * 4;
            int row = lin >> 4, kc = lin & 15;
            float4 v = *(const float4*)(W + row * 128 + k0 + kc);
            Ws[kc + 0][row] = v.x; Ws[kc + 1][row] = v.y;
            Ws[kc + 2][row] = v.z; Ws[kc + 3][row] = v.w;
        }
        __syncthreads();
        #pragma unroll
        for (int kk = 0; kk < 16; ++kk) {
            float4 a0 = *(const float4*)(&As[kk][tc * 4]);
            float4 a1 = *(const float4*)(&As[kk][64 + tc * 4]);
            float4 w0 = *(const float4*)(&Ws[kk][tr * 4]);
            float4 w1 = *(const float4*)(&Ws[kk][64 + tr * 4]);
            float av[8] = {a0.x,a0.y,a0.z,a0.w,a1.x,a1.y,a1.z,a1.w};
            float wv[8] = {w0.x,w0.y,w0.z,w0.w,w1.x,w1.y,w1.z,w1.w};
            #pragma unroll
            for (int i = 0; i < 8; ++i)
                #pragma unroll
                for (int j = 0; j < 8; ++j)
                    acc[i][j] = fmaf(av[i], wv[j], acc[i][j]);
        }
        __syncthreads();
    }

    #pragma unroll
    for (int i = 0; i < 8; ++i) {
        int px = (i >> 2) * 64 + tc * 4 + (i & 3);
        int q  = q0 + px;
        int np = (q & 255) * 192 + (q >> 8);
        float* op = outp + (size_t)np * 128;
        #pragma unroll
        for (int jg = 0; jg < 2; ++jg) {
            float4 o;
            o.x = lrelu(acc[i][jg*4+0]); o.y = lrelu(acc[i][jg*4+1]);
            o.z = lrelu(acc[i][jg*4+2]); o.w = lrelu(acc[i][jg*4+3]);
            *(float4*)(op + jg * 64 + tr * 4) = o;
        }
    }
}

// ============================================================================
// k1b (R16, part of the 233.8us best): 64-px tiles, grid 768 = 3 blocks/CU.
// ============================================================================
__global__ __launch_bounds__(256, 3) void k1b(
    const float* __restrict__ x_t,
    const float* __restrict__ Wcl21, const float* __restrict__ bcl21,
    const float* __restrict__ Wcl31, const float* __restrict__ bcl31,
    int* __restrict__ inds1_q)
{
    __shared__ float smem[8576];                        // 34304 B
    float (*As)[132]    = (float(*)[132])smem;          // [16][132] cols 0..63 used
    float (*Ws)[132]    = (float(*)[132])(smem + 2112); // [16][132]
    float (*W31)[132]   = (float(*)[132])smem;          // [32][132] aliases As+Ws
    float (*x2t)[68]    = (float(*)[68])(smem + 4224);  // [64][68]
    float (*cl1buf)[33] = (float(*)[33])(smem + 4224);  // [64][33] aliases x2t

    const int tid = threadIdx.x;
    const int n0  = blockIdx.x * 64;
    const int tcA = tid & 15, trA = tid >> 4;

    float acc[4][8];
    #pragma unroll
    for (int i = 0; i < 4; ++i)
        #pragma unroll
        for (int j = 0; j < 8; ++j)
            acc[i][j] = bcl21[(j >> 2) * 64 + trA * 4 + (j & 3)];

    for (int k0 = 0; k0 < 128; k0 += 16) {
        {
            int lin = tid * 4;
            int px = lin >> 4, kc = lin & 15;
            float4 v = *(const float4*)(x_t + (size_t)(n0 + px) * 128 + k0 + kc);
            As[kc + 0][px] = v.x; As[kc + 1][px] = v.y;
            As[kc + 2][px] = v.z; As[kc + 3][px] = v.w;
        }
        #pragma unroll
        for (int p = 0; p < 2; ++p) {
            int lin = p * 256 + tid;
            int r = lin >> 2, kc = (lin & 3) * 4;
            float4 v = *(const float4*)(Wcl21 + r * 128 + k0 + kc);
            Ws[kc + 0][r] = v.x; Ws[kc + 1][r] = v.y;
            Ws[kc + 2][r] = v.z; Ws[kc + 3][r] = v.w;
        }
        __syncthreads();
        #pragma unroll
        for (int kk = 0; kk < 16; ++kk) {
            float4 a  = *(const float4*)(&As[kk][tcA * 4]);
            float4 w0 = *(const float4*)(&Ws[kk][trA * 4]);
            float4 w1 = *(const float4*)(&Ws[kk][64 + trA * 4]);
            float av[4] = {a.x,a.y,a.z,a.w};
            float wv[8] = {w0.x,w0.y,w0.z,w0.w,w1.x,w1.y,w1.z,w1.w};
            #pragma unroll
            for (int i = 0; i < 4; ++i)
                #pragma unroll
                for (int j = 0; j < 8; ++j)
                    acc[i][j] = fmaf(av[i], wv[j], acc[i][j]);
        }
        __syncthreads();
    }

    const int tcB = tid & 15;
    const int trB = tid >> 4;
    float accB[4][2];
    #pragma unroll
    for (int i = 0; i < 4; ++i)
        #pragma unroll
        for (int j = 0; j < 2; ++j)
            accB[i][j] = bcl31[trB * 2 + j];

    #pragma unroll
    for (int p = 0; p < 4; ++p) {
        int lin = p * 1024 + tid * 4;
        int row = lin >> 7, kc = lin & 127;
        *(float4*)(&W31[row][kc]) = *(const float4*)(Wcl31 + row * 128 + kc);
    }
    #pragma unroll
    for (int j = 0; j < 4; ++j) {
        float4 o;
        o.x = lrelu(acc[0][j]); o.y = lrelu(acc[1][j]);
        o.z = lrelu(acc[2][j]); o.w = lrelu(acc[3][j]);
        *(float4*)(&x2t[trA * 4 + j][tcA * 4]) = o;
    }
    __syncthreads();
    for (int k = 0; k < 64; ++k) {
        float4 a = *(const float4*)(&x2t[k][tcB * 4]);
        float av[4] = {a.x,a.y,a.z,a.w};
        float w0 = W31[trB * 2 + 0][k];
        float w1 = W31[trB * 2 + 1][k];
        #pragma unroll
        for (int i = 0; i < 4; ++i) {
            accB[i][0] = fmaf(av[i], w0, accB[i][0]);
            accB[i][1] = fmaf(av[i], w1, accB[i][1]);
        }
    }
    __syncthreads();
    #pragma unroll
    for (int j = 0; j < 4; ++j) {
        float4 o;
        o.x = lrelu(acc[0][4+j]); o.y = lrelu(acc[1][4+j]);
        o.z = lrelu(acc[2][4+j]); o.w = lrelu(acc[3][4+j]);
        *(float4*)(&x2t[trA * 4 + j][tcA * 4]) = o;
    }
    __syncthreads();
    for (int k = 0; k < 64; ++k) {
        float4 a = *(const float4*)(&x2t[k][tcB * 4]);
        float av[4] = {a.x,a.y,a.z,a.w};
        float w0 = W31[trB * 2 + 0][64 + k];
        float w1 = W31[trB * 2 + 1][64 + k];
        #pragma unroll
        for (int i = 0; i < 4; ++i) {
            accB[i][0] = fmaf(av[i], w0, accB[i][0]);
            accB[i][1] = fmaf(av[i], w1, accB[i][1]);
        }
    }
    __syncthreads();

    #pragma unroll
    for (int i = 0; i < 4; ++i)
        #pragma unroll
        for (int j = 0; j < 2; ++j)
            cl1buf[tcB * 4 + i][trB * 2 + j] = accB[i][j];
    __syncthreads();
    if (tid < 64) {
        float bv = cl1buf[tid][0]; int bi = 0;
        #pragma unroll
        for (int c = 1; c < 32; ++c) {
            float v = cl1buf[tid][c];
            if (v > bv) { bv = v; bi = c; }
        }
        int n = n0 + tid;
        int w = n / 192, hh = n - w * 192;
        inds1_q[hh * 256 + w] = bi;
    }
}

// ============================================================================
// k_hist / k_scanA / k_scatter2 (R0 text)
// ============================================================================
__global__ void k_hist(const int* __restrict__ inds1_q, int* __restrict__ bh) {
    int tid = threadIdx.x;
    int n = blockIdx.x * 256 + tid;
    int key = inds1_q[n];
    int lane = tid & 63;
    int cnt = 0;
    for (int k = 0; k < 32; ++k) {
        unsigned long long m = __ballot(key == k);
        if (lane == k) cnt = __popcll(m);
    }
    if (lane < 32) bh[(n >> 6) * 32 + lane] = cnt;
}

__global__ void k_scanA(const int* __restrict__ bh, int* __restrict__ ebb,
                        int* __restrict__ total) {
    __shared__ int s[256];
    const int k = blockIdx.x, t = threadIdx.x;
    int v0 = bh[(t * 3 + 0) * 32 + k];
    int v1 = bh[(t * 3 + 1) * 32 + k];
    int v2 = bh[(t * 3 + 2) * 32 + k];
    int sum = v0 + v1 + v2;
    s[t] = sum; __syncthreads();
    for (int d = 1; d < 256; d <<= 1) {
        int x = (t >= d) ? s[t - d] : 0;
        __syncthreads();
        s[t] += x;
        __syncthreads();
    }
    int ex = s[t] - sum;
    ebb[(t * 3 + 0) * 32 + k] = ex;
    ebb[(t * 3 + 1) * 32 + k] = ex + v0;
    ebb[(t * 3 + 2) * 32 + k] = ex + v0 + v1;
    if (t == 255) total[k] = s[255];
}

__global__ void k_scatter2(const int* __restrict__ inds1_q,
                           const int* __restrict__ ebb,
                           const int* __restrict__ total,
                           int* __restrict__ order)
{
    __shared__ int ttot[32];
    const int tid = threadIdx.x;
    if (tid < 32) ttot[tid] = total[tid];
    __syncthreads();
    int n = blockIdx.x * 256 + tid;
    int key = inds1_q[n];
    int lane = tid & 63;
    unsigned long long peers = 0;
    for (int k = 0; k < 32; ++k) {
        unsigned long long m = __ballot(key == k);
        if (key == k) peers = m;
    }
    int rank = __popcll(peers & ((1ull << lane) - 1ull));
    int cbase = 0;
    #pragma unroll
    for (int k = 0; k < 32; ++k) cbase += (k < key) ? ttot[k] : 0;
    order[cbase + ebb[(n >> 6) * 32 + key] + rank] = n;
}

// ============================================================================
// k2h: stage-2 first half (R0 text — CLOSED: R15/R17/R18 all regressed)
// ============================================================================
__global__ __launch_bounds__(256, 4) void k2h(
    const float* __restrict__ x_t,
    const float* __restrict__ Wcl22, const float* __restrict__ bcl22,
    const float* __restrict__ Wcl32, const float* __restrict__ bcl32,
    const int* __restrict__ total, const int* __restrict__ order,
    int* __restrict__ ind_ord)
{
    __shared__ float Was[4096];
    __shared__ float Wbs[1024];
    __shared__ int cpre[33];
    __shared__ int cbase[33];
    __shared__ int ttot[32];

    const int tid = threadIdx.x;
    if (tid < 32) ttot[tid] = total[tid];
    __syncthreads();
    if (tid == 0) {
        int s = 0, cb = 0;
        for (int k = 0; k < 32; ++k) {
            cpre[k] = s; cbase[k] = cb;
            int c = ttot[k];
            s += (c + 255) >> 8;
            cb += c;
        }
        cpre[32] = s; cbase[32] = cb;
    }
    __syncthreads();
    const int ci = blockIdx.x;
    if (ci >= cpre[32]) return;
    int cls = 0;
    while (cpre[cls + 1] <= ci) ++cls;
    const int st   = (ci - cpre[cls]) * 256;
    const int npx  = min(256, ttot[cls] - st);
    const int base = cbase[cls] + st;

    {
        const float4* ws = (const float4*)(Wcl22 + cls * 4096);
        #pragma unroll
        for (int j = 0; j < 4; ++j) ((float4*)Was)[j * 256 + tid] = ws[j * 256 + tid];
        ((float4*)Wbs)[tid] = ((const float4*)(Wcl32 + cls * 1024))[tid];
    }
    __syncthreads();

    const int m = order[base + min(tid, npx - 1)];
    const float4* xp = (const float4*)(x_t + (size_t)m * 128);

    float h[32];
    #pragma unroll
    for (int j = 0; j < 32; ++j) h[j] = bcl22[cls * 32 + j];
    #pragma unroll 2
    for (int c4 = 0; c4 < 32; ++c4) {
        float4 xv = xp[c4];
        float xa[4] = {xv.x, xv.y, xv.z, xv.w};
        #pragma unroll
        for (int cc = 0; cc < 4; ++cc) {
            const float* wr = &Was[(c4 * 4 + cc) * 32];
            #pragma unroll
            for (int j = 0; j < 32; ++j) h[j] = fmaf(xa[cc], wr[j], h[j]);
        }
    }
    #pragma unroll
    for (int j = 0; j < 32; ++j) h[j] = lrelu(h[j]);

    float g[32];
    #pragma unroll
    for (int j = 0; j < 32; ++j) g[j] = bcl32[cls * 32 + j];
    #pragma unroll 2
    for (int c = 0; c < 32; ++c) {
        float hv = h[c];
        const float* wr = &Wbs[c * 32];
        #pragma unroll
        for (int j = 0; j < 32; ++j) g[j] = fmaf(hv, wr[j], g[j]);
    }
    float bv = g[0]; int bi = 0;
    #pragma unroll
    for (int j = 1; j < 32; ++j)
        if (g[j] > bv) { bv = g[j]; bi = j; }     // strict > = first-max (np.argmax)
    if (tid < npx) ind_ord[base + tid] = cls * 32 + bi;
}

// ============================================================================
// k2r: stage-2 second half (R0 text)
// ============================================================================
__global__ __launch_bounds__(256, 4) void k2r(
    const float* __restrict__ r_t,
    const float* __restrict__ Wr2,  const float* __restrict__ br2,
    const float* __restrict__ Wr3,  const float* __restrict__ br3,
    const int* __restrict__ total, const int* __restrict__ order,
    const int* __restrict__ ind_ord,
    float* __restrict__ out)
{
    __shared__ float Wcs[4096];
    __shared__ int cpre[33];
    __shared__ int cbase[33];
    __shared__ int ttot[32];

    const int tid = threadIdx.x;
    if (tid < 32) ttot[tid] = total[tid];
    __syncthreads();
    if (tid == 0) {
        int s = 0, cb = 0;
        for (int k = 0; k < 32; ++k) {
            cpre[k] = s; cbase[k] = cb;
            int c = ttot[k];
            s += (c + 255) >> 8;
            cb += c;
        }
        cpre[32] = s; cbase[32] = cb;
    }
    __syncthreads();
    const int ci = blockIdx.x;
    if (ci >= cpre[32]) return;
    int cls = 0;
    while (cpre[cls + 1] <= ci) ++cls;
    const int st   = (ci - cpre[cls]) * 256;
    const int npx  = min(256, ttot[cls] - st);
    const int base = cbase[cls] + st;
    const int sup  = cls >> 2;

    {
        const float4* ws = (const float4*)(Wr2 + sup * 4096);
        #pragma unroll
        for (int j = 0; j < 4; ++j) ((float4*)Wcs)[j * 256 + tid] = ws[j * 256 + tid];
    }
    __syncthreads();

    const int li  = min(tid, npx - 1);
    const int m   = order[base + li];
    const int ind = ind_ord[base + li];
    const float4* rp = (const float4*)(r_t + (size_t)m * 128);

    float r2[32];
    #pragma unroll
    for (int j = 0; j < 32; ++j) r2[j] = br2[sup * 32 + j];
    #pragma unroll 2
    for (int c4 = 0; c4 < 32; ++c4) {
        float4 rv = rp[c4];
        float ra[4] = {rv.x, rv.y, rv.z, rv.w};
        #pragma unroll
        for (int cc = 0; cc < 4; ++cc) {
            const float* wr = &Wcs[(c4 * 4 + cc) * 32];
            #pragma unroll
            for (int j = 0; j < 32; ++j) r2[j] = fmaf(ra[cc], wr[j], r2[j]);
        }
    }

    float reg = br3[ind];
    const float* __restrict__ w3 = Wr3 + ind * 32;
    #pragma unroll
    for (int j = 0; j < 32; ++j) reg = fmaf(lrelu(r2[j]), w3[j], reg);

    if (tid < npx) out[m] = ((float)ind + reg) * (1.0f / 1024.0f);
}

extern "C" void kernel_launch(void* const* d_in, const int* in_sizes, int n_in,
                              void* d_out, int out_size, void* d_ws, size_t ws_size,
                              hipStream_t stream)
{
    const float* X     = (const float*)d_in[0];
    const float* Wm1   = (const float*)d_in[1];
    const float* bm1   = (const float*)d_in[2];
    const float* Wm2   = (const float*)d_in[3];
    const float* bm2   = (const float*)d_in[4];
    const float* Wm3   = (const float*)d_in[5];
    const float* bm3   = (const float*)d_in[6];
    const float* Wcl1  = (const float*)d_in[7];
    const float* bcl1  = (const float*)d_in[8];
    const float* Wcl21 = (const float*)d_in[9];
    const float* bcl21 = (const float*)d_in[10];
    const float* Wcl31 = (const float*)d_in[11];
    const float* bcl31 = (const float*)d_in[12];
    const float* Wcl22 = (const float*)d_in[13];
    const float* bcl22 = (const float*)d_in[14];
    const float* Wcl32 = (const float*)d_in[15];
    const float* bcl32 = (const float*)d_in[16];
    const float* Wr1   = (const float*)d_in[17];
    const float* br1   = (const float*)d_in[18];
    const float* Wr2   = (const float*)d_in[19];
    const float* br2   = (const float*)d_in[20];
    const float* Wr3   = (const float*)d_in[21];
    const float* br3   = (const float*)d_in[22];
    float* out = (float*)d_out;

    float* x_t   = (float*)d_ws;
    float* r_t   = x_t + (size_t)NPIX * 128;
    int* inds1_q = (int*)(r_t + (size_t)NPIX * 128);
    int* order   = inds1_q + NPIX;
    int* ind_ord = order + NPIX;
    int* bh      = ind_ord + NPIX;      // [768][32]
    int* ebb     = bh + NSEG * 32;      // [768][32]
    int* total   = ebb + NSEG * 32;     // [32]

    k_fused1<<<dim3(NPIX / 128, 3), 256, 0, stream>>>(X, Wcl1, bcl1, Wr1, br1,
                                                      Wm1, bm1, Wm2, bm2, Wm3, bm3,
                                                      x_t, r_t, out);
    k1b<<<NPIX / 64, 256, 0, stream>>>(x_t, Wcl21, bcl21, Wcl31, bcl31, inds1_q);
    k_hist<<<NPIX / 256, 256, 0, stream>>>(inds1_q, bh);
    k_scanA<<<32, 256, 0, stream>>>(bh, ebb, total);
    k_scatter2<<<NPIX / 256, 256, 0, stream>>>(inds1_q, ebb, total, order);
    // 256-px chunks: worst case sum ceil = 192 + 31 = 223 -> grid 224 covers all
    k2h<<<224, 256, 0, stream>>>(x_t, Wcl22, bcl22, Wcl32, bcl32, total, order, ind_ord);
    k2r<<<224, 256, 0, stream>>>(r_t, Wr2, br2, Wr3, br3, total, order, ind_ord, out);
}

// Round 15
// 223.465 us; speedup vs baseline: 1.6275x; 1.0323x over previous
//
#include <hip/hip_runtime.h>

#define HH 192
#define WW 256
#define NPIX (HH*WW)   // 49152
#define NSEG (NPIX/64) // 768

__device__ __forceinline__ float lrelu(float v) { return v > 0.0f ? v : 0.01f * v; }

// bf16 hi/lo split helpers (RNE via round-half-up on guard bit)
__device__ __forceinline__ unsigned short bfhi(float x) {
    unsigned b = __float_as_uint(x);
    return (unsigned short)((b + 0x7FFFu + ((b >> 16) & 1u)) >> 16);
}
__device__ __forceinline__ float bff(unsigned short u) {
    return __uint_as_float(((unsigned)u) << 16);
}

typedef __attribute__((ext_vector_type(8))) short short8v;  // 8 bf16 = 4 VGPR
typedef __attribute__((ext_vector_type(4))) short short4v;  // 8B packed write
typedef __attribute__((ext_vector_type(4))) float f32x4;    // MFMA acc

// ============================================================================
// k_fused1 (R21): y=0/y=2 EXACT R6 text (CLOSED). y=1 bf16 hi/lo MFMA (R20,
// verified: MfmaUtil 3.4%, absmax unchanged) with R21 staging fix:
//  - X-staging: thread owns 1px x 16k (16 coalesced dword loads) -> 2 packed
//    short8 writes (was 16 scalar shorts at 32-way conflict -> 6.92M
//    SQ_LDS_BANK_CONFLICT in R20).
//  - XOR k-group swizzle (g^(row&3)) on BOTH write and fragment-read sides
//    of X and W tiles (both-sides-or-neither).
// ============================================================================
__global__ __launch_bounds__(256, 3) void k_fused1(
    const float* __restrict__ X,
    const float* __restrict__ Wcl1, const float* __restrict__ bcl1,
    const float* __restrict__ Wr1,  const float* __restrict__ br1,
    const float* __restrict__ Wm1,  const float* __restrict__ bm1,
    const float* __restrict__ Wm2,  const float* __restrict__ bm2,
    const float* __restrict__ Wm3,  const float* __restrict__ bm3,
    float* __restrict__ x_t, float* __restrict__ r_t,
    float* __restrict__ out)
{
    __shared__ float smem[10240];                      // 40960 B
    float (*As)[132]   = (float(*)[132])smem;          // y0/y2: [16][132]
    float (*Ws)[132]   = (float(*)[132])(smem + 2112);
    float (*m1buf)[33] = (float(*)[33])(smem + 4224);  // y2 epilogue

    const int tid = threadIdx.x;
    const int q0  = blockIdx.x * 128;

    if (blockIdx.y == 2) {
        // ---- mask branch: EXACT R6 text ----
        const int tc = tid & 31;
        const int tr = tid >> 5;
        float acc[4][4];
        #pragma unroll
        for (int i = 0; i < 4; ++i)
            #pragma unroll
            for (int j = 0; j < 4; ++j)
                acc[i][j] = bm1[tr * 4 + j];

        for (int k0 = 0; k0 < 128; k0 += 16) {
            #pragma unroll
            for (int p = 0; p < 2; ++p) {
                int lin = p * 1024 + tid * 4;
                int kk = lin >> 7, px = lin & 127;
                float4 v = *(const float4*)(X + (k0 + kk) * NPIX + q0 + px);
                *(float4*)(&As[kk][px]) = v;
            }
            if (tid < 128) {
                int row = tid >> 2, kc = (tid & 3) * 4;
                float4 v = *(const float4*)(Wm1 + row * 128 + k0 + kc);
                Ws[kc + 0][row] = v.x; Ws[kc + 1][row] = v.y;
                Ws[kc + 2][row] = v.z; Ws[kc + 3][row] = v.w;
            }
            __syncthreads();
            #pragma unroll
            for (int kk = 0; kk < 16; ++kk) {
                float4 a = *(const float4*)(&As[kk][tc * 4]);
                float4 w = *(const float4*)(&Ws[kk][tr * 4]);
                float av[4] = {a.x,a.y,a.z,a.w};
                float wv[4] = {w.x,w.y,w.z,w.w};
                #pragma unroll
                for (int i = 0; i < 4; ++i)
                    #pragma unroll
                    for (int j = 0; j < 4; ++j)
                        acc[i][j] = fmaf(av[i], wv[j], acc[i][j]);
            }
            __syncthreads();
        }
        #pragma unroll
        for (int i = 0; i < 4; ++i)
            #pragma unroll
            for (int j = 0; j < 4; ++j)
                m1buf[tc * 4 + i][tr * 4 + j] = lrelu(acc[i][j]);
        __syncthreads();
        if (tid < 128) {
            float m3 = bm3[0];
            #pragma unroll 2
            for (int j = 0; j < 16; ++j) {
                float s = bm2[j];
                #pragma unroll
                for (int k = 0; k < 32; ++k)
                    s = fmaf(Wm2[j * 32 + k], m1buf[tid][k], s);
                m3 = fmaf(Wm3[j], lrelu(s), m3);
            }
            out[NPIX + q0 + tid] = lrelu(m3);
        }
        return;
    }

    if (blockIdx.y == 1) {
        // ---- y=1: r_t via bf16 hi/lo-split MFMA, swizzled staging ----
        unsigned short* Whi  = (unsigned short*)smem;            // [128][40]
        unsigned short* Wlo  = Whi  + 5120;                      // [128][40]
        unsigned short* Xthi = Wlo  + 5120;                      // [128px][40]
        unsigned short* Xtlo = Xthi + 5120;                      // [128px][40]

        const int l = tid & 63;           // lane
        const int w = tid >> 6;           // wave 0..3
        const int c = l & 15;
        const int g = l >> 4;
        const int o0 = w * 32;            // wave's 32 output channels

        float bv[2][4];
        #pragma unroll
        for (int ot = 0; ot < 2; ++ot)
            #pragma unroll
            for (int r = 0; r < 4; ++r)
                bv[ot][r] = br1[o0 + ot * 16 + g * 4 + r];

        f32x4 acc[2][8];
        #pragma unroll
        for (int ot = 0; ot < 2; ++ot)
            #pragma unroll
            for (int pt = 0; pt < 8; ++pt) {
                acc[ot][pt][0] = bv[ot][0]; acc[ot][pt][1] = bv[ot][1];
                acc[ot][pt][2] = bv[ot][2]; acc[ot][pt][3] = bv[ot][3];
            }

        // staging geometry (hoisted)
        const int sx_px = tid & 127;          // this thread's pixel row
        const int sx_kh = (tid >> 7) * 16;    // k-half 0 or 16
        const float* Xp = X + q0 + sx_px;

        for (int k0 = 0; k0 < 128; k0 += 32) {
            // ---- stage X tile: 1 px x 16 k per thread, packed+swizzled ----
            {
                float xv[16];
                #pragma unroll
                for (int i = 0; i < 16; ++i)
                    xv[i] = Xp[(size_t)(k0 + sx_kh + i) * NPIX];
                #pragma unroll
                for (int j = 0; j < 2; ++j) {
                    short8v hv, lv;
                    #pragma unroll
                    for (int i = 0; i < 8; ++i) {
                        unsigned short h = bfhi(xv[j * 8 + i]);
                        hv[i] = (short)h;
                        lv[i] = (short)bfhi(xv[j * 8 + i] - bff(h));
                    }
                    int gg = (sx_kh >> 3) + j;            // k-group 0..3
                    int gs = gg ^ (sx_px & 3);            // swizzled group
                    *(short8v*)(Xthi + sx_px * 40 + gs * 8) = hv;
                    *(short8v*)(Xtlo + sx_px * 40 + gs * 8) = lv;
                }
            }
            // ---- stage W tile: float4 along k, short4-packed+swizzled ----
            #pragma unroll
            for (int p = 0; p < 4; ++p) {
                int lin = p * 1024 + tid * 4;
                int o = lin >> 5, kc = lin & 31;
                float4 v = *(const float4*)(Wr1 + o * 128 + k0 + kc);
                float wv[4] = {v.x, v.y, v.z, v.w};
                short4v hv, lv;
                #pragma unroll
                for (int i = 0; i < 4; ++i) {
                    unsigned short h = bfhi(wv[i]);
                    hv[i] = (short)h;
                    lv[i] = (short)bfhi(wv[i] - bff(h));
                }
                int gg = kc >> 3;
                int gs = gg ^ (o & 3);
                int addr = o * 40 + gs * 8 + (kc & 7);
                *(short4v*)(Whi + addr) = hv;
                *(short4v*)(Wlo + addr) = lv;
            }
            __syncthreads();

            // A-frags (swizzled read: group g at row -> g^(row&3))
            short8v ahi[2], alo[2];
            #pragma unroll
            for (int ot = 0; ot < 2; ++ot) {
                int row = o0 + ot * 16 + c;
                int ao = row * 40 + (g ^ (row & 3)) * 8;
                ahi[ot] = *(const short8v*)(Whi + ao);
                alo[ot] = *(const short8v*)(Wlo + ao);
            }
            #pragma unroll
            for (int pt = 0; pt < 8; ++pt) {
                int row = pt * 16 + c;
                int bo = row * 40 + (g ^ (row & 3)) * 8;
                short8v bhi = *(const short8v*)(Xthi + bo);
                short8v blo = *(const short8v*)(Xtlo + bo);
                #pragma unroll
                for (int ot = 0; ot < 2; ++ot) {
                    acc[ot][pt] = __builtin_amdgcn_mfma_f32_16x16x32_bf16(
                        ahi[ot], bhi, acc[ot][pt], 0, 0, 0);
                    acc[ot][pt] = __builtin_amdgcn_mfma_f32_16x16x32_bf16(
                        ahi[ot], blo, acc[ot][pt], 0, 0, 0);
                    acc[ot][pt] = __builtin_amdgcn_mfma_f32_16x16x32_bf16(
                        alo[ot], bhi, acc[ot][pt], 0, 0, 0);
                }
            }
            __syncthreads();
        }

        // epilogue: D[row=(l>>4)*4+r][col=c] -> o = o0+ot*16+g*4+r, px = pt*16+c
        #pragma unroll
        for (int pt = 0; pt < 8; ++pt) {
            int px = pt * 16 + c;
            int q  = q0 + px;
            int np = (q & 255) * 192 + (q >> 8);
            float* op = r_t + (size_t)np * 128;
            #pragma unroll
            for (int ot = 0; ot < 2; ++ot) {
                float4 o4;
                o4.x = lrelu(acc[ot][pt][0]); o4.y = lrelu(acc[ot][pt][1]);
                o4.z = lrelu(acc[ot][pt][2]); o4.w = lrelu(acc[ot][pt][3]);
                *(float4*)(op + o0 + ot * 16 + g * 4) = o4;
            }
        }
        return;
    }

    // ---- y=0: x_t via fp32 VALU — EXACT R6 text (argmax-safe path) ----
    const float* __restrict__ W    = Wcl1;
    const float* __restrict__ bias = bcl1;
    float* __restrict__ outp       = x_t;

    const int tc = tid & 15;
    const int tr = tid >> 4;

    float acc[8][8];
    #pragma unroll
    for (int i = 0; i < 8; ++i)
        #pragma unroll
        for (int j = 0; j < 8; ++j)
            acc[i][j] = bias[(j >> 2) * 64 + tr * 4 + (j & 3)];

    for (int k0 = 0; k0 < 128; k0 += 16) {
        #pragma unroll
        for (int p = 0; p < 2; ++p) {
            int lin = p * 1024 + tid * 4;
            int kk = lin >> 7, px = lin & 127;
            float4 v = *(const float4*)(X + (k0 + kk) * NPIX + q0 + px);
            *(float4*)(&As[kk][px]) = v;
        }
        #pragma unroll
        for (int p = 0; p < 2; ++p) {
            int lin = p * 1024 + tid * 4;
            int row = lin >> 4, kc = lin & 15;
            float4 v = *(const float4*)(W + row * 128 + k0 + kc);
            Ws[kc + 0][row] = v.x; Ws[kc + 1][row] = v.y;
            Ws[kc + 2][row] = v.z; Ws[kc + 3][row] = v.w;
        }
        __syncthreads();
        #pragma unroll
        for (int kk = 0; kk < 16; ++kk) {
            float4 a0 = *(const float4*)(&As[kk][tc * 4]);
            float4 a1 = *(const float4*)(&As[kk][64 + tc * 4]);
            float4 w0 = *(const float4*)(&Ws[kk][tr * 4]);
            float4 w1 = *(const float4*)(&Ws[kk][64 + tr * 4]);
            float av[8] = {a0.x,a0.y,a0.z,a0.w,a1.x,a1.y,a1.z,a1.w};
            float wv[8] = {w0.x,w0.y,w0.z,w0.w,w1.x,w1.y,w1.z,w1.w};
            #pragma unroll
            for (int i = 0; i < 8; ++i)
                #pragma unroll
                for (int j = 0; j < 8; ++j)
                    acc[i][j] = fmaf(av[i], wv[j], acc[i][j]);
        }
        __syncthreads();
    }

    #pragma unroll
    for (int i = 0; i < 8; ++i) {
        int px = (i >> 2) * 64 + tc * 4 + (i & 3);
        int q  = q0 + px;
        int np = (q & 255) * 192 + (q >> 8);
        float* op = outp + (size_t)np * 128;
        #pragma unroll
        for (int jg = 0; jg < 2; ++jg) {
            float4 o;
            o.x = lrelu(acc[i][jg*4+0]); o.y = lrelu(acc[i][jg*4+1]);
            o.z = lrelu(acc[i][jg*4+2]); o.w = lrelu(acc[i][jg*4+3]);
            *(float4*)(op + jg * 64 + tr * 4) = o;
        }
    }
}

// ============================================================================
// k1b (R16, part of the best config): 64-px tiles, grid 768 = 3 blocks/CU.
// ============================================================================
__global__ __launch_bounds__(256, 3) void k1b(
    const float* __restrict__ x_t,
    const float* __restrict__ Wcl21, const float* __restrict__ bcl21,
    const float* __restrict__ Wcl31, const float* __restrict__ bcl31,
    int* __restrict__ inds1_q)
{
    __shared__ float smem[8576];                        // 34304 B
    float (*As)[132]    = (float(*)[132])smem;          // [16][132] cols 0..63 used
    float (*Ws)[132]    = (float(*)[132])(smem + 2112); // [16][132]
    float (*W31)[132]   = (float(*)[132])smem;          // [32][132] aliases As+Ws
    float (*x2t)[68]    = (float(*)[68])(smem + 4224);  // [64][68]
    float (*cl1buf)[33] = (float(*)[33])(smem + 4224);  // [64][33] aliases x2t

    const int tid = threadIdx.x;
    const int n0  = blockIdx.x * 64;
    const int tcA = tid & 15, trA = tid >> 4;

    float acc[4][8];
    #pragma unroll
    for (int i = 0; i < 4; ++i)
        #pragma unroll
        for (int j = 0; j < 8; ++j)
            acc[i][j] = bcl21[(j >> 2) * 64 + trA * 4 + (j & 3)];

    for (int k0 = 0; k0 < 128; k0 += 16) {
        {
            int lin = tid * 4;
            int px = lin >> 4, kc = lin & 15;
            float4 v = *(const float4*)(x_t + (size_t)(n0 + px) * 128 + k0 + kc);
            As[kc + 0][px] = v.x; As[kc + 1][px] = v.y;
            As[kc + 2][px] = v.z; As[kc + 3][px] = v.w;
        }
        #pragma unroll
        for (int p = 0; p < 2; ++p) {
            int lin = p * 256 + tid;
            int r = lin >> 2, kc = (lin & 3) * 4;
            float4 v = *(const float4*)(Wcl21 + r * 128 + k0 + kc);
            Ws[kc + 0][r] = v.x; Ws[kc + 1][r] = v.y;
            Ws[kc + 2][r] = v.z; Ws[kc + 3][r] = v.w;
        }
        __syncthreads();
        #pragma unroll
        for (int kk = 0; kk < 16; ++kk) {
            float4 a  = *(const float4*)(&As[kk][tcA * 4]);
            float4 w0 = *(const float4*)(&Ws[kk][trA * 4]);
            float4 w1 = *(const float4*)(&Ws[kk][64 + trA * 4]);
            float av[4] = {a.x,a.y,a.z,a.w};
            float wv[8] = {w0.x,w0.y,w0.z,w0.w,w1.x,w1.y,w1.z,w1.w};
            #pragma unroll
            for (int i = 0; i < 4; ++i)
                #pragma unroll
                for (int j = 0; j < 8; ++j)
                    acc[i][j] = fmaf(av[i], wv[j], acc[i][j]);
        }
        __syncthreads();
    }

    const int tcB = tid & 15;
    const int trB = tid >> 4;
    float accB[4][2];
    #pragma unroll
    for (int i = 0; i < 4; ++i)
        #pragma unroll
        for (int j = 0; j < 2; ++j)
            accB[i][j] = bcl31[trB * 2 + j];

    #pragma unroll
    for (int p = 0; p < 4; ++p) {
        int lin = p * 1024 + tid * 4;
        int row = lin >> 7, kc = lin & 127;
        *(float4*)(&W31[row][kc]) = *(const float4*)(Wcl31 + row * 128 + kc);
    }
    #pragma unroll
    for (int j = 0; j < 4; ++j) {
        float4 o;
        o.x = lrelu(acc[0][j]); o.y = lrelu(acc[1][j]);
        o.z = lrelu(acc[2][j]); o.w = lrelu(acc[3][j]);
        *(float4*)(&x2t[trA * 4 + j][tcA * 4]) = o;
    }
    __syncthreads();
    for (int k = 0; k < 64; ++k) {
        float4 a = *(const float4*)(&x2t[k][tcB * 4]);
        float av[4] = {a.x,a.y,a.z,a.w};
        float w0 = W31[trB * 2 + 0][k];
        float w1 = W31[trB * 2 + 1][k];
        #pragma unroll
        for (int i = 0; i < 4; ++i) {
            accB[i][0] = fmaf(av[i], w0, accB[i][0]);
            accB[i][1] = fmaf(av[i], w1, accB[i][1]);
        }
    }
    __syncthreads();
    #pragma unroll
    for (int j = 0; j < 4; ++j) {
        float4 o;
        o.x = lrelu(acc[0][4+j]); o.y = lrelu(acc[1][4+j]);
        o.z = lrelu(acc[2][4+j]); o.w = lrelu(acc[3][4+j]);
        *(float4*)(&x2t[trA * 4 + j][tcA * 4]) = o;
    }
    __syncthreads();
    for (int k = 0; k < 64; ++k) {
        float4 a = *(const float4*)(&x2t[k][tcB * 4]);
        float av[4] = {a.x,a.y,a.z,a.w};
        float w0 = W31[trB * 2 + 0][64 + k];
        float w1 = W31[trB * 2 + 1][64 + k];
        #pragma unroll
        for (int i = 0; i < 4; ++i) {
            accB[i][0] = fmaf(av[i], w0, accB[i][0]);
            accB[i][1] = fmaf(av[i], w1, accB[i][1]);
        }
    }
    __syncthreads();

    #pragma unroll
    for (int i = 0; i < 4; ++i)
        #pragma unroll
        for (int j = 0; j < 2; ++j)
            cl1buf[tcB * 4 + i][trB * 2 + j] = accB[i][j];
    __syncthreads();
    if (tid < 64) {
        float bv = cl1buf[tid][0]; int bi = 0;
        #pragma unroll
        for (int c = 1; c < 32; ++c) {
            float v = cl1buf[tid][c];
            if (v > bv) { bv = v; bi = c; }
        }
        int n = n0 + tid;
        int w = n / 192, hh = n - w * 192;
        inds1_q[hh * 256 + w] = bi;
    }
}

// ============================================================================
// k_hist / k_scanA / k_scatter2 (R0 text)
// ============================================================================
__global__ void k_hist(const int* __restrict__ inds1_q, int* __restrict__ bh) {
    int tid = threadIdx.x;
    int n = blockIdx.x * 256 + tid;
    int key = inds1_q[n];
    int lane = tid & 63;
    int cnt = 0;
    for (int k = 0; k < 32; ++k) {
        unsigned long long m = __ballot(key == k);
        if (lane == k) cnt = __popcll(m);
    }
    if (lane < 32) bh[(n >> 6) * 32 + lane] = cnt;
}

__global__ void k_scanA(const int* __restrict__ bh, int* __restrict__ ebb,
                        int* __restrict__ total) {
    __shared__ int s[256];
    const int k = blockIdx.x, t = threadIdx.x;
    int v0 = bh[(t * 3 + 0) * 32 + k];
    int v1 = bh[(t * 3 + 1) * 32 + k];
    int v2 = bh[(t * 3 + 2) * 32 + k];
    int sum = v0 + v1 + v2;
    s[t] = sum; __syncthreads();
    for (int d = 1; d < 256; d <<= 1) {
        int x = (t >= d) ? s[t - d] : 0;
        __syncthreads();
        s[t] += x;
        __syncthreads();
    }
    int ex = s[t] - sum;
    ebb[(t * 3 + 0) * 32 + k] = ex;
    ebb[(t * 3 + 1) * 32 + k] = ex + v0;
    ebb[(t * 3 + 2) * 32 + k] = ex + v0 + v1;
    if (t == 255) total[k] = s[255];
}

__global__ void k_scatter2(const int* __restrict__ inds1_q,
                           const int* __restrict__ ebb,
                           const int* __restrict__ total,
                           int* __restrict__ order)
{
    __shared__ int ttot[32];
    const int tid = threadIdx.x;
    if (tid < 32) ttot[tid] = total[tid];
    __syncthreads();
    int n = blockIdx.x * 256 + tid;
    int key = inds1_q[n];
    int lane = tid & 63;
    unsigned long long peers = 0;
    for (int k = 0; k < 32; ++k) {
        unsigned long long m = __ballot(key == k);
        if (key == k) peers = m;
    }
    int rank = __popcll(peers & ((1ull << lane) - 1ull));
    int cbase = 0;
    #pragma unroll
    for (int k = 0; k < 32; ++k) cbase += (k < key) ? ttot[k] : 0;
    order[cbase + ebb[(n >> 6) * 32 + key] + rank] = n;
}

// ============================================================================
// k2h: stage-2 first half (R0 text — CLOSED: R15/R17/R18 all regressed)
// ============================================================================
__global__ __launch_bounds__(256, 4) void k2h(
    const float* __restrict__ x_t,
    const float* __restrict__ Wcl22, const float* __restrict__ bcl22,
    const float* __restrict__ Wcl32, const float* __restrict__ bcl32,
    const int* __restrict__ total, const int* __restrict__ order,
    int* __restrict__ ind_ord)
{
    __shared__ float Was[4096];
    __shared__ float Wbs[1024];
    __shared__ int cpre[33];
    __shared__ int cbase[33];
    __shared__ int ttot[32];

    const int tid = threadIdx.x;
    if (tid < 32) ttot[tid] = total[tid];
    __syncthreads();
    if (tid == 0) {
        int s = 0, cb = 0;
        for (int k = 0; k < 32; ++k) {
            cpre[k] = s; cbase[k] = cb;
            int c = ttot[k];
            s += (c + 255) >> 8;
            cb += c;
        }
        cpre[32] = s; cbase[32] = cb;
    }
    __syncthreads();
    const int ci = blockIdx.x;
    if (ci >= cpre[32]) return;
    int cls = 0;
    while (cpre[cls + 1] <= ci) ++cls;
    const int st   = (ci - cpre[cls]) * 256;
    const int npx  = min(256, ttot[cls] - st);
    const int base = cbase[cls] + st;

    {
        const float4* ws = (const float4*)(Wcl22 + cls * 4096);
        #pragma unroll
        for (int j = 0; j < 4; ++j) ((float4*)Was)[j * 256 + tid] = ws[j * 256 + tid];
        ((float4*)Wbs)[tid] = ((const float4*)(Wcl32 + cls * 1024))[tid];
    }
    __syncthreads();

    const int m = order[base + min(tid, npx - 1)];
    const float4* xp = (const float4*)(x_t + (size_t)m * 128);

    float h[32];
    #pragma unroll
    for (int j = 0; j < 32; ++j) h[j] = bcl22[cls * 32 + j];
    #pragma unroll 2
    for (int c4 = 0; c4 < 32; ++c4) {
        float4 xv = xp[c4];
        float xa[4] = {xv.x, xv.y, xv.z, xv.w};
        #pragma unroll
        for (int cc = 0; cc < 4; ++cc) {
            const float* wr = &Was[(c4 * 4 + cc) * 32];
            #pragma unroll
            for (int j = 0; j < 32; ++j) h[j] = fmaf(xa[cc], wr[j], h[j]);
        }
    }
    #pragma unroll
    for (int j = 0; j < 32; ++j) h[j] = lrelu(h[j]);

    float g[32];
    #pragma unroll
    for (int j = 0; j < 32; ++j) g[j] = bcl32[cls * 32 + j];
    #pragma unroll 2
    for (int c = 0; c < 32; ++c) {
        float hv = h[c];
        const float* wr = &Wbs[c * 32];
        #pragma unroll
        for (int j = 0; j < 32; ++j) g[j] = fmaf(hv, wr[j], g[j]);
    }
    float bv = g[0]; int bi = 0;
    #pragma unroll
    for (int j = 1; j < 32; ++j)
        if (g[j] > bv) { bv = g[j]; bi = j; }     // strict > = first-max (np.argmax)
    if (tid < npx) ind_ord[base + tid] = cls * 32 + bi;
}

// ============================================================================
// k2r: stage-2 second half (R0 text)
// ============================================================================
__global__ __launch_bounds__(256, 4) void k2r(
    const float* __restrict__ r_t,
    const float* __restrict__ Wr2,  const float* __restrict__ br2,
    const float* __restrict__ Wr3,  const float* __restrict__ br3,
    const int* __restrict__ total, const int* __restrict__ order,
    const int* __restrict__ ind_ord,
    float* __restrict__ out)
{
    __shared__ float Wcs[4096];
    __shared__ int cpre[33];
    __shared__ int cbase[33];
    __shared__ int ttot[32];

    const int tid = threadIdx.x;
    if (tid < 32) ttot[tid] = total[tid];
    __syncthreads();
    if (tid == 0) {
        int s = 0, cb = 0;
        for (int k = 0; k < 32; ++k) {
            cpre[k] = s; cbase[k] = cb;
            int c = ttot[k];
            s += (c + 255) >> 8;
            cb += c;
        }
        cpre[32] = s; cbase[32] = cb;
    }
    __syncthreads();
    const int ci = blockIdx.x;
    if (ci >= cpre[32]) return;
    int cls = 0;
    while (cpre[cls + 1] <= ci) ++cls;
    const int st   = (ci - cpre[cls]) * 256;
    const int npx  = min(256, ttot[cls] - st);
    const int base = cbase[cls] + st;
    const int sup  = cls >> 2;

    {
        const float4* ws = (const float4*)(Wr2 + sup * 4096);
        #pragma unroll
        for (int j = 0; j < 4; ++j) ((float4*)Wcs)[j * 256 + tid] = ws[j * 256 + tid];
    }
    __syncthreads();

    const int li  = min(tid, npx - 1);
    const int m   = order[base + li];
    const int ind = ind_ord[base + li];
    const float4* rp = (const float4*)(r_t + (size_t)m * 128);

    float r2[32];
    #pragma unroll
    for (int j = 0; j < 32; ++j) r2[j] = br2[sup * 32 + j];
    #pragma unroll 2
    for (int c4 = 0; c4 < 32; ++c4) {
        float4 rv = rp[c4];
        float ra[4] = {rv.x, rv.y, rv.z, rv.w};
        #pragma unroll
        for (int cc = 0; cc < 4; ++cc) {
            const float* wr = &Wcs[(c4 * 4 + cc) * 32];
            #pragma unroll
            for (int j = 0; j < 32; ++j) r2[j] = fmaf(ra[cc], wr[j], r2[j]);
        }
    }

    float reg = br3[ind];
    const float* __restrict__ w3 = Wr3 + ind * 32;
    #pragma unroll
    for (int j = 0; j < 32; ++j) reg = fmaf(lrelu(r2[j]), w3[j], reg);

    if (tid < npx) out[m] = ((float)ind + reg) * (1.0f / 1024.0f);
}

extern "C" void kernel_launch(void* const* d_in, const int* in_sizes, int n_in,
                              void* d_out, int out_size, void* d_ws, size_t ws_size,
                              hipStream_t stream)
{
    const float* X     = (const float*)d_in[0];
    const float* Wm1   = (const float*)d_in[1];
    const float* bm1   = (const float*)d_in[2];
    const float* Wm2   = (const float*)d_in[3];
    const float* bm2   = (const float*)d_in[4];
    const float* Wm3   = (const float*)d_in[5];
    const float* bm3   = (const float*)d_in[6];
    const float* Wcl1  = (const float*)d_in[7];
    const float* bcl1  = (const float*)d_in[8];
    const float* Wcl21 = (const float*)d_in[9];
    const float* bcl21 = (const float*)d_in[10];
    const float* Wcl31 = (const float*)d_in[11];
    const float* bcl31 = (const float*)d_in[12];
    const float* Wcl22 = (const float*)d_in[13];
    const float* bcl22 = (const float*)d_in[14];
    const float* Wcl32 = (const float*)d_in[15];
    const float* bcl32 = (const float*)d_in[16];
    const float* Wr1   = (const float*)d_in[17];
    const float* br1   = (const float*)d_in[18];
    const float* Wr2   = (const float*)d_in[19];
    const float* br2   = (const float*)d_in[20];
    const float* Wr3   = (const float*)d_in[21];
    const float* br3   = (const float*)d_in[22];
    float* out = (float*)d_out;

    float* x_t   = (float*)d_ws;
    float* r_t   = x_t + (size_t)NPIX * 128;
    int* inds1_q = (int*)(r_t + (size_t)NPIX * 128);
    int* order   = inds1_q + NPIX;
    int* ind_ord = order + NPIX;
    int* bh      = ind_ord + NPIX;      // [768][32]
    int* ebb     = bh + NSEG * 32;      // [768][32]
    int* total   = ebb + NSEG * 32;     // [32]

    k_fused1<<<dim3(NPIX / 128, 3), 256, 0, stream>>>(X, Wcl1, bcl1, Wr1, br1,
                                                      Wm1, bm1, Wm2, bm2, Wm3, bm3,
                                                      x_t, r_t, out);
    k1b<<<NPIX / 64, 256, 0, stream>>>(x_t, Wcl21, bcl21, Wcl31, bcl31, inds1_q);
    k_hist<<<NPIX / 256, 256, 0, stream>>>(inds1_q, bh);
    k_scanA<<<32, 256, 0, stream>>>(bh, ebb, total);
    k_scatter2<<<NPIX / 256, 256, 0, stream>>>(inds1_q, ebb, total, order);
    // 256-px chunks: worst case sum ceil = 192 + 31 = 223 -> grid 224 covers all
    k2h<<<224, 256, 0, stream>>>(x_t, Wcl22, bcl22, Wcl32, bcl32, total, order, ind_ord);
    k2r<<<224, 256, 0, stream>>>(r_t, Wr2, br2, Wr3, br3, total, order, ind_ord, out);
}

// Round 16
// 222.999 us; speedup vs baseline: 1.6309x; 1.0021x over previous
//
#include <hip/hip_runtime.h>

#define HH 192
#define WW 256
#define NPIX (HH*WW)   // 49152
#define NSEG (NPIX/64) // 768

__device__ __forceinline__ float lrelu(float v) { return v > 0.0f ? v : 0.01f * v; }

// bf16 hi/lo split helpers (RNE via round-half-up on guard bit)
__device__ __forceinline__ unsigned short bfhi(float x) {
    unsigned b = __float_as_uint(x);
    return (unsigned short)((b + 0x7FFFu + ((b >> 16) & 1u)) >> 16);
}
__device__ __forceinline__ float bff(unsigned short u) {
    return __uint_as_float(((unsigned)u) << 16);
}

typedef __attribute__((ext_vector_type(8))) short short8v;  // 8 bf16 = 4 VGPR
typedef __attribute__((ext_vector_type(4))) short short4v;  // 8B packed write
typedef __attribute__((ext_vector_type(4))) float f32x4;    // MFMA acc

// ============================================================================
// k_fused1 (R22): y=0/y=2 EXACT R6 text (CLOSED). y=1 bf16 hi/lo MFMA
// (R20/R21 verified: MfmaUtil 4%, absmax unchanged, conflicts 6.92M->1.66M).
// R22: X-tile swizzle bit-source px&3 -> (px>>3)&3 (write AND read).
// Rationale: bank base 20*px mod 32 has period 8 in px; lanes sharing
// px mod 8 also shared px&3 -> same slot -> residual 8-way on packed
// stores. (px>>3)&3 spreads each mod-8 class across all 4 slots (2-way =
// free). W-tile swizzle (o&3) already conflict-light — unchanged.
// ============================================================================
__global__ __launch_bounds__(256, 3) void k_fused1(
    const float* __restrict__ X,
    const float* __restrict__ Wcl1, const float* __restrict__ bcl1,
    const float* __restrict__ Wr1,  const float* __restrict__ br1,
    const float* __restrict__ Wm1,  const float* __restrict__ bm1,
    const float* __restrict__ Wm2,  const float* __restrict__ bm2,
    const float* __restrict__ Wm3,  const float* __restrict__ bm3,
    float* __restrict__ x_t, float* __restrict__ r_t,
    float* __restrict__ out)
{
    __shared__ float smem[10240];                      // 40960 B
    float (*As)[132]   = (float(*)[132])smem;          // y0/y2: [16][132]
    float (*Ws)[132]   = (float(*)[132])(smem + 2112);
    float (*m1buf)[33] = (float(*)[33])(smem + 4224);  // y2 epilogue

    const int tid = threadIdx.x;
    const int q0  = blockIdx.x * 128;

    if (blockIdx.y == 2) {
        // ---- mask branch: EXACT R6 text ----
        const int tc = tid & 31;
        const int tr = tid >> 5;
        float acc[4][4];
        #pragma unroll
        for (int i = 0; i < 4; ++i)
            #pragma unroll
            for (int j = 0; j < 4; ++j)
                acc[i][j] = bm1[tr * 4 + j];

        for (int k0 = 0; k0 < 128; k0 += 16) {
            #pragma unroll
            for (int p = 0; p < 2; ++p) {
                int lin = p * 1024 + tid * 4;
                int kk = lin >> 7, px = lin & 127;
                float4 v = *(const float4*)(X + (k0 + kk) * NPIX + q0 + px);
                *(float4*)(&As[kk][px]) = v;
            }
            if (tid < 128) {
                int row = tid >> 2, kc = (tid & 3) * 4;
                float4 v = *(const float4*)(Wm1 + row * 128 + k0 + kc);
                Ws[kc + 0][row] = v.x; Ws[kc + 1][row] = v.y;
                Ws[kc + 2][row] = v.z; Ws[kc + 3][row] = v.w;
            }
            __syncthreads();
            #pragma unroll
            for (int kk = 0; kk < 16; ++kk) {
                float4 a = *(const float4*)(&As[kk][tc * 4]);
                float4 w = *(const float4*)(&Ws[kk][tr * 4]);
                float av[4] = {a.x,a.y,a.z,a.w};
                float wv[4] = {w.x,w.y,w.z,w.w};
                #pragma unroll
                for (int i = 0; i < 4; ++i)
                    #pragma unroll
                    for (int j = 0; j < 4; ++j)
                        acc[i][j] = fmaf(av[i], wv[j], acc[i][j]);
            }
            __syncthreads();
        }
        #pragma unroll
        for (int i = 0; i < 4; ++i)
            #pragma unroll
            for (int j = 0; j < 4; ++j)
                m1buf[tc * 4 + i][tr * 4 + j] = lrelu(acc[i][j]);
        __syncthreads();
        if (tid < 128) {
            float m3 = bm3[0];
            #pragma unroll 2
            for (int j = 0; j < 16; ++j) {
                float s = bm2[j];
                #pragma unroll
                for (int k = 0; k < 32; ++k)
                    s = fmaf(Wm2[j * 32 + k], m1buf[tid][k], s);
                m3 = fmaf(Wm3[j], lrelu(s), m3);
            }
            out[NPIX + q0 + tid] = lrelu(m3);
        }
        return;
    }

    if (blockIdx.y == 1) {
        // ---- y=1: r_t via bf16 hi/lo-split MFMA, swizzled staging ----
        unsigned short* Whi  = (unsigned short*)smem;            // [128][40]
        unsigned short* Wlo  = Whi  + 5120;                      // [128][40]
        unsigned short* Xthi = Wlo  + 5120;                      // [128px][40]
        unsigned short* Xtlo = Xthi + 5120;                      // [128px][40]

        const int l = tid & 63;           // lane
        const int w = tid >> 6;           // wave 0..3
        const int c = l & 15;
        const int g = l >> 4;
        const int o0 = w * 32;            // wave's 32 output channels

        float bv[2][4];
        #pragma unroll
        for (int ot = 0; ot < 2; ++ot)
            #pragma unroll
            for (int r = 0; r < 4; ++r)
                bv[ot][r] = br1[o0 + ot * 16 + g * 4 + r];

        f32x4 acc[2][8];
        #pragma unroll
        for (int ot = 0; ot < 2; ++ot)
            #pragma unroll
            for (int pt = 0; pt < 8; ++pt) {
                acc[ot][pt][0] = bv[ot][0]; acc[ot][pt][1] = bv[ot][1];
                acc[ot][pt][2] = bv[ot][2]; acc[ot][pt][3] = bv[ot][3];
            }

        // staging geometry (hoisted)
        const int sx_px = tid & 127;          // this thread's pixel row
        const int sx_kh = (tid >> 7) * 16;    // k-half 0 or 16
        const float* Xp = X + q0 + sx_px;

        for (int k0 = 0; k0 < 128; k0 += 32) {
            // ---- stage X tile: 1 px x 16 k per thread, packed+swizzled ----
            {
                float xv[16];
                #pragma unroll
                for (int i = 0; i < 16; ++i)
                    xv[i] = Xp[(size_t)(k0 + sx_kh + i) * NPIX];
                #pragma unroll
                for (int j = 0; j < 2; ++j) {
                    short8v hv, lv;
                    #pragma unroll
                    for (int i = 0; i < 8; ++i) {
                        unsigned short h = bfhi(xv[j * 8 + i]);
                        hv[i] = (short)h;
                        lv[i] = (short)bfhi(xv[j * 8 + i] - bff(h));
                    }
                    int gg = (sx_kh >> 3) + j;            // k-group 0..3
                    int gs = gg ^ ((sx_px >> 3) & 3);     // R22 swizzle
                    *(short8v*)(Xthi + sx_px * 40 + gs * 8) = hv;
                    *(short8v*)(Xtlo + sx_px * 40 + gs * 8) = lv;
                }
            }
            // ---- stage W tile: float4 along k, short4-packed+swizzled ----
            #pragma unroll
            for (int p = 0; p < 4; ++p) {
                int lin = p * 1024 + tid * 4;
                int o = lin >> 5, kc = lin & 31;
                float4 v = *(const float4*)(Wr1 + o * 128 + k0 + kc);
                float wv[4] = {v.x, v.y, v.z, v.w};
                short4v hv, lv;
                #pragma unroll
                for (int i = 0; i < 4; ++i) {
                    unsigned short h = bfhi(wv[i]);
                    hv[i] = (short)h;
                    lv[i] = (short)bfhi(wv[i] - bff(h));
                }
                int gg = kc >> 3;
                int gs = gg ^ (o & 3);
                int addr = o * 40 + gs * 8 + (kc & 7);
                *(short4v*)(Whi + addr) = hv;
                *(short4v*)(Wlo + addr) = lv;
            }
            __syncthreads();

            // A-frags (W swizzle unchanged: g ^ (row&3))
            short8v ahi[2], alo[2];
            #pragma unroll
            for (int ot = 0; ot < 2; ++ot) {
                int row = o0 + ot * 16 + c;
                int ao = row * 40 + (g ^ (row & 3)) * 8;
                ahi[ot] = *(const short8v*)(Whi + ao);
                alo[ot] = *(const short8v*)(Wlo + ao);
            }
            #pragma unroll
            for (int pt = 0; pt < 8; ++pt) {
                int row = pt * 16 + c;
                int bo = row * 40 + (g ^ ((row >> 3) & 3)) * 8;   // R22 swizzle
                short8v bhi = *(const short8v*)(Xthi + bo);
                short8v blo = *(const short8v*)(Xtlo + bo);
                #pragma unroll
                for (int ot = 0; ot < 2; ++ot) {
                    acc[ot][pt] = __builtin_amdgcn_mfma_f32_16x16x32_bf16(
                        ahi[ot], bhi, acc[ot][pt], 0, 0, 0);
                    acc[ot][pt] = __builtin_amdgcn_mfma_f32_16x16x32_bf16(
                        ahi[ot], blo, acc[ot][pt], 0, 0, 0);
                    acc[ot][pt] = __builtin_amdgcn_mfma_f32_16x16x32_bf16(
                        alo[ot], bhi, acc[ot][pt], 0, 0, 0);
                }
            }
            __syncthreads();
        }

        // epilogue: D[row=(l>>4)*4+r][col=c] -> o = o0+ot*16+g*4+r, px = pt*16+c
        #pragma unroll
        for (int pt = 0; pt < 8; ++pt) {
            int px = pt * 16 + c;
            int q  = q0 + px;
            int np = (q & 255) * 192 + (q >> 8);
            float* op = r_t + (size_t)np * 128;
            #pragma unroll
            for (int ot = 0; ot < 2; ++ot) {
                float4 o4;
                o4.x = lrelu(acc[ot][pt][0]); o4.y = lrelu(acc[ot][pt][1]);
                o4.z = lrelu(acc[ot][pt][2]); o4.w = lrelu(acc[ot][pt][3]);
                *(float4*)(op + o0 + ot * 16 + g * 4) = o4;
            }
        }
        return;
    }

    // ---- y=0: x_t via fp32 VALU — EXACT R6 text (argmax-safe path) ----
    const float* __restrict__ W    = Wcl1;
    const float* __restrict__ bias = bcl1;
    float* __restrict__ outp       = x_t;

    const int tc = tid & 15;
    const int tr = tid >> 4;

    float acc[8][8];
    #pragma unroll
    for (int i = 0; i < 8; ++i)
        #pragma unroll
        for (int j = 0; j < 8; ++j)
            acc[i][j] = bias[(j >> 2) * 64 + tr * 4 + (j & 3)];

    for (int k0 = 0; k0 < 128; k0 += 16) {
        #pragma unroll
        for (int p = 0; p < 2; ++p) {
            int lin = p * 1024 + tid * 4;
            int kk = lin >> 7, px = lin & 127;
            float4 v = *(const float4*)(X + (k0 + kk) * NPIX + q0 + px);
            *(float4*)(&As[kk][px]) = v;
        }
        #pragma unroll
        for (int p = 0; p < 2; ++p) {
            int lin = p * 1024 + tid * 4;
            int row = lin >> 4, kc = lin & 15;
            float4 v = *(const float4*)(W + row * 128 + k0 + kc);
            Ws[kc + 0][row] = v.x; Ws[kc + 1][row] = v.y;
            Ws[kc + 2][row] = v.z; Ws[kc + 3][row] = v.w;
        }
        __syncthreads();
        #pragma unroll
        for (int kk = 0; kk < 16; ++kk) {
            float4 a0 = *(const float4*)(&As[kk][tc * 4]);
            float4 a1 = *(const float4*)(&As[kk][64 + tc * 4]);
            float4 w0 = *(const float4*)(&Ws[kk][tr * 4]);
            float4 w1 = *(const float4*)(&Ws[kk][64 + tr * 4]);
            float av[8] = {a0.x,a0.y,a0.z,a0.w,a1.x,a1.y,a1.z,a1.w};
            float wv[8] = {w0.x,w0.y,w0.z,w0.w,w1.x,w1.y,w1.z,w1.w};
            #pragma unroll
            for (int i = 0; i < 8; ++i)
                #pragma unroll
                for (int j = 0; j < 8; ++j)
                    acc[i][j] = fmaf(av[i], wv[j], acc[i][j]);
        }
        __syncthreads();
    }

    #pragma unroll
    for (int i = 0; i < 8; ++i) {
        int px = (i >> 2) * 64 + tc * 4 + (i & 3);
        int q  = q0 + px;
        int np = (q & 255) * 192 + (q >> 8);
        float* op = outp + (size_t)np * 128;
        #pragma unroll
        for (int jg = 0; jg < 2; ++jg) {
            float4 o;
            o.x = lrelu(acc[i][jg*4+0]); o.y = lrelu(acc[i][jg*4+1]);
            o.z = lrelu(acc[i][jg*4+2]); o.w = lrelu(acc[i][jg*4+3]);
            *(float4*)(op + jg * 64 + tr * 4) = o;
        }
    }
}

// ============================================================================
// k1b (R16, part of the best config): 64-px tiles, grid 768 = 3 blocks/CU.
// ============================================================================
__global__ __launch_bounds__(256, 3) void k1b(
    const float* __restrict__ x_t,
    const float* __restrict__ Wcl21, const float* __restrict__ bcl21,
    const float* __restrict__ Wcl31, const float* __restrict__ bcl31,
    int* __restrict__ inds1_q)
{
    __shared__ float smem[8576];                        // 34304 B
    float (*As)[132]    = (float(*)[132])smem;          // [16][132] cols 0..63 used
    float (*Ws)[132]    = (float(*)[132])(smem + 2112); // [16][132]
    float (*W31)[132]   = (float(*)[132])smem;          // [32][132] aliases As+Ws
    float (*x2t)[68]    = (float(*)[68])(smem + 4224);  // [64][68]
    float (*cl1buf)[33] = (float(*)[33])(smem + 4224);  // [64][33] aliases x2t

    const int tid = threadIdx.x;
    const int n0  = blockIdx.x * 64;
    const int tcA = tid & 15, trA = tid >> 4;

    float acc[4][8];
    #pragma unroll
    for (int i = 0; i < 4; ++i)
        #pragma unroll
        for (int j = 0; j < 8; ++j)
            acc[i][j] = bcl21[(j >> 2) * 64 + trA * 4 + (j & 3)];

    for (int k0 = 0; k0 < 128; k0 += 16) {
        {
            int lin = tid * 4;
            int px = lin >> 4, kc = lin & 15;
            float4 v = *(const float4*)(x_t + (size_t)(n0 + px) * 128 + k0 + kc);
            As[kc + 0][px] = v.x; As[kc + 1][px] = v.y;
            As[kc + 2][px] = v.z; As[kc + 3][px] = v.w;
        }
        #pragma unroll
        for (int p = 0; p < 2; ++p) {
            int lin = p * 256 + tid;
            int r = lin >> 2, kc = (lin & 3) * 4;
            float4 v = *(const float4*)(Wcl21 + r * 128 + k0 + kc);
            Ws[kc + 0][r] = v.x; Ws[kc + 1][r] = v.y;
            Ws[kc + 2][r] = v.z; Ws[kc + 3][r] = v.w;
        }
        __syncthreads();
        #pragma unroll
        for (int kk = 0; kk < 16; ++kk) {
            float4 a  = *(const float4*)(&As[kk][tcA * 4]);
            float4 w0 = *(const float4*)(&Ws[kk][trA * 4]);
            float4 w1 = *(const float4*)(&Ws[kk][64 + trA * 4]);
            float av[4] = {a.x,a.y,a.z,a.w};
            float wv[8] = {w0.x,w0.y,w0.z,w0.w,w1.x,w1.y,w1.z,w1.w};
            #pragma unroll
            for (int i = 0; i < 4; ++i)
                #pragma unroll
                for (int j = 0; j < 8; ++j)
                    acc[i][j] = fmaf(av[i], wv[j], acc[i][j]);
        }
        __syncthreads();
    }

    const int tcB = tid & 15;
    const int trB = tid >> 4;
    float accB[4][2];
    #pragma unroll
    for (int i = 0; i < 4; ++i)
        #pragma unroll
        for (int j = 0; j < 2; ++j)
            accB[i][j] = bcl31[trB * 2 + j];

    #pragma unroll
    for (int p = 0; p < 4; ++p) {
        int lin = p * 1024 + tid * 4;
        int row = lin >> 7, kc = lin & 127;
        *(float4*)(&W31[row][kc]) = *(const float4*)(Wcl31 + row * 128 + kc);
    }
    #pragma unroll
    for (int j = 0; j < 4; ++j) {
        float4 o;
        o.x = lrelu(acc[0][j]); o.y = lrelu(acc[1][j]);
        o.z = lrelu(acc[2][j]); o.w = lrelu(acc[3][j]);
        *(float4*)(&x2t[trA * 4 + j][tcA * 4]) = o;
    }
    __syncthreads();
    for (int k = 0; k < 64; ++k) {
        float4 a = *(const float4*)(&x2t[k][tcB * 4]);
        float av[4] = {a.x,a.y,a.z,a.w};
        float w0 = W31[trB * 2 + 0][k];
        float w1 = W31[trB * 2 + 1][k];
        #pragma unroll
        for (int i = 0; i < 4; ++i) {
            accB[i][0] = fmaf(av[i], w0, accB[i][0]);
            accB[i][1] = fmaf(av[i], w1, accB[i][1]);
        }
    }
    __syncthreads();
    #pragma unroll
    for (int j = 0; j < 4; ++j) {
        float4 o;
        o.x = lrelu(acc[0][4+j]); o.y = lrelu(acc[1][4+j]);
        o.z = lrelu(acc[2][4+j]); o.w = lrelu(acc[3][4+j]);
        *(float4*)(&x2t[trA * 4 + j][tcA * 4]) = o;
    }
    __syncthreads();
    for (int k = 0; k < 64; ++k) {
        float4 a = *(const float4*)(&x2t[k][tcB * 4]);
        float av[4] = {a.x,a.y,a.z,a.w};
        float w0 = W31[trB * 2 + 0][64 + k];
        float w1 = W31[trB * 2 + 1][64 + k];
        #pragma unroll
        for (int i = 0; i < 4; ++i) {
            accB[i][0] = fmaf(av[i], w0, accB[i][0]);
            accB[i][1] = fmaf(av[i], w1, accB[i][1]);
        }
    }
    __syncthreads();

    #pragma unroll
    for (int i = 0; i < 4; ++i)
        #pragma unroll
        for (int j = 0; j < 2; ++j)
            cl1buf[tcB * 4 + i][trB * 2 + j] = accB[i][j];
    __syncthreads();
    if (tid < 64) {
        float bv = cl1buf[tid][0]; int bi = 0;
        #pragma unroll
        for (int c = 1; c < 32; ++c) {
            float v = cl1buf[tid][c];
            if (v > bv) { bv = v; bi = c; }
        }
        int n = n0 + tid;
        int w = n / 192, hh = n - w * 192;
        inds1_q[hh * 256 + w] = bi;
    }
}

// ============================================================================
// k_hist / k_scanA / k_scatter2 (R0 text)
// ============================================================================
__global__ void k_hist(const int* __restrict__ inds1_q, int* __restrict__ bh) {
    int tid = threadIdx.x;
    int n = blockIdx.x * 256 + tid;
    int key = inds1_q[n];
    int lane = tid & 63;
    int cnt = 0;
    for (int k = 0; k < 32; ++k) {
        unsigned long long m = __ballot(key == k);
        if (lane == k) cnt = __popcll(m);
    }
    if (lane < 32) bh[(n >> 6) * 32 + lane] = cnt;
}

__global__ void k_scanA(const int* __restrict__ bh, int* __restrict__ ebb,
                        int* __restrict__ total) {
    __shared__ int s[256];
    const int k = blockIdx.x, t = threadIdx.x;
    int v0 = bh[(t * 3 + 0) * 32 + k];
    int v1 = bh[(t * 3 + 1) * 32 + k];
    int v2 = bh[(t * 3 + 2) * 32 + k];
    int sum = v0 + v1 + v2;
    s[t] = sum; __syncthreads();
    for (int d = 1; d < 256; d <<= 1) {
        int x = (t >= d) ? s[t - d] : 0;
        __syncthreads();
        s[t] += x;
        __syncthreads();
    }
    int ex = s[t] - sum;
    ebb[(t * 3 + 0) * 32 + k] = ex;
    ebb[(t * 3 + 1) * 32 + k] = ex + v0;
    ebb[(t * 3 + 2) * 32 + k] = ex + v0 + v1;
    if (t == 255) total[k] = s[255];
}

__global__ void k_scatter2(const int* __restrict__ inds1_q,
                           const int* __restrict__ ebb,
                           const int* __restrict__ total,
                           int* __restrict__ order)
{
    __shared__ int ttot[32];
    const int tid = threadIdx.x;
    if (tid < 32) ttot[tid] = total[tid];
    __syncthreads();
    int n = blockIdx.x * 256 + tid;
    int key = inds1_q[n];
    int lane = tid & 63;
    unsigned long long peers = 0;
    for (int k = 0; k < 32; ++k) {
        unsigned long long m = __ballot(key == k);
        if (key == k) peers = m;
    }
    int rank = __popcll(peers & ((1ull << lane) - 1ull));
    int cbase = 0;
    #pragma unroll
    for (int k = 0; k < 32; ++k) cbase += (k < key) ? ttot[k] : 0;
    order[cbase + ebb[(n >> 6) * 32 + key] + rank] = n;
}

// ============================================================================
// k2h: stage-2 first half (R0 text — CLOSED: R15/R17/R18 all regressed)
// ============================================================================
__global__ __launch_bounds__(256, 4) void k2h(
    const float* __restrict__ x_t,
    const float* __restrict__ Wcl22, const float* __restrict__ bcl22,
    const float* __restrict__ Wcl32, const float* __restrict__ bcl32,
    const int* __restrict__ total, const int* __restrict__ order,
    int* __restrict__ ind_ord)
{
    __shared__ float Was[4096];
    __shared__ float Wbs[1024];
    __shared__ int cpre[33];
    __shared__ int cbase[33];
    __shared__ int ttot[32];

    const int tid = threadIdx.x;
    if (tid < 32) ttot[tid] = total[tid];
    __syncthreads();
    if (tid == 0) {
        int s = 0, cb = 0;
        for (int k = 0; k < 32; ++k) {
            cpre[k] = s; cbase[k] = cb;
            int c = ttot[k];
            s += (c + 255) >> 8;
            cb += c;
        }
        cpre[32] = s; cbase[32] = cb;
    }
    __syncthreads();
    const int ci = blockIdx.x;
    if (ci >= cpre[32]) return;
    int cls = 0;
    while (cpre[cls + 1] <= ci) ++cls;
    const int st   = (ci - cpre[cls]) * 256;
    const int npx  = min(256, ttot[cls] - st);
    const int base = cbase[cls] + st;

    {
        const float4* ws = (const float4*)(Wcl22 + cls * 4096);
        #pragma unroll
        for (int j = 0; j < 4; ++j) ((float4*)Was)[j * 256 + tid] = ws[j * 256 + tid];
        ((float4*)Wbs)[tid] = ((const float4*)(Wcl32 + cls * 1024))[tid];
    }
    __syncthreads();

    const int m = order[base + min(tid, npx - 1)];
    const float4* xp = (const float4*)(x_t + (size_t)m * 128);

    float h[32];
    #pragma unroll
    for (int j = 0; j < 32; ++j) h[j] = bcl22[cls * 32 + j];
    #pragma unroll 2
    for (int c4 = 0; c4 < 32; ++c4) {
        float4 xv = xp[c4];
        float xa[4] = {xv.x, xv.y, xv.z, xv.w};
        #pragma unroll
        for (int cc = 0; cc < 4; ++cc) {
            const float* wr = &Was[(c4 * 4 + cc) * 32];
            #pragma unroll
            for (int j = 0; j < 32; ++j) h[j] = fmaf(xa[cc], wr[j], h[j]);
        }
    }
    #pragma unroll
    for (int j = 0; j < 32; ++j) h[j] = lrelu(h[j]);

    float g[32];
    #pragma unroll
    for (int j = 0; j < 32; ++j) g[j] = bcl32[cls * 32 + j];
    #pragma unroll 2
    for (int c = 0; c < 32; ++c) {
        float hv = h[c];
        const float* wr = &Wbs[c * 32];
        #pragma unroll
        for (int j = 0; j < 32; ++j) g[j] = fmaf(hv, wr[j], g[j]);
    }
    float bv = g[0]; int bi = 0;
    #pragma unroll
    for (int j = 1; j < 32; ++j)
        if (g[j] > bv) { bv = g[j]; bi = j; }     // strict > = first-max (np.argmax)
    if (tid < npx) ind_ord[base + tid] = cls * 32 + bi;
}

// ============================================================================
// k2r: stage-2 second half (R0 text)
// ============================================================================
__global__ __launch_bounds__(256, 4) void k2r(
    const float* __restrict__ r_t,
    const float* __restrict__ Wr2,  const float* __restrict__ br2,
    const float* __restrict__ Wr3,  const float* __restrict__ br3,
    const int* __restrict__ total, const int* __restrict__ order,
    const int* __restrict__ ind_ord,
    float* __restrict__ out)
{
    __shared__ float Wcs[4096];
    __shared__ int cpre[33];
    __shared__ int cbase[33];
    __shared__ int ttot[32];

    const int tid = threadIdx.x;
    if (tid < 32) ttot[tid] = total[tid];
    __syncthreads();
    if (tid == 0) {
        int s = 0, cb = 0;
        for (int k = 0; k < 32; ++k) {
            cpre[k] = s; cbase[k] = cb;
            int c = ttot[k];
            s += (c + 255) >> 8;
            cb += c;
        }
        cpre[32] = s; cbase[32] = cb;
    }
    __syncthreads();
    const int ci = blockIdx.x;
    if (ci >= cpre[32]) return;
    int cls = 0;
    while (cpre[cls + 1] <= ci) ++cls;
    const int st   = (ci - cpre[cls]) * 256;
    const int npx  = min(256, ttot[cls] - st);
    const int base = cbase[cls] + st;
    const int sup  = cls >> 2;

    {
        const float4* ws = (const float4*)(Wr2 + sup * 4096);
        #pragma unroll
        for (int j = 0; j < 4; ++j) ((float4*)Wcs)[j * 256 + tid] = ws[j * 256 + tid];
    }
    __syncthreads();

    const int li  = min(tid, npx - 1);
    const int m   = order[base + li];
    const int ind = ind_ord[base + li];
    const float4* rp = (const float4*)(r_t + (size_t)m * 128);

    float r2[32];
    #pragma unroll
    for (int j = 0; j < 32; ++j) r2[j] = br2[sup * 32 + j];
    #pragma unroll 2
    for (int c4 = 0; c4 < 32; ++c4) {
        float4 rv = rp[c4];
        float ra[4] = {rv.x, rv.y, rv.z, rv.w};
        #pragma unroll
        for (int cc = 0; cc < 4; ++cc) {
            const float* wr = &Wcs[(c4 * 4 + cc) * 32];
            #pragma unroll
            for (int j = 0; j < 32; ++j) r2[j] = fmaf(ra[cc], wr[j], r2[j]);
        }
    }

    float reg = br3[ind];
    const float* __restrict__ w3 = Wr3 + ind * 32;
    #pragma unroll
    for (int j = 0; j < 32; ++j) reg = fmaf(lrelu(r2[j]), w3[j], reg);

    if (tid < npx) out[m] = ((float)ind + reg) * (1.0f / 1024.0f);
}

extern "C" void kernel_launch(void* const* d_in, const int* in_sizes, int n_in,
                              void* d_out, int out_size, void* d_ws, size_t ws_size,
                              hipStream_t stream)
{
    const float* X     = (const float*)d_in[0];
    const float* Wm1   = (const float*)d_in[1];
    const float* bm1   = (const float*)d_in[2];
    const float* Wm2   = (const float*)d_in[3];
    const float* bm2   = (const float*)d_in[4];
    const float* Wm3   = (const float*)d_in[5];
    const float* bm3   = (const float*)d_in[6];
    const float* Wcl1  = (const float*)d_in[7];
    const float* bcl1  = (const float*)d_in[8];
    const float* Wcl21 = (const float*)d_in[9];
    const float* bcl21 = (const float*)d_in[10];
    const float* Wcl31 = (const float*)d_in[11];
    const float* bcl31 = (const float*)d_in[12];
    const float* Wcl22 = (const float*)d_in[13];
    const float* bcl22 = (const float*)d_in[14];
    const float* Wcl32 = (const float*)d_in[15];
    const float* bcl32 = (const float*)d_in[16];
    const float* Wr1   = (const float*)d_in[17];
    const float* br1   = (const float*)d_in[18];
    const float* Wr2   = (const float*)d_in[19];
    const float* br2   = (const float*)d_in[20];
    const float* Wr3   = (const float*)d_in[21];
    const float* br3   = (const float*)d_in[22];
    float* out = (float*)d_out;

    float* x_t   = (float*)d_ws;
    float* r_t   = x_t + (size_t)NPIX * 128;
    int* inds1_q = (int*)(r_t + (size_t)NPIX * 128);
    int* order   = inds1_q + NPIX;
    int* ind_ord = order + NPIX;
    int* bh      = ind_ord + NPIX;      // [768][32]
    int* ebb     = bh + NSEG * 32;      // [768][32]
    int* total   = ebb + NSEG * 32;     // [32]

    k_fused1<<<dim3(NPIX / 128, 3), 256, 0, stream>>>(X, Wcl1, bcl1, Wr1, br1,
                                                      Wm1, bm1, Wm2, bm2, Wm3, bm3,
                                                      x_t, r_t, out);
    k1b<<<NPIX / 64, 256, 0, stream>>>(x_t, Wcl21, bcl21, Wcl31, bcl31, inds1_q);
    k_hist<<<NPIX / 256, 256, 0, stream>>>(inds1_q, bh);
    k_scanA<<<32, 256, 0, stream>>>(bh, ebb, total);
    k_scatter2<<<NPIX / 256, 256, 0, stream>>>(inds1_q, ebb, total, order);
    // 256-px chunks: worst case sum ceil = 192 + 31 = 223 -> grid 224 covers all
    k2h<<<224, 256, 0, stream>>>(x_t, Wcl22, bcl22, Wcl32, bcl32, total, order, ind_ord);
    k2r<<<224, 256, 0, stream>>>(r_t, Wr2, br2, Wr3, br3, total, order, ind_ord, out);
}

// Round 17
// 221.278 us; speedup vs baseline: 1.6435x; 1.0078x over previous
//
#include <hip/hip_runtime.h>

#define HH 192
#define WW 256
#define NPIX (HH*WW)   // 49152
#define NSEG (NPIX/64) // 768

__device__ __forceinline__ float lrelu(float v) { return v > 0.0f ? v : 0.01f * v; }

// bf16 hi/lo split helpers (RNE via round-half-up on guard bit)
__device__ __forceinline__ unsigned short bfhi(float x) {
    unsigned b = __float_as_uint(x);
    return (unsigned short)((b + 0x7FFFu + ((b >> 16) & 1u)) >> 16);
}
__device__ __forceinline__ float bff(unsigned short u) {
    return __uint_as_float(((unsigned)u) << 16);
}

typedef __attribute__((ext_vector_type(8))) short short8v;  // 8 bf16 = 4 VGPR
typedef __attribute__((ext_vector_type(4))) short short4v;  // 8B packed write
typedef __attribute__((ext_vector_type(4))) float f32x4;    // MFMA acc

// ============================================================================
// k_fused1 (R23): y=0 EXACT R6 fp32 (argmax-locked, CLOSED). y=1 bf16 hi/lo
// MFMA (R20-R22 verified: conflicts 6.92M->1.07M, absmax unchanged).
// R23: y=2 mask branch ALSO converted to hi/lo MFMA — mask feeds NO argmax,
// error ~2e-5 direct (absmax may rise 6.1e-5 -> <~1e-4). Structure clones
// the verified y1 branch: same X staging/swizzles, Wm1 32x32 tile, per-wave
// 2 px-tiles x 2 o-tiles. m2/m3 tail unchanged (m1buf aliased post-loop).
// ============================================================================
__global__ __launch_bounds__(256, 3) void k_fused1(
    const float* __restrict__ X,
    const float* __restrict__ Wcl1, const float* __restrict__ bcl1,
    const float* __restrict__ Wr1,  const float* __restrict__ br1,
    const float* __restrict__ Wm1,  const float* __restrict__ bm1,
    const float* __restrict__ Wm2,  const float* __restrict__ bm2,
    const float* __restrict__ Wm3,  const float* __restrict__ bm3,
    float* __restrict__ x_t, float* __restrict__ r_t,
    float* __restrict__ out)
{
    __shared__ float smem[10240];                      // 40960 B
    float (*As)[132]   = (float(*)[132])smem;          // y0: [16][132]
    float (*Ws)[132]   = (float(*)[132])(smem + 2112);

    const int tid = threadIdx.x;
    const int q0  = blockIdx.x * 128;

    if (blockIdx.y == 2) {
        // ---- mask branch (R23): Wm1@X via bf16 hi/lo MFMA ----
        unsigned short* Wmhi = (unsigned short*)smem;          // [32][40]
        unsigned short* Wmlo = Wmhi + 1280;                    // [32][40]
        unsigned short* Xthi = Wmlo + 1280;                    // [128][40]
        unsigned short* Xtlo = Xthi + 5120;                    // [128][40]
        float (*m1b)[33] = (float(*)[33])smem;                 // post-loop alias

        const int l = tid & 63;
        const int w = tid >> 6;
        const int c = l & 15;
        const int g = l >> 4;

        float bvm[2][4];
        #pragma unroll
        for (int ot = 0; ot < 2; ++ot)
            #pragma unroll
            for (int r = 0; r < 4; ++r)
                bvm[ot][r] = bm1[ot * 16 + g * 4 + r];

        f32x4 accM[2][2];
        #pragma unroll
        for (int ot = 0; ot < 2; ++ot)
            #pragma unroll
            for (int pi = 0; pi < 2; ++pi) {
                accM[ot][pi][0] = bvm[ot][0]; accM[ot][pi][1] = bvm[ot][1];
                accM[ot][pi][2] = bvm[ot][2]; accM[ot][pi][3] = bvm[ot][3];
            }

        const int sx_px = tid & 127;
        const int sx_kh = (tid >> 7) * 16;
        const float* Xp = X + q0 + sx_px;

        for (int k0 = 0; k0 < 128; k0 += 32) {
            // X staging — verbatim y1 pattern
            {
                float xv[16];
                #pragma unroll
                for (int i = 0; i < 16; ++i)
                    xv[i] = Xp[(size_t)(k0 + sx_kh + i) * NPIX];
                #pragma unroll
                for (int j = 0; j < 2; ++j) {
                    short8v hv, lv;
                    #pragma unroll
                    for (int i = 0; i < 8; ++i) {
                        unsigned short h = bfhi(xv[j * 8 + i]);
                        hv[i] = (short)h;
                        lv[i] = (short)bfhi(xv[j * 8 + i] - bff(h));
                    }
                    int gg = (sx_kh >> 3) + j;
                    int gs = gg ^ ((sx_px >> 3) & 3);
                    *(short8v*)(Xthi + sx_px * 40 + gs * 8) = hv;
                    *(short8v*)(Xtlo + sx_px * 40 + gs * 8) = lv;
                }
            }
            // Wm1 staging: 32 o x 32 k, one float4 per thread
            {
                int o = tid >> 3, kc = (tid & 7) * 4;
                float4 v = *(const float4*)(Wm1 + o * 128 + k0 + kc);
                float wv[4] = {v.x, v.y, v.z, v.w};
                short4v hv, lv;
                #pragma unroll
                for (int i = 0; i < 4; ++i) {
                    unsigned short h = bfhi(wv[i]);
                    hv[i] = (short)h;
                    lv[i] = (short)bfhi(wv[i] - bff(h));
                }
                int gg = kc >> 3;
                int gs = gg ^ (o & 3);
                int addr = o * 40 + gs * 8 + (kc & 7);
                *(short4v*)(Wmhi + addr) = hv;
                *(short4v*)(Wmlo + addr) = lv;
            }
            __syncthreads();

            short8v ahi[2], alo[2];
            #pragma unroll
            for (int ot = 0; ot < 2; ++ot) {
                int row = ot * 16 + c;
                int ao = row * 40 + (g ^ (row & 3)) * 8;
                ahi[ot] = *(const short8v*)(Wmhi + ao);
                alo[ot] = *(const short8v*)(Wmlo + ao);
            }
            #pragma unroll
            for (int pi = 0; pi < 2; ++pi) {
                int row = (2 * w + pi) * 16 + c;
                int bo = row * 40 + (g ^ ((row >> 3) & 3)) * 8;
                short8v bhi = *(const short8v*)(Xthi + bo);
                short8v blo = *(const short8v*)(Xtlo + bo);
                #pragma unroll
                for (int ot = 0; ot < 2; ++ot) {
                    accM[ot][pi] = __builtin_amdgcn_mfma_f32_16x16x32_bf16(
                        ahi[ot], bhi, accM[ot][pi], 0, 0, 0);
                    accM[ot][pi] = __builtin_amdgcn_mfma_f32_16x16x32_bf16(
                        ahi[ot], blo, accM[ot][pi], 0, 0, 0);
                    accM[ot][pi] = __builtin_amdgcn_mfma_f32_16x16x32_bf16(
                        alo[ot], bhi, accM[ot][pi], 0, 0, 0);
                }
            }
            __syncthreads();
        }
        // epilogue: D[row=g*4+r][col=c] -> m1b[px][o] (tiles dead post-barrier)
        #pragma unroll
        for (int pi = 0; pi < 2; ++pi) {
            int px = (2 * w + pi) * 16 + c;
            #pragma unroll
            for (int ot = 0; ot < 2; ++ot)
                #pragma unroll
                for (int r = 0; r < 4; ++r)
                    m1b[px][ot * 16 + g * 4 + r] = lrelu(accM[ot][pi][r]);
        }
        __syncthreads();
        if (tid < 128) {
            float m3 = bm3[0];
            #pragma unroll 2
            for (int j = 0; j < 16; ++j) {
                float s = bm2[j];
                #pragma unroll
                for (int k = 0; k < 32; ++k)
                    s = fmaf(Wm2[j * 32 + k], m1b[tid][k], s);
                m3 = fmaf(Wm3[j], lrelu(s), m3);
            }
            out[NPIX + q0 + tid] = lrelu(m3);
        }
        return;
    }

    if (blockIdx.y == 1) {
        // ---- y=1: r_t via bf16 hi/lo-split MFMA (R22 text) ----
        unsigned short* Whi  = (unsigned short*)smem;            // [128][40]
        unsigned short* Wlo  = Whi  + 5120;                      // [128][40]
        unsigned short* Xthi = Wlo  + 5120;                      // [128px][40]
        unsigned short* Xtlo = Xthi + 5120;                      // [128px][40]

        const int l = tid & 63;
        const int w = tid >> 6;
        const int c = l & 15;
        const int g = l >> 4;
        const int o0 = w * 32;

        float bv[2][4];
        #pragma unroll
        for (int ot = 0; ot < 2; ++ot)
            #pragma unroll
            for (int r = 0; r < 4; ++r)
                bv[ot][r] = br1[o0 + ot * 16 + g * 4 + r];

        f32x4 acc[2][8];
        #pragma unroll
        for (int ot = 0; ot < 2; ++ot)
            #pragma unroll
            for (int pt = 0; pt < 8; ++pt) {
                acc[ot][pt][0] = bv[ot][0]; acc[ot][pt][1] = bv[ot][1];
                acc[ot][pt][2] = bv[ot][2]; acc[ot][pt][3] = bv[ot][3];
            }

        const int sx_px = tid & 127;
        const int sx_kh = (tid >> 7) * 16;
        const float* Xp = X + q0 + sx_px;

        for (int k0 = 0; k0 < 128; k0 += 32) {
            {
                float xv[16];
                #pragma unroll
                for (int i = 0; i < 16; ++i)
                    xv[i] = Xp[(size_t)(k0 + sx_kh + i) * NPIX];
                #pragma unroll
                for (int j = 0; j < 2; ++j) {
                    short8v hv, lv;
                    #pragma unroll
                    for (int i = 0; i < 8; ++i) {
                        unsigned short h = bfhi(xv[j * 8 + i]);
                        hv[i] = (short)h;
                        lv[i] = (short)bfhi(xv[j * 8 + i] - bff(h));
                    }
                    int gg = (sx_kh >> 3) + j;
                    int gs = gg ^ ((sx_px >> 3) & 3);
                    *(short8v*)(Xthi + sx_px * 40 + gs * 8) = hv;
                    *(short8v*)(Xtlo + sx_px * 40 + gs * 8) = lv;
                }
            }
            #pragma unroll
            for (int p = 0; p < 4; ++p) {
                int lin = p * 1024 + tid * 4;
                int o = lin >> 5, kc = lin & 31;
                float4 v = *(const float4*)(Wr1 + o * 128 + k0 + kc);
                float wv[4] = {v.x, v.y, v.z, v.w};
                short4v hv, lv;
                #pragma unroll
                for (int i = 0; i < 4; ++i) {
                    unsigned short h = bfhi(wv[i]);
                    hv[i] = (short)h;
                    lv[i] = (short)bfhi(wv[i] - bff(h));
                }
                int gg = kc >> 3;
                int gs = gg ^ (o & 3);
                int addr = o * 40 + gs * 8 + (kc & 7);
                *(short4v*)(Whi + addr) = hv;
                *(short4v*)(Wlo + addr) = lv;
            }
            __syncthreads();

            short8v ahi[2], alo[2];
            #pragma unroll
            for (int ot = 0; ot < 2; ++ot) {
                int row = o0 + ot * 16 + c;
                int ao = row * 40 + (g ^ (row & 3)) * 8;
                ahi[ot] = *(const short8v*)(Whi + ao);
                alo[ot] = *(const short8v*)(Wlo + ao);
            }
            #pragma unroll
            for (int pt = 0; pt < 8; ++pt) {
                int row = pt * 16 + c;
                int bo = row * 40 + (g ^ ((row >> 3) & 3)) * 8;
                short8v bhi = *(const short8v*)(Xthi + bo);
                short8v blo = *(const short8v*)(Xtlo + bo);
                #pragma unroll
                for (int ot = 0; ot < 2; ++ot) {
                    acc[ot][pt] = __builtin_amdgcn_mfma_f32_16x16x32_bf16(
                        ahi[ot], bhi, acc[ot][pt], 0, 0, 0);
                    acc[ot][pt] = __builtin_amdgcn_mfma_f32_16x16x32_bf16(
                        ahi[ot], blo, acc[ot][pt], 0, 0, 0);
                    acc[ot][pt] = __builtin_amdgcn_mfma_f32_16x16x32_bf16(
                        alo[ot], bhi, acc[ot][pt], 0, 0, 0);
                }
            }
            __syncthreads();
        }

        #pragma unroll
        for (int pt = 0; pt < 8; ++pt) {
            int px = pt * 16 + c;
            int q  = q0 + px;
            int np = (q & 255) * 192 + (q >> 8);
            float* op = r_t + (size_t)np * 128;
            #pragma unroll
            for (int ot = 0; ot < 2; ++ot) {
                float4 o4;
                o4.x = lrelu(acc[ot][pt][0]); o4.y = lrelu(acc[ot][pt][1]);
                o4.z = lrelu(acc[ot][pt][2]); o4.w = lrelu(acc[ot][pt][3]);
                *(float4*)(op + o0 + ot * 16 + g * 4) = o4;
            }
        }
        return;
    }

    // ---- y=0: x_t via fp32 VALU — EXACT R6 text (argmax-safe path) ----
    const float* __restrict__ W    = Wcl1;
    const float* __restrict__ bias = bcl1;
    float* __restrict__ outp       = x_t;

    const int tc = tid & 15;
    const int tr = tid >> 4;

    float acc[8][8];
    #pragma unroll
    for (int i = 0; i < 8; ++i)
        #pragma unroll
        for (int j = 0; j < 8; ++j)
            acc[i][j] = bias[(j >> 2) * 64 + tr * 4 + (j & 3)];

    for (int k0 = 0; k0 < 128; k0 += 16) {
        #pragma unroll
        for (int p = 0; p < 2; ++p) {
            int lin = p * 1024 + tid * 4;
            int kk = lin >> 7, px = lin & 127;
            float4 v = *(const float4*)(X + (k0 + kk) * NPIX + q0 + px);
            *(float4*)(&As[kk][px]) = v;
        }
        #pragma unroll
        for (int p = 0; p < 2; ++p) {
            int lin = p * 1024 + tid * 4;
            int row = lin >> 4, kc = lin & 15;
            float4 v = *(const float4*)(W + row * 128 + k0 + kc);
            Ws[kc + 0][row] = v.x; Ws[kc + 1][row] = v.y;
            Ws[kc + 2][row] = v.z; Ws[kc + 3][row] = v.w;
        }
        __syncthreads();
        #pragma unroll
        for (int kk = 0; kk < 16; ++kk) {
            float4 a0 = *(const float4*)(&As[kk][tc * 4]);
            float4 a1 = *(const float4*)(&As[kk][64 + tc * 4]);
            float4 w0 = *(const float4*)(&Ws[kk][tr * 4]);
            float4 w1 = *(const float4*)(&Ws[kk][64 + tr * 4]);
            float av[8] = {a0.x,a0.y,a0.z,a0.w,a1.x,a1.y,a1.z,a1.w};
            float wv[8] = {w0.x,w0.y,w0.z,w0.w,w1.x,w1.y,w1.z,w1.w};
            #pragma unroll
            for (int i = 0; i < 8; ++i)
                #pragma unroll
                for (int j = 0; j < 8; ++j)
                    acc[i][j] = fmaf(av[i], wv[j], acc[i][j]);
        }
        __syncthreads();
    }

    #pragma unroll
    for (int i = 0; i < 8; ++i) {
        int px = (i >> 2) * 64 + tc * 4 + (i & 3);
        int q  = q0 + px;
        int np = (q & 255) * 192 + (q >> 8);
        float* op = outp + (size_t)np * 128;
        #pragma unroll
        for (int jg = 0; jg < 2; ++jg) {
            float4 o;
            o.x = lrelu(acc[i][jg*4+0]); o.y = lrelu(acc[i][jg*4+1]);
            o.z = lrelu(acc[i][jg*4+2]); o.w = lrelu(acc[i][jg*4+3]);
            *(float4*)(op + jg * 64 + tr * 4) = o;
        }
    }
}

// ============================================================================
// k1b (R16, part of the best config): 64-px tiles, grid 768 = 3 blocks/CU.
// ============================================================================
__global__ __launch_bounds__(256, 3) void k1b(
    const float* __restrict__ x_t,
    const float* __restrict__ Wcl21, const float* __restrict__ bcl21,
    const float* __restrict__ Wcl31, const float* __restrict__ bcl31,
    int* __restrict__ inds1_q)
{
    __shared__ float smem[8576];                        // 34304 B
    float (*As)[132]    = (float(*)[132])smem;          // [16][132] cols 0..63 used
    float (*Ws)[132]    = (float(*)[132])(smem + 2112); // [16][132]
    float (*W31)[132]   = (float(*)[132])smem;          // [32][132] aliases As+Ws
    float (*x2t)[68]    = (float(*)[68])(smem + 4224);  // [64][68]
    float (*cl1buf)[33] = (float(*)[33])(smem + 4224);  // [64][33] aliases x2t

    const int tid = threadIdx.x;
    const int n0  = blockIdx.x * 64;
    const int tcA = tid & 15, trA = tid >> 4;

    float acc[4][8];
    #pragma unroll
    for (int i = 0; i < 4; ++i)
        #pragma unroll
        for (int j = 0; j < 8; ++j)
            acc[i][j] = bcl21[(j >> 2) * 64 + trA * 4 + (j & 3)];

    for (int k0 = 0; k0 < 128; k0 += 16) {
        {
            int lin = tid * 4;
            int px = lin >> 4, kc = lin & 15;
            float4 v = *(const float4*)(x_t + (size_t)(n0 + px) * 128 + k0 + kc);
            As[kc + 0][px] = v.x; As[kc + 1][px] = v.y;
            As[kc + 2][px] = v.z; As[kc + 3][px] = v.w;
        }
        #pragma unroll
        for (int p = 0; p < 2; ++p) {
            int lin = p * 256 + tid;
            int r = lin >> 2, kc = (lin & 3) * 4;
            float4 v = *(const float4*)(Wcl21 + r * 128 + k0 + kc);
            Ws[kc + 0][r] = v.x; Ws[kc + 1][r] = v.y;
            Ws[kc + 2][r] = v.z; Ws[kc + 3][r] = v.w;
        }
        __syncthreads();
        #pragma unroll
        for (int kk = 0; kk < 16; ++kk) {
            float4 a  = *(const float4*)(&As[kk][tcA * 4]);
            float4 w0 = *(const float4*)(&Ws[kk][trA * 4]);
            float4 w1 = *(const float4*)(&Ws[kk][64 + trA * 4]);
            float av[4] = {a.x,a.y,a.z,a.w};
            float wv[8] = {w0.x,w0.y,w0.z,w0.w,w1.x,w1.y,w1.z,w1.w};
            #pragma unroll
            for (int i = 0; i < 4; ++i)
                #pragma unroll
                for (int j = 0; j < 8; ++j)
                    acc[i][j] = fmaf(av[i], wv[j], acc[i][j]);
        }
        __syncthreads();
    }

    const int tcB = tid & 15;
    const int trB = tid >> 4;
    float accB[4][2];
    #pragma unroll
    for (int i = 0; i < 4; ++i)
        #pragma unroll
        for (int j = 0; j < 2; ++j)
            accB[i][j] = bcl31[trB * 2 + j];

    #pragma unroll
    for (int p = 0; p < 4; ++p) {
        int lin = p * 1024 + tid * 4;
        int row = lin >> 7, kc = lin & 127;
        *(float4*)(&W31[row][kc]) = *(const float4*)(Wcl31 + row * 128 + kc);
    }
    #pragma unroll
    for (int j = 0; j < 4; ++j) {
        float4 o;
        o.x = lrelu(acc[0][j]); o.y = lrelu(acc[1][j]);
        o.z = lrelu(acc[2][j]); o.w = lrelu(acc[3][j]);
        *(float4*)(&x2t[trA * 4 + j][tcA * 4]) = o;
    }
    __syncthreads();
    for (int k = 0; k < 64; ++k) {
        float4 a = *(const float4*)(&x2t[k][tcB * 4]);
        float av[4] = {a.x,a.y,a.z,a.w};
        float w0 = W31[trB * 2 + 0][k];
        float w1 = W31[trB * 2 + 1][k];
        #pragma unroll
        for (int i = 0; i < 4; ++i) {
            accB[i][0] = fmaf(av[i], w0, accB[i][0]);
            accB[i][1] = fmaf(av[i], w1, accB[i][1]);
        }
    }
    __syncthreads();
    #pragma unroll
    for (int j = 0; j < 4; ++j) {
        float4 o;
        o.x = lrelu(acc[0][4+j]); o.y = lrelu(acc[1][4+j]);
        o.z = lrelu(acc[2][4+j]); o.w = lrelu(acc[3][4+j]);
        *(float4*)(&x2t[trA * 4 + j][tcA * 4]) = o;
    }
    __syncthreads();
    for (int k = 0; k < 64; ++k) {
        float4 a = *(const float4*)(&x2t[k][tcB * 4]);
        float av[4] = {a.x,a.y,a.z,a.w};
        float w0 = W31[trB * 2 + 0][64 + k];
        float w1 = W31[trB * 2 + 1][64 + k];
        #pragma unroll
        for (int i = 0; i < 4; ++i) {
            accB[i][0] = fmaf(av[i], w0, accB[i][0]);
            accB[i][1] = fmaf(av[i], w1, accB[i][1]);
        }
    }
    __syncthreads();

    #pragma unroll
    for (int i = 0; i < 4; ++i)
        #pragma unroll
        for (int j = 0; j < 2; ++j)
            cl1buf[tcB * 4 + i][trB * 2 + j] = accB[i][j];
    __syncthreads();
    if (tid < 64) {
        float bv = cl1buf[tid][0]; int bi = 0;
        #pragma unroll
        for (int c = 1; c < 32; ++c) {
            float v = cl1buf[tid][c];
            if (v > bv) { bv = v; bi = c; }
        }
        int n = n0 + tid;
        int w = n / 192, hh = n - w * 192;
        inds1_q[hh * 256 + w] = bi;
    }
}

// ============================================================================
// k_hist / k_scanA / k_scatter2 (R0 text)
// ============================================================================
__global__ void k_hist(const int* __restrict__ inds1_q, int* __restrict__ bh) {
    int tid = threadIdx.x;
    int n = blockIdx.x * 256 + tid;
    int key = inds1_q[n];
    int lane = tid & 63;
    int cnt = 0;
    for (int k = 0; k < 32; ++k) {
        unsigned long long m = __ballot(key == k);
        if (lane == k) cnt = __popcll(m);
    }
    if (lane < 32) bh[(n >> 6) * 32 + lane] = cnt;
}

__global__ void k_scanA(const int* __restrict__ bh, int* __restrict__ ebb,
                        int* __restrict__ total) {
    __shared__ int s[256];
    const int k = blockIdx.x, t = threadIdx.x;
    int v0 = bh[(t * 3 + 0) * 32 + k];
    int v1 = bh[(t * 3 + 1) * 32 + k];
    int v2 = bh[(t * 3 + 2) * 32 + k];
    int sum = v0 + v1 + v2;
    s[t] = sum; __syncthreads();
    for (int d = 1; d < 256; d <<= 1) {
        int x = (t >= d) ? s[t - d] : 0;
        __syncthreads();
        s[t] += x;
        __syncthreads();
    }
    int ex = s[t] - sum;
    ebb[(t * 3 + 0) * 32 + k] = ex;
    ebb[(t * 3 + 1) * 32 + k] = ex + v0;
    ebb[(t * 3 + 2) * 32 + k] = ex + v0 + v1;
    if (t == 255) total[k] = s[255];
}

__global__ void k_scatter2(const int* __restrict__ inds1_q,
                           const int* __restrict__ ebb,
                           const int* __restrict__ total,
                           int* __restrict__ order)
{
    __shared__ int ttot[32];
    const int tid = threadIdx.x;
    if (tid < 32) ttot[tid] = total[tid];
    __syncthreads();
    int n = blockIdx.x * 256 + tid;
    int key = inds1_q[n];
    int lane = tid & 63;
    unsigned long long peers = 0;
    for (int k = 0; k < 32; ++k) {
        unsigned long long m = __ballot(key == k);
        if (key == k) peers = m;
    }
    int rank = __popcll(peers & ((1ull << lane) - 1ull));
    int cbase = 0;
    #pragma unroll
    for (int k = 0; k < 32; ++k) cbase += (k < key) ? ttot[k] : 0;
    order[cbase + ebb[(n >> 6) * 32 + key] + rank] = n;
}

// ============================================================================
// k2h: stage-2 first half (R0 text — CLOSED: R15/R17/R18 all regressed)
// ============================================================================
__global__ __launch_bounds__(256, 4) void k2h(
    const float* __restrict__ x_t,
    const float* __restrict__ Wcl22, const float* __restrict__ bcl22,
    const float* __restrict__ Wcl32, const float* __restrict__ bcl32,
    const int* __restrict__ total, const int* __restrict__ order,
    int* __restrict__ ind_ord)
{
    __shared__ float Was[4096];
    __shared__ float Wbs[1024];
    __shared__ int cpre[33];
    __shared__ int cbase[33];
    __shared__ int ttot[32];

    const int tid = threadIdx.x;
    if (tid < 32) ttot[tid] = total[tid];
    __syncthreads();
    if (tid == 0) {
        int s = 0, cb = 0;
        for (int k = 0; k < 32; ++k) {
            cpre[k] = s; cbase[k] = cb;
            int c = ttot[k];
            s += (c + 255) >> 8;
            cb += c;
        }
        cpre[32] = s; cbase[32] = cb;
    }
    __syncthreads();
    const int ci = blockIdx.x;
    if (ci >= cpre[32]) return;
    int cls = 0;
    while (cpre[cls + 1] <= ci) ++cls;
    const int st   = (ci - cpre[cls]) * 256;
    const int npx  = min(256, ttot[cls] - st);
    const int base = cbase[cls] + st;

    {
        const float4* ws = (const float4*)(Wcl22 + cls * 4096);
        #pragma unroll
        for (int j = 0; j < 4; ++j) ((float4*)Was)[j * 256 + tid] = ws[j * 256 + tid];
        ((float4*)Wbs)[tid] = ((const float4*)(Wcl32 + cls * 1024))[tid];
    }
    __syncthreads();

    const int m = order[base + min(tid, npx - 1)];
    const float4* xp = (const float4*)(x_t + (size_t)m * 128);

    float h[32];
    #pragma unroll
    for (int j = 0; j < 32; ++j) h[j] = bcl22[cls * 32 + j];
    #pragma unroll 2
    for (int c4 = 0; c4 < 32; ++c4) {
        float4 xv = xp[c4];
        float xa[4] = {xv.x, xv.y, xv.z, xv.w};
        #pragma unroll
        for (int cc = 0; cc < 4; ++cc) {
            const float* wr = &Was[(c4 * 4 + cc) * 32];
            #pragma unroll
            for (int j = 0; j < 32; ++j) h[j] = fmaf(xa[cc], wr[j], h[j]);
        }
    }
    #pragma unroll
    for (int j = 0; j < 32; ++j) h[j] = lrelu(h[j]);

    float g[32];
    #pragma unroll
    for (int j = 0; j < 32; ++j) g[j] = bcl32[cls * 32 + j];
    #pragma unroll 2
    for (int c = 0; c < 32; ++c) {
        float hv = h[c];
        const float* wr = &Wbs[c * 32];
        #pragma unroll
        for (int j = 0; j < 32; ++j) g[j] = fmaf(hv, wr[j], g[j]);
    }
    float bv = g[0]; int bi = 0;
    #pragma unroll
    for (int j = 1; j < 32; ++j)
        if (g[j] > bv) { bv = g[j]; bi = j; }     // strict > = first-max (np.argmax)
    if (tid < npx) ind_ord[base + tid] = cls * 32 + bi;
}

// ============================================================================
// k2r: stage-2 second half (R0 text)
// ============================================================================
__global__ __launch_bounds__(256, 4) void k2r(
    const float* __restrict__ r_t,
    const float* __restrict__ Wr2,  const float* __restrict__ br2,
    const float* __restrict__ Wr3,  const float* __restrict__ br3,
    const int* __restrict__ total, const int* __restrict__ order,
    const int* __restrict__ ind_ord,
    float* __restrict__ out)
{
    __shared__ float Wcs[4096];
    __shared__ int cpre[33];
    __shared__ int cbase[33];
    __shared__ int ttot[32];

    const int tid = threadIdx.x;
    if (tid < 32) ttot[tid] = total[tid];
    __syncthreads();
    if (tid == 0) {
        int s = 0, cb = 0;
        for (int k = 0; k < 32; ++k) {
            cpre[k] = s; cbase[k] = cb;
            int c = ttot[k];
            s += (c + 255) >> 8;
            cb += c;
        }
        cpre[32] = s; cbase[32] = cb;
    }
    __syncthreads();
    const int ci = blockIdx.x;
    if (ci >= cpre[32]) return;
    int cls = 0;
    while (cpre[cls + 1] <= ci) ++cls;
    const int st   = (ci - cpre[cls]) * 256;
    const int npx  = min(256, ttot[cls] - st);
    const int base = cbase[cls] + st;
    const int sup  = cls >> 2;

    {
        const float4* ws = (const float4*)(Wr2 + sup * 4096);
        #pragma unroll
        for (int j = 0; j < 4; ++j) ((float4*)Wcs)[j * 256 + tid] = ws[j * 256 + tid];
    }
    __syncthreads();

    const int li  = min(tid, npx - 1);
    const int m   = order[base + li];
    const int ind = ind_ord[base + li];
    const float4* rp = (const float4*)(r_t + (size_t)m * 128);

    float r2[32];
    #pragma unroll
    for (int j = 0; j < 32; ++j) r2[j] = br2[sup * 32 + j];
    #pragma unroll 2
    for (int c4 = 0; c4 < 32; ++c4) {
        float4 rv = rp[c4];
        float ra[4] = {rv.x, rv.y, rv.z, rv.w};
        #pragma unroll
        for (int cc = 0; cc < 4; ++cc) {
            const float* wr = &Wcs[(c4 * 4 + cc) * 32];
            #pragma unroll
            for (int j = 0; j < 32; ++j) r2[j] = fmaf(ra[cc], wr[j], r2[j]);
        }
    }

    float reg = br3[ind];
    const float* __restrict__ w3 = Wr3 + ind * 32;
    #pragma unroll
    for (int j = 0; j < 32; ++j) reg = fmaf(lrelu(r2[j]), w3[j], reg);

    if (tid < npx) out[m] = ((float)ind + reg) * (1.0f / 1024.0f);
}

extern "C" void kernel_launch(void* const* d_in, const int* in_sizes, int n_in,
                              void* d_out, int out_size, void* d_ws, size_t ws_size,
                              hipStream_t stream)
{
    const float* X     = (const float*)d_in[0];
    const float* Wm1   = (const float*)d_in[1];
    const float* bm1   = (const float*)d_in[2];
    const float* Wm2   = (const float*)d_in[3];
    const float* bm2   = (const float*)d_in[4];
    const float* Wm3   = (const float*)d_in[5];
    const float* bm3   = (const float*)d_in[6];
    const float* Wcl1  = (const float*)d_in[7];
    const float* bcl1  = (const float*)d_in[8];
    const float* Wcl21 = (const float*)d_in[9];
    const float* bcl21 = (const float*)d_in[10];
    const float* Wcl31 = (const float*)d_in[11];
    const float* bcl31 = (const float*)d_in[12];
    const float* Wcl22 = (const float*)d_in[13];
    const float* bcl22 = (const float*)d_in[14];
    const float* Wcl32 = (const float*)d_in[15];
    const float* bcl32 = (const float*)d_in[16];
    const float* Wr1   = (const float*)d_in[17];
    const float* br1   = (const float*)d_in[18];
    const float* Wr2   = (const float*)d_in[19];
    const float* br2   = (const float*)d_in[20];
    const float* Wr3   = (const float*)d_in[21];
    const float* br3   = (const float*)d_in[22];
    float* out = (float*)d_out;

    float* x_t   = (float*)d_ws;
    float* r_t   = x_t + (size_t)NPIX * 128;
    int* inds1_q = (int*)(r_t + (size_t)NPIX * 128);
    int* order   = inds1_q + NPIX;
    int* ind_ord = order + NPIX;
    int* bh      = ind_ord + NPIX;      // [768][32]
    int* ebb     = bh + NSEG * 32;      // [768][32]
    int* total   = ebb + NSEG * 32;     // [32]

    k_fused1<<<dim3(NPIX / 128, 3), 256, 0, stream>>>(X, Wcl1, bcl1, Wr1, br1,
                                                      Wm1, bm1, Wm2, bm2, Wm3, bm3,
                                                      x_t, r_t, out);
    k1b<<<NPIX / 64, 256, 0, stream>>>(x_t, Wcl21, bcl21, Wcl31, bcl31, inds1_q);
    k_hist<<<NPIX / 256, 256, 0, stream>>>(inds1_q, bh);
    k_scanA<<<32, 256, 0, stream>>>(bh, ebb, total);
    k_scatter2<<<NPIX / 256, 256, 0, stream>>>(inds1_q, ebb, total, order);
    // 256-px chunks: worst case sum ceil = 192 + 31 = 223 -> grid 224 covers all
    k2h<<<224, 256, 0, stream>>>(x_t, Wcl22, bcl22, Wcl32, bcl32, total, order, ind_ord);
    k2r<<<224, 256, 0, stream>>>(r_t, Wr2, br2, Wr3, br3, total, order, ind_ord, out);
}

// Round 18
// 215.219 us; speedup vs baseline: 1.6898x; 1.0282x over previous
//
#include <hip/hip_runtime.h>

#define HH 192
#define WW 256
#define NPIX (HH*WW)   // 49152
#define NSEG (NPIX/64) // 768

__device__ __forceinline__ float lrelu(float v) { return v > 0.0f ? v : 0.01f * v; }

// bf16 hi/lo split helpers (RNE via round-half-up on guard bit)
__device__ __forceinline__ unsigned short bfhi(float x) {
    unsigned b = __float_as_uint(x);
    return (unsigned short)((b + 0x7FFFu + ((b >> 16) & 1u)) >> 16);
}
__device__ __forceinline__ float bff(unsigned short u) {
    return __uint_as_float(((unsigned)u) << 16);
}

typedef __attribute__((ext_vector_type(8))) short short8v;  // 8 bf16 = 4 VGPR
typedef __attribute__((ext_vector_type(4))) short short4v;  // 8B packed write
typedef __attribute__((ext_vector_type(4))) float f32x4;    // MFMA acc

// ============================================================================
// k_fused1 (R24): ALL THREE branches now bf16 hi/lo MFMA.
//   y=1 (r_t):  3-term (R20-R22 verified; error 1/1024-scaled in out).
//   y=2 (mask): 3-term (R23 verified; absmax 2.44e-4, passed).
//   y=0 (x_t):  R24 — 4-TERM split (adds Wlo.Xlo MFMA): residual = pair
//     representation error ~2^-18 rel; reaches the argmax chains only
//     through two further fp32 GEMMs (~3e-5 at cl1 vs ~0.1 gaps).
//     Pre-registered failure: argmax flips -> absmax >= 0.03 -> revert to
//     R23 and declare floor.
// ============================================================================
__global__ __launch_bounds__(256, 3) void k_fused1(
    const float* __restrict__ X,
    const float* __restrict__ Wcl1, const float* __restrict__ bcl1,
    const float* __restrict__ Wr1,  const float* __restrict__ br1,
    const float* __restrict__ Wm1,  const float* __restrict__ bm1,
    const float* __restrict__ Wm2,  const float* __restrict__ bm2,
    const float* __restrict__ Wm3,  const float* __restrict__ bm3,
    float* __restrict__ x_t, float* __restrict__ r_t,
    float* __restrict__ out)
{
    __shared__ float smem[10240];                      // 40960 B

    const int tid = threadIdx.x;
    const int q0  = blockIdx.x * 128;

    if (blockIdx.y == 2) {
        // ---- mask branch (R23 text): Wm1@X via bf16 hi/lo MFMA ----
        unsigned short* Wmhi = (unsigned short*)smem;          // [32][40]
        unsigned short* Wmlo = Wmhi + 1280;                    // [32][40]
        unsigned short* Xthi = Wmlo + 1280;                    // [128][40]
        unsigned short* Xtlo = Xthi + 5120;                    // [128][40]
        float (*m1b)[33] = (float(*)[33])smem;                 // post-loop alias

        const int l = tid & 63;
        const int w = tid >> 6;
        const int c = l & 15;
        const int g = l >> 4;

        float bvm[2][4];
        #pragma unroll
        for (int ot = 0; ot < 2; ++ot)
            #pragma unroll
            for (int r = 0; r < 4; ++r)
                bvm[ot][r] = bm1[ot * 16 + g * 4 + r];

        f32x4 accM[2][2];
        #pragma unroll
        for (int ot = 0; ot < 2; ++ot)
            #pragma unroll
            for (int pi = 0; pi < 2; ++pi) {
                accM[ot][pi][0] = bvm[ot][0]; accM[ot][pi][1] = bvm[ot][1];
                accM[ot][pi][2] = bvm[ot][2]; accM[ot][pi][3] = bvm[ot][3];
            }

        const int sx_px = tid & 127;
        const int sx_kh = (tid >> 7) * 16;
        const float* Xp = X + q0 + sx_px;

        for (int k0 = 0; k0 < 128; k0 += 32) {
            {
                float xv[16];
                #pragma unroll
                for (int i = 0; i < 16; ++i)
                    xv[i] = Xp[(size_t)(k0 + sx_kh + i) * NPIX];
                #pragma unroll
                for (int j = 0; j < 2; ++j) {
                    short8v hv, lv;
                    #pragma unroll
                    for (int i = 0; i < 8; ++i) {
                        unsigned short h = bfhi(xv[j * 8 + i]);
                        hv[i] = (short)h;
                        lv[i] = (short)bfhi(xv[j * 8 + i] - bff(h));
                    }
                    int gg = (sx_kh >> 3) + j;
                    int gs = gg ^ ((sx_px >> 3) & 3);
                    *(short8v*)(Xthi + sx_px * 40 + gs * 8) = hv;
                    *(short8v*)(Xtlo + sx_px * 40 + gs * 8) = lv;
                }
            }
            {
                int o = tid >> 3, kc = (tid & 7) * 4;
                float4 v = *(const float4*)(Wm1 + o * 128 + k0 + kc);
                float wv[4] = {v.x, v.y, v.z, v.w};
                short4v hv, lv;
                #pragma unroll
                for (int i = 0; i < 4; ++i) {
                    unsigned short h = bfhi(wv[i]);
                    hv[i] = (short)h;
                    lv[i] = (short)bfhi(wv[i] - bff(h));
                }
                int gg = kc >> 3;
                int gs = gg ^ (o & 3);
                int addr = o * 40 + gs * 8 + (kc & 7);
                *(short4v*)(Wmhi + addr) = hv;
                *(short4v*)(Wmlo + addr) = lv;
            }
            __syncthreads();

            short8v ahi[2], alo[2];
            #pragma unroll
            for (int ot = 0; ot < 2; ++ot) {
                int row = ot * 16 + c;
                int ao = row * 40 + (g ^ (row & 3)) * 8;
                ahi[ot] = *(const short8v*)(Wmhi + ao);
                alo[ot] = *(const short8v*)(Wmlo + ao);
            }
            #pragma unroll
            for (int pi = 0; pi < 2; ++pi) {
                int row = (2 * w + pi) * 16 + c;
                int bo = row * 40 + (g ^ ((row >> 3) & 3)) * 8;
                short8v bhi = *(const short8v*)(Xthi + bo);
                short8v blo = *(const short8v*)(Xtlo + bo);
                #pragma unroll
                for (int ot = 0; ot < 2; ++ot) {
                    accM[ot][pi] = __builtin_amdgcn_mfma_f32_16x16x32_bf16(
                        ahi[ot], bhi, accM[ot][pi], 0, 0, 0);
                    accM[ot][pi] = __builtin_amdgcn_mfma_f32_16x16x32_bf16(
                        ahi[ot], blo, accM[ot][pi], 0, 0, 0);
                    accM[ot][pi] = __builtin_amdgcn_mfma_f32_16x16x32_bf16(
                        alo[ot], bhi, accM[ot][pi], 0, 0, 0);
                }
            }
            __syncthreads();
        }
        #pragma unroll
        for (int pi = 0; pi < 2; ++pi) {
            int px = (2 * w + pi) * 16 + c;
            #pragma unroll
            for (int ot = 0; ot < 2; ++ot)
                #pragma unroll
                for (int r = 0; r < 4; ++r)
                    m1b[px][ot * 16 + g * 4 + r] = lrelu(accM[ot][pi][r]);
        }
        __syncthreads();
        if (tid < 128) {
            float m3 = bm3[0];
            #pragma unroll 2
            for (int j = 0; j < 16; ++j) {
                float s = bm2[j];
                #pragma unroll
                for (int k = 0; k < 32; ++k)
                    s = fmaf(Wm2[j * 32 + k], m1b[tid][k], s);
                m3 = fmaf(Wm3[j], lrelu(s), m3);
            }
            out[NPIX + q0 + tid] = lrelu(m3);
        }
        return;
    }

    // ---- y=0 / y=1: x_t (4-term) / r_t (3-term) via bf16 hi/lo MFMA ----
    {
        const bool exact = (blockIdx.y == 0);   // y0: add Wlo.Xlo term
        const float* __restrict__ Wsrc = exact ? Wcl1 : Wr1;
        const float* __restrict__ bsrc = exact ? bcl1 : br1;
        float* __restrict__ osrc       = exact ? x_t : r_t;

        unsigned short* Whi  = (unsigned short*)smem;            // [128][40]
        unsigned short* Wlo  = Whi  + 5120;                      // [128][40]
        unsigned short* Xthi = Wlo  + 5120;                      // [128px][40]
        unsigned short* Xtlo = Xthi + 5120;                      // [128px][40]

        const int l = tid & 63;
        const int w = tid >> 6;
        const int c = l & 15;
        const int g = l >> 4;
        const int o0 = w * 32;

        float bv[2][4];
        #pragma unroll
        for (int ot = 0; ot < 2; ++ot)
            #pragma unroll
            for (int r = 0; r < 4; ++r)
                bv[ot][r] = bsrc[o0 + ot * 16 + g * 4 + r];

        f32x4 acc[2][8];
        #pragma unroll
        for (int ot = 0; ot < 2; ++ot)
            #pragma unroll
            for (int pt = 0; pt < 8; ++pt) {
                acc[ot][pt][0] = bv[ot][0]; acc[ot][pt][1] = bv[ot][1];
                acc[ot][pt][2] = bv[ot][2]; acc[ot][pt][3] = bv[ot][3];
            }

        const int sx_px = tid & 127;
        const int sx_kh = (tid >> 7) * 16;
        const float* Xp = X + q0 + sx_px;

        for (int k0 = 0; k0 < 128; k0 += 32) {
            {
                float xv[16];
                #pragma unroll
                for (int i = 0; i < 16; ++i)
                    xv[i] = Xp[(size_t)(k0 + sx_kh + i) * NPIX];
                #pragma unroll
                for (int j = 0; j < 2; ++j) {
                    short8v hv, lv;
                    #pragma unroll
                    for (int i = 0; i < 8; ++i) {
                        unsigned short h = bfhi(xv[j * 8 + i]);
                        hv[i] = (short)h;
                        lv[i] = (short)bfhi(xv[j * 8 + i] - bff(h));
                    }
                    int gg = (sx_kh >> 3) + j;
                    int gs = gg ^ ((sx_px >> 3) & 3);
                    *(short8v*)(Xthi + sx_px * 40 + gs * 8) = hv;
                    *(short8v*)(Xtlo + sx_px * 40 + gs * 8) = lv;
                }
            }
            #pragma unroll
            for (int p = 0; p < 4; ++p) {
                int lin = p * 1024 + tid * 4;
                int o = lin >> 5, kc = lin & 31;
                float4 v = *(const float4*)(Wsrc + o * 128 + k0 + kc);
                float wv[4] = {v.x, v.y, v.z, v.w};
                short4v hv, lv;
                #pragma unroll
                for (int i = 0; i < 4; ++i) {
                    unsigned short h = bfhi(wv[i]);
                    hv[i] = (short)h;
                    lv[i] = (short)bfhi(wv[i] - bff(h));
                }
                int gg = kc >> 3;
                int gs = gg ^ (o & 3);
                int addr = o * 40 + gs * 8 + (kc & 7);
                *(short4v*)(Whi + addr) = hv;
                *(short4v*)(Wlo + addr) = lv;
            }
            __syncthreads();

            short8v ahi[2], alo[2];
            #pragma unroll
            for (int ot = 0; ot < 2; ++ot) {
                int row = o0 + ot * 16 + c;
                int ao = row * 40 + (g ^ (row & 3)) * 8;
                ahi[ot] = *(const short8v*)(Whi + ao);
                alo[ot] = *(const short8v*)(Wlo + ao);
            }
            #pragma unroll
            for (int pt = 0; pt < 8; ++pt) {
                int row = pt * 16 + c;
                int bo = row * 40 + (g ^ ((row >> 3) & 3)) * 8;
                short8v bhi = *(const short8v*)(Xthi + bo);
                short8v blo = *(const short8v*)(Xtlo + bo);
                #pragma unroll
                for (int ot = 0; ot < 2; ++ot) {
                    acc[ot][pt] = __builtin_amdgcn_mfma_f32_16x16x32_bf16(
                        ahi[ot], bhi, acc[ot][pt], 0, 0, 0);
                    acc[ot][pt] = __builtin_amdgcn_mfma_f32_16x16x32_bf16(
                        ahi[ot], blo, acc[ot][pt], 0, 0, 0);
                    acc[ot][pt] = __builtin_amdgcn_mfma_f32_16x16x32_bf16(
                        alo[ot], bhi, acc[ot][pt], 0, 0, 0);
                    if (exact)
                        acc[ot][pt] = __builtin_amdgcn_mfma_f32_16x16x32_bf16(
                            alo[ot], blo, acc[ot][pt], 0, 0, 0);
                }
            }
            __syncthreads();
        }

        #pragma unroll
        for (int pt = 0; pt < 8; ++pt) {
            int px = pt * 16 + c;
            int q  = q0 + px;
            int np = (q & 255) * 192 + (q >> 8);
            float* op = osrc + (size_t)np * 128;
            #pragma unroll
            for (int ot = 0; ot < 2; ++ot) {
                float4 o4;
                o4.x = lrelu(acc[ot][pt][0]); o4.y = lrelu(acc[ot][pt][1]);
                o4.z = lrelu(acc[ot][pt][2]); o4.w = lrelu(acc[ot][pt][3]);
                *(float4*)(op + o0 + ot * 16 + g * 4) = o4;
            }
        }
    }
}

// ============================================================================
// k1b (R16, part of the best config): 64-px tiles, grid 768 = 3 blocks/CU.
// ============================================================================
__global__ __launch_bounds__(256, 3) void k1b(
    const float* __restrict__ x_t,
    const float* __restrict__ Wcl21, const float* __restrict__ bcl21,
    const float* __restrict__ Wcl31, const float* __restrict__ bcl31,
    int* __restrict__ inds1_q)
{
    __shared__ float smem[8576];                        // 34304 B
    float (*As)[132]    = (float(*)[132])smem;          // [16][132] cols 0..63 used
    float (*Ws)[132]    = (float(*)[132])(smem + 2112); // [16][132]
    float (*W31)[132]   = (float(*)[132])smem;          // [32][132] aliases As+Ws
    float (*x2t)[68]    = (float(*)[68])(smem + 4224);  // [64][68]
    float (*cl1buf)[33] = (float(*)[33])(smem + 4224);  // [64][33] aliases x2t

    const int tid = threadIdx.x;
    const int n0  = blockIdx.x * 64;
    const int tcA = tid & 15, trA = tid >> 4;

    float acc[4][8];
    #pragma unroll
    for (int i = 0; i < 4; ++i)
        #pragma unroll
        for (int j = 0; j < 8; ++j)
            acc[i][j] = bcl21[(j >> 2) * 64 + trA * 4 + (j & 3)];

    for (int k0 = 0; k0 < 128; k0 += 16) {
        {
            int lin = tid * 4;
            int px = lin >> 4, kc = lin & 15;
            float4 v = *(const float4*)(x_t + (size_t)(n0 + px) * 128 + k0 + kc);
            As[kc + 0][px] = v.x; As[kc + 1][px] = v.y;
            As[kc + 2][px] = v.z; As[kc + 3][px] = v.w;
        }
        #pragma unroll
        for (int p = 0; p < 2; ++p) {
            int lin = p * 256 + tid;
            int r = lin >> 2, kc = (lin & 3) * 4;
            float4 v = *(const float4*)(Wcl21 + r * 128 + k0 + kc);
            Ws[kc + 0][r] = v.x; Ws[kc + 1][r] = v.y;
            Ws[kc + 2][r] = v.z; Ws[kc + 3][r] = v.w;
        }
        __syncthreads();
        #pragma unroll
        for (int kk = 0; kk < 16; ++kk) {
            float4 a  = *(const float4*)(&As[kk][tcA * 4]);
            float4 w0 = *(const float4*)(&Ws[kk][trA * 4]);
            float4 w1 = *(const float4*)(&Ws[kk][64 + trA * 4]);
            float av[4] = {a.x,a.y,a.z,a.w};
            float wv[8] = {w0.x,w0.y,w0.z,w0.w,w1.x,w1.y,w1.z,w1.w};
            #pragma unroll
            for (int i = 0; i < 4; ++i)
                #pragma unroll
                for (int j = 0; j < 8; ++j)
                    acc[i][j] = fmaf(av[i], wv[j], acc[i][j]);
        }
        __syncthreads();
    }

    const int tcB = tid & 15;
    const int trB = tid >> 4;
    float accB[4][2];
    #pragma unroll
    for (int i = 0; i < 4; ++i)
        #pragma unroll
        for (int j = 0; j < 2; ++j)
            accB[i][j] = bcl31[trB * 2 + j];

    #pragma unroll
    for (int p = 0; p < 4; ++p) {
        int lin = p * 1024 + tid * 4;
        int row = lin >> 7, kc = lin & 127;
        *(float4*)(&W31[row][kc]) = *(const float4*)(Wcl31 + row * 128 + kc);
    }
    #pragma unroll
    for (int j = 0; j < 4; ++j) {
        float4 o;
        o.x = lrelu(acc[0][j]); o.y = lrelu(acc[1][j]);
        o.z = lrelu(acc[2][j]); o.w = lrelu(acc[3][j]);
        *(float4*)(&x2t[trA * 4 + j][tcA * 4]) = o;
    }
    __syncthreads();
    for (int k = 0; k < 64; ++k) {
        float4 a = *(const float4*)(&x2t[k][tcB * 4]);
        float av[4] = {a.x,a.y,a.z,a.w};
        float w0 = W31[trB * 2 + 0][k];
        float w1 = W31[trB * 2 + 1][k];
        #pragma unroll
        for (int i = 0; i < 4; ++i) {
            accB[i][0] = fmaf(av[i], w0, accB[i][0]);
            accB[i][1] = fmaf(av[i], w1, accB[i][1]);
        }
    }
    __syncthreads();
    #pragma unroll
    for (int j = 0; j < 4; ++j) {
        float4 o;
        o.x = lrelu(acc[0][4+j]); o.y = lrelu(acc[1][4+j]);
        o.z = lrelu(acc[2][4+j]); o.w = lrelu(acc[3][4+j]);
        *(float4*)(&x2t[trA * 4 + j][tcA * 4]) = o;
    }
    __syncthreads();
    for (int k = 0; k < 64; ++k) {
        float4 a = *(const float4*)(&x2t[k][tcB * 4]);
        float av[4] = {a.x,a.y,a.z,a.w};
        float w0 = W31[trB * 2 + 0][64 + k];
        float w1 = W31[trB * 2 + 1][64 + k];
        #pragma unroll
        for (int i = 0; i < 4; ++i) {
            accB[i][0] = fmaf(av[i], w0, accB[i][0]);
            accB[i][1] = fmaf(av[i], w1, accB[i][1]);
        }
    }
    __syncthreads();

    #pragma unroll
    for (int i = 0; i < 4; ++i)
        #pragma unroll
        for (int j = 0; j < 2; ++j)
            cl1buf[tcB * 4 + i][trB * 2 + j] = accB[i][j];
    __syncthreads();
    if (tid < 64) {
        float bv = cl1buf[tid][0]; int bi = 0;
        #pragma unroll
        for (int c = 1; c < 32; ++c) {
            float v = cl1buf[tid][c];
            if (v > bv) { bv = v; bi = c; }
        }
        int n = n0 + tid;
        int w = n / 192, hh = n - w * 192;
        inds1_q[hh * 256 + w] = bi;
    }
}

// ============================================================================
// k_hist / k_scanA / k_scatter2 (R0 text)
// ============================================================================
__global__ void k_hist(const int* __restrict__ inds1_q, int* __restrict__ bh) {
    int tid = threadIdx.x;
    int n = blockIdx.x * 256 + tid;
    int key = inds1_q[n];
    int lane = tid & 63;
    int cnt = 0;
    for (int k = 0; k < 32; ++k) {
        unsigned long long m = __ballot(key == k);
        if (lane == k) cnt = __popcll(m);
    }
    if (lane < 32) bh[(n >> 6) * 32 + lane] = cnt;
}

__global__ void k_scanA(const int* __restrict__ bh, int* __restrict__ ebb,
                        int* __restrict__ total) {
    __shared__ int s[256];
    const int k = blockIdx.x, t = threadIdx.x;
    int v0 = bh[(t * 3 + 0) * 32 + k];
    int v1 = bh[(t * 3 + 1) * 32 + k];
    int v2 = bh[(t * 3 + 2) * 32 + k];
    int sum = v0 + v1 + v2;
    s[t] = sum; __syncthreads();
    for (int d = 1; d < 256; d <<= 1) {
        int x = (t >= d) ? s[t - d] : 0;
        __syncthreads();
        s[t] += x;
        __syncthreads();
    }
    int ex = s[t] - sum;
    ebb[(t * 3 + 0) * 32 + k] = ex;
    ebb[(t * 3 + 1) * 32 + k] = ex + v0;
    ebb[(t * 3 + 2) * 32 + k] = ex + v0 + v1;
    if (t == 255) total[k] = s[255];
}

__global__ void k_scatter2(const int* __restrict__ inds1_q,
                           const int* __restrict__ ebb,
                           const int* __restrict__ total,
                           int* __restrict__ order)
{
    __shared__ int ttot[32];
    const int tid = threadIdx.x;
    if (tid < 32) ttot[tid] = total[tid];
    __syncthreads();
    int n = blockIdx.x * 256 + tid;
    int key = inds1_q[n];
    int lane = tid & 63;
    unsigned long long peers = 0;
    for (int k = 0; k < 32; ++k) {
        unsigned long long m = __ballot(key == k);
        if (key == k) peers = m;
    }
    int rank = __popcll(peers & ((1ull << lane) - 1ull));
    int cbase = 0;
    #pragma unroll
    for (int k = 0; k < 32; ++k) cbase += (k < key) ? ttot[k] : 0;
    order[cbase + ebb[(n >> 6) * 32 + key] + rank] = n;
}

// ============================================================================
// k2h: stage-2 first half (R0 text — CLOSED: R15/R17/R18 all regressed)
// ============================================================================
__global__ __launch_bounds__(256, 4) void k2h(
    const float* __restrict__ x_t,
    const float* __restrict__ Wcl22, const float* __restrict__ bcl22,
    const float* __restrict__ Wcl32, const float* __restrict__ bcl32,
    const int* __restrict__ total, const int* __restrict__ order,
    int* __restrict__ ind_ord)
{
    __shared__ float Was[4096];
    __shared__ float Wbs[1024];
    __shared__ int cpre[33];
    __shared__ int cbase[33];
    __shared__ int ttot[32];

    const int tid = threadIdx.x;
    if (tid < 32) ttot[tid] = total[tid];
    __syncthreads();
    if (tid == 0) {
        int s = 0, cb = 0;
        for (int k = 0; k < 32; ++k) {
            cpre[k] = s; cbase[k] = cb;
            int c = ttot[k];
            s += (c + 255) >> 8;
            cb += c;
        }
        cpre[32] = s; cbase[32] = cb;
    }
    __syncthreads();
    const int ci = blockIdx.x;
    if (ci >= cpre[32]) return;
    int cls = 0;
    while (cpre[cls + 1] <= ci) ++cls;
    const int st   = (ci - cpre[cls]) * 256;
    const int npx  = min(256, ttot[cls] - st);
    const int base = cbase[cls] + st;

    {
        const float4* ws = (const float4*)(Wcl22 + cls * 4096);
        #pragma unroll
        for (int j = 0; j < 4; ++j) ((float4*)Was)[j * 256 + tid] = ws[j * 256 + tid];
        ((float4*)Wbs)[tid] = ((const float4*)(Wcl32 + cls * 1024))[tid];
    }
    __syncthreads();

    const int m = order[base + min(tid, npx - 1)];
    const float4* xp = (const float4*)(x_t + (size_t)m * 128);

    float h[32];
    #pragma unroll
    for (int j = 0; j < 32; ++j) h[j] = bcl22[cls * 32 + j];
    #pragma unroll 2
    for (int c4 = 0; c4 < 32; ++c4) {
        float4 xv = xp[c4];
        float xa[4] = {xv.x, xv.y, xv.z, xv.w};
        #pragma unroll
        for (int cc = 0; cc < 4; ++cc) {
            const float* wr = &Was[(c4 * 4 + cc) * 32];
            #pragma unroll
            for (int j = 0; j < 32; ++j) h[j] = fmaf(xa[cc], wr[j], h[j]);
        }
    }
    #pragma unroll
    for (int j = 0; j < 32; ++j) h[j] = lrelu(h[j]);

    float g[32];
    #pragma unroll
    for (int j = 0; j < 32; ++j) g[j] = bcl32[cls * 32 + j];
    #pragma unroll 2
    for (int c = 0; c < 32; ++c) {
        float hv = h[c];
        const float* wr = &Wbs[c * 32];
        #pragma unroll
        for (int j = 0; j < 32; ++j) g[j] = fmaf(hv, wr[j], g[j]);
    }
    float bv = g[0]; int bi = 0;
    #pragma unroll
    for (int j = 1; j < 32; ++j)
        if (g[j] > bv) { bv = g[j]; bi = j; }     // strict > = first-max (np.argmax)
    if (tid < npx) ind_ord[base + tid] = cls * 32 + bi;
}

// ============================================================================
// k2r: stage-2 second half (R0 text)
// ============================================================================
__global__ __launch_bounds__(256, 4) void k2r(
    const float* __restrict__ r_t,
    const float* __restrict__ Wr2,  const float* __restrict__ br2,
    const float* __restrict__ Wr3,  const float* __restrict__ br3,
    const int* __restrict__ total, const int* __restrict__ order,
    const int* __restrict__ ind_ord,
    float* __restrict__ out)
{
    __shared__ float Wcs[4096];
    __shared__ int cpre[33];
    __shared__ int cbase[33];
    __shared__ int ttot[32];

    const int tid = threadIdx.x;
    if (tid < 32) ttot[tid] = total[tid];
    __syncthreads();
    if (tid == 0) {
        int s = 0, cb = 0;
        for (int k = 0; k < 32; ++k) {
            cpre[k] = s; cbase[k] = cb;
            int c = ttot[k];
            s += (c + 255) >> 8;
            cb += c;
        }
        cpre[32] = s; cbase[32] = cb;
    }
    __syncthreads();
    const int ci = blockIdx.x;
    if (ci >= cpre[32]) return;
    int cls = 0;
    while (cpre[cls + 1] <= ci) ++cls;
    const int st   = (ci - cpre[cls]) * 256;
    const int npx  = min(256, ttot[cls] - st);
    const int base = cbase[cls] + st;
    const int sup  = cls >> 2;

    {
        const float4* ws = (const float4*)(Wr2 + sup * 4096);
        #pragma unroll
        for (int j = 0; j < 4; ++j) ((float4*)Wcs)[j * 256 + tid] = ws[j * 256 + tid];
    }
    __syncthreads();

    const int li  = min(tid, npx - 1);
    const int m   = order[base + li];
    const int ind = ind_ord[base + li];
    const float4* rp = (const float4*)(r_t + (size_t)m * 128);

    float r2[32];
    #pragma unroll
    for (int j = 0; j < 32; ++j) r2[j] = br2[sup * 32 + j];
    #pragma unroll 2
    for (int c4 = 0; c4 < 32; ++c4) {
        float4 rv = rp[c4];
        float ra[4] = {rv.x, rv.y, rv.z, rv.w};
        #pragma unroll
        for (int cc = 0; cc < 4; ++cc) {
            const float* wr = &Wcs[(c4 * 4 + cc) * 32];
            #pragma unroll
            for (int j = 0; j < 32; ++j) r2[j] = fmaf(ra[cc], wr[j], r2[j]);
        }
    }

    float reg = br3[ind];
    const float* __restrict__ w3 = Wr3 + ind * 32;
    #pragma unroll
    for (int j = 0; j < 32; ++j) reg = fmaf(lrelu(r2[j]), w3[j], reg);

    if (tid < npx) out[m] = ((float)ind + reg) * (1.0f / 1024.0f);
}

extern "C" void kernel_launch(void* const* d_in, const int* in_sizes, int n_in,
                              void* d_out, int out_size, void* d_ws, size_t ws_size,
                              hipStream_t stream)
{
    const float* X     = (const float*)d_in[0];
    const float* Wm1   = (const float*)d_in[1];
    const float* bm1   = (const float*)d_in[2];
    const float* Wm2   = (const float*)d_in[3];
    const float* bm2   = (const float*)d_in[4];
    const float* Wm3   = (const float*)d_in[5];
    const float* bm3   = (const float*)d_in[6];
    const float* Wcl1  = (const float*)d_in[7];
    const float* bcl1  = (const float*)d_in[8];
    const float* Wcl21 = (const float*)d_in[9];
    const float* bcl21 = (const float*)d_in[10];
    const float* Wcl31 = (const float*)d_in[11];
    const float* bcl31 = (const float*)d_in[12];
    const float* Wcl22 = (const float*)d_in[13];
    const float* bcl22 = (const float*)d_in[14];
    const float* Wcl32 = (const float*)d_in[15];
    const float* bcl32 = (const float*)d_in[16];
    const float* Wr1   = (const float*)d_in[17];
    const float* br1   = (const float*)d_in[18];
    const float* Wr2   = (const float*)d_in[19];
    const float* br2   = (const float*)d_in[20];
    const float* Wr3   = (const float*)d_in[21];
    const float* br3   = (const float*)d_in[22];
    float* out = (float*)d_out;

    float* x_t   = (float*)d_ws;
    float* r_t   = x_t + (size_t)NPIX * 128;
    int* inds1_q = (int*)(r_t + (size_t)NPIX * 128);
    int* order   = inds1_q + NPIX;
    int* ind_ord = order + NPIX;
    int* bh      = ind_ord + NPIX;      // [768][32]
    int* ebb     = bh + NSEG * 32;      // [768][32]
    int* total   = ebb + NSEG * 32;     // [32]

    k_fused1<<<dim3(NPIX / 128, 3), 256, 0, stream>>>(X, Wcl1, bcl1, Wr1, br1,
                                                      Wm1, bm1, Wm2, bm2, Wm3, bm3,
                                                      x_t, r_t, out);
    k1b<<<NPIX / 64, 256, 0, stream>>>(x_t, Wcl21, bcl21, Wcl31, bcl31, inds1_q);
    k_hist<<<NPIX / 256, 256, 0, stream>>>(inds1_q, bh);
    k_scanA<<<32, 256, 0, stream>>>(bh, ebb, total);
    k_scatter2<<<NPIX / 256, 256, 0, stream>>>(inds1_q, ebb, total, order);
    // 256-px chunks: worst case sum ceil = 192 + 31 = 223 -> grid 224 covers all
    k2h<<<224, 256, 0, stream>>>(x_t, Wcl22, bcl22, Wcl32, bcl32, total, order, ind_ord);
    k2r<<<224, 256, 0, stream>>>(r_t, Wr2, br2, Wr3, br3, total, order, ind_ord, out);
}

// Round 19
// 199.700 us; speedup vs baseline: 1.8211x; 1.0777x over previous
//
#include <hip/hip_runtime.h>

#define HH 192
#define WW 256
#define NPIX (HH*WW)   // 49152
#define NSEG (NPIX/64) // 768

__device__ __forceinline__ float lrelu(float v) { return v > 0.0f ? v : 0.01f * v; }

// bf16 hi/lo split helpers (RNE via round-half-up on guard bit)
__device__ __forceinline__ unsigned short bfhi(float x) {
    unsigned b = __float_as_uint(x);
    return (unsigned short)((b + 0x7FFFu + ((b >> 16) & 1u)) >> 16);
}
__device__ __forceinline__ float bff(unsigned short u) {
    return __uint_as_float(((unsigned)u) << 16);
}

typedef __attribute__((ext_vector_type(8))) short short8v;  // 8 bf16 = 4 VGPR
typedef __attribute__((ext_vector_type(4))) short short4v;  // 8B packed write
typedef __attribute__((ext_vector_type(4))) float f32x4;    // MFMA acc

// ============================================================================
// k_fused1 (R24 text, verified 215.2us best): all branches bf16 hi/lo MFMA.
// y=1 3-term; y=2 3-term; y=0 4-term. absmax 2.44e-4 (mask-path dominated).
// ============================================================================
__global__ __launch_bounds__(256, 3) void k_fused1(
    const float* __restrict__ X,
    const float* __restrict__ Wcl1, const float* __restrict__ bcl1,
    const float* __restrict__ Wr1,  const float* __restrict__ br1,
    const float* __restrict__ Wm1,  const float* __restrict__ bm1,
    const float* __restrict__ Wm2,  const float* __restrict__ bm2,
    const float* __restrict__ Wm3,  const float* __restrict__ bm3,
    float* __restrict__ x_t, float* __restrict__ r_t,
    float* __restrict__ out)
{
    __shared__ float smem[10240];                      // 40960 B

    const int tid = threadIdx.x;
    const int q0  = blockIdx.x * 128;

    if (blockIdx.y == 2) {
        unsigned short* Wmhi = (unsigned short*)smem;          // [32][40]
        unsigned short* Wmlo = Wmhi + 1280;                    // [32][40]
        unsigned short* Xthi = Wmlo + 1280;                    // [128][40]
        unsigned short* Xtlo = Xthi + 5120;                    // [128][40]
        float (*m1b)[33] = (float(*)[33])smem;                 // post-loop alias

        const int l = tid & 63;
        const int w = tid >> 6;
        const int c = l & 15;
        const int g = l >> 4;

        float bvm[2][4];
        #pragma unroll
        for (int ot = 0; ot < 2; ++ot)
            #pragma unroll
            for (int r = 0; r < 4; ++r)
                bvm[ot][r] = bm1[ot * 16 + g * 4 + r];

        f32x4 accM[2][2];
        #pragma unroll
        for (int ot = 0; ot < 2; ++ot)
            #pragma unroll
            for (int pi = 0; pi < 2; ++pi) {
                accM[ot][pi][0] = bvm[ot][0]; accM[ot][pi][1] = bvm[ot][1];
                accM[ot][pi][2] = bvm[ot][2]; accM[ot][pi][3] = bvm[ot][3];
            }

        const int sx_px = tid & 127;
        const int sx_kh = (tid >> 7) * 16;
        const float* Xp = X + q0 + sx_px;

        for (int k0 = 0; k0 < 128; k0 += 32) {
            {
                float xv[16];
                #pragma unroll
                for (int i = 0; i < 16; ++i)
                    xv[i] = Xp[(size_t)(k0 + sx_kh + i) * NPIX];
                #pragma unroll
                for (int j = 0; j < 2; ++j) {
                    short8v hv, lv;
                    #pragma unroll
                    for (int i = 0; i < 8; ++i) {
                        unsigned short h = bfhi(xv[j * 8 + i]);
                        hv[i] = (short)h;
                        lv[i] = (short)bfhi(xv[j * 8 + i] - bff(h));
                    }
                    int gg = (sx_kh >> 3) + j;
                    int gs = gg ^ ((sx_px >> 3) & 3);
                    *(short8v*)(Xthi + sx_px * 40 + gs * 8) = hv;
                    *(short8v*)(Xtlo + sx_px * 40 + gs * 8) = lv;
                }
            }
            {
                int o = tid >> 3, kc = (tid & 7) * 4;
                float4 v = *(const float4*)(Wm1 + o * 128 + k0 + kc);
                float wv[4] = {v.x, v.y, v.z, v.w};
                short4v hv, lv;
                #pragma unroll
                for (int i = 0; i < 4; ++i) {
                    unsigned short h = bfhi(wv[i]);
                    hv[i] = (short)h;
                    lv[i] = (short)bfhi(wv[i] - bff(h));
                }
                int gg = kc >> 3;
                int gs = gg ^ (o & 3);
                int addr = o * 40 + gs * 8 + (kc & 7);
                *(short4v*)(Wmhi + addr) = hv;
                *(short4v*)(Wmlo + addr) = lv;
            }
            __syncthreads();

            short8v ahi[2], alo[2];
            #pragma unroll
            for (int ot = 0; ot < 2; ++ot) {
                int row = ot * 16 + c;
                int ao = row * 40 + (g ^ (row & 3)) * 8;
                ahi[ot] = *(const short8v*)(Wmhi + ao);
                alo[ot] = *(const short8v*)(Wmlo + ao);
            }
            #pragma unroll
            for (int pi = 0; pi < 2; ++pi) {
                int row = (2 * w + pi) * 16 + c;
                int bo = row * 40 + (g ^ ((row >> 3) & 3)) * 8;
                short8v bhi = *(const short8v*)(Xthi + bo);
                short8v blo = *(const short8v*)(Xtlo + bo);
                #pragma unroll
                for (int ot = 0; ot < 2; ++ot) {
                    accM[ot][pi] = __builtin_amdgcn_mfma_f32_16x16x32_bf16(
                        ahi[ot], bhi, accM[ot][pi], 0, 0, 0);
                    accM[ot][pi] = __builtin_amdgcn_mfma_f32_16x16x32_bf16(
                        ahi[ot], blo, accM[ot][pi], 0, 0, 0);
                    accM[ot][pi] = __builtin_amdgcn_mfma_f32_16x16x32_bf16(
                        alo[ot], bhi, accM[ot][pi], 0, 0, 0);
                }
            }
            __syncthreads();
        }
        #pragma unroll
        for (int pi = 0; pi < 2; ++pi) {
            int px = (2 * w + pi) * 16 + c;
            #pragma unroll
            for (int ot = 0; ot < 2; ++ot)
                #pragma unroll
                for (int r = 0; r < 4; ++r)
                    m1b[px][ot * 16 + g * 4 + r] = lrelu(accM[ot][pi][r]);
        }
        __syncthreads();
        if (tid < 128) {
            float m3 = bm3[0];
            #pragma unroll 2
            for (int j = 0; j < 16; ++j) {
                float s = bm2[j];
                #pragma unroll
                for (int k = 0; k < 32; ++k)
                    s = fmaf(Wm2[j * 32 + k], m1b[tid][k], s);
                m3 = fmaf(Wm3[j], lrelu(s), m3);
            }
            out[NPIX + q0 + tid] = lrelu(m3);
        }
        return;
    }

    // ---- y=0 / y=1: x_t (4-term) / r_t (3-term) via bf16 hi/lo MFMA ----
    {
        const bool exact = (blockIdx.y == 0);   // y0: add Wlo.Xlo term
        const float* __restrict__ Wsrc = exact ? Wcl1 : Wr1;
        const float* __restrict__ bsrc = exact ? bcl1 : br1;
        float* __restrict__ osrc       = exact ? x_t : r_t;

        unsigned short* Whi  = (unsigned short*)smem;            // [128][40]
        unsigned short* Wlo  = Whi  + 5120;                      // [128][40]
        unsigned short* Xthi = Wlo  + 5120;                      // [128px][40]
        unsigned short* Xtlo = Xthi + 5120;                      // [128px][40]

        const int l = tid & 63;
        const int w = tid >> 6;
        const int c = l & 15;
        const int g = l >> 4;
        const int o0 = w * 32;

        float bv[2][4];
        #pragma unroll
        for (int ot = 0; ot < 2; ++ot)
            #pragma unroll
            for (int r = 0; r < 4; ++r)
                bv[ot][r] = bsrc[o0 + ot * 16 + g * 4 + r];

        f32x4 acc[2][8];
        #pragma unroll
        for (int ot = 0; ot < 2; ++ot)
            #pragma unroll
            for (int pt = 0; pt < 8; ++pt) {
                acc[ot][pt][0] = bv[ot][0]; acc[ot][pt][1] = bv[ot][1];
                acc[ot][pt][2] = bv[ot][2]; acc[ot][pt][3] = bv[ot][3];
            }

        const int sx_px = tid & 127;
        const int sx_kh = (tid >> 7) * 16;
        const float* Xp = X + q0 + sx_px;

        for (int k0 = 0; k0 < 128; k0 += 32) {
            {
                float xv[16];
                #pragma unroll
                for (int i = 0; i < 16; ++i)
                    xv[i] = Xp[(size_t)(k0 + sx_kh + i) * NPIX];
                #pragma unroll
                for (int j = 0; j < 2; ++j) {
                    short8v hv, lv;
                    #pragma unroll
                    for (int i = 0; i < 8; ++i) {
                        unsigned short h = bfhi(xv[j * 8 + i]);
                        hv[i] = (short)h;
                        lv[i] = (short)bfhi(xv[j * 8 + i] - bff(h));
                    }
                    int gg = (sx_kh >> 3) + j;
                    int gs = gg ^ ((sx_px >> 3) & 3);
                    *(short8v*)(Xthi + sx_px * 40 + gs * 8) = hv;
                    *(short8v*)(Xtlo + sx_px * 40 + gs * 8) = lv;
                }
            }
            #pragma unroll
            for (int p = 0; p < 4; ++p) {
                int lin = p * 1024 + tid * 4;
                int o = lin >> 5, kc = lin & 31;
                float4 v = *(const float4*)(Wsrc + o * 128 + k0 + kc);
                float wv[4] = {v.x, v.y, v.z, v.w};
                short4v hv, lv;
                #pragma unroll
                for (int i = 0; i < 4; ++i) {
                    unsigned short h = bfhi(wv[i]);
                    hv[i] = (short)h;
                    lv[i] = (short)bfhi(wv[i] - bff(h));
                }
                int gg = kc >> 3;
                int gs = gg ^ (o & 3);
                int addr = o * 40 + gs * 8 + (kc & 7);
                *(short4v*)(Whi + addr) = hv;
                *(short4v*)(Wlo + addr) = lv;
            }
            __syncthreads();

            short8v ahi[2], alo[2];
            #pragma unroll
            for (int ot = 0; ot < 2; ++ot) {
                int row = o0 + ot * 16 + c;
                int ao = row * 40 + (g ^ (row & 3)) * 8;
                ahi[ot] = *(const short8v*)(Whi + ao);
                alo[ot] = *(const short8v*)(Wlo + ao);
            }
            #pragma unroll
            for (int pt = 0; pt < 8; ++pt) {
                int row = pt * 16 + c;
                int bo = row * 40 + (g ^ ((row >> 3) & 3)) * 8;
                short8v bhi = *(const short8v*)(Xthi + bo);
                short8v blo = *(const short8v*)(Xtlo + bo);
                #pragma unroll
                for (int ot = 0; ot < 2; ++ot) {
                    acc[ot][pt] = __builtin_amdgcn_mfma_f32_16x16x32_bf16(
                        ahi[ot], bhi, acc[ot][pt], 0, 0, 0);
                    acc[ot][pt] = __builtin_amdgcn_mfma_f32_16x16x32_bf16(
                        ahi[ot], blo, acc[ot][pt], 0, 0, 0);
                    acc[ot][pt] = __builtin_amdgcn_mfma_f32_16x16x32_bf16(
                        alo[ot], bhi, acc[ot][pt], 0, 0, 0);
                    if (exact)
                        acc[ot][pt] = __builtin_amdgcn_mfma_f32_16x16x32_bf16(
                            alo[ot], blo, acc[ot][pt], 0, 0, 0);
                }
            }
            __syncthreads();
        }

        #pragma unroll
        for (int pt = 0; pt < 8; ++pt) {
            int px = pt * 16 + c;
            int q  = q0 + px;
            int np = (q & 255) * 192 + (q >> 8);
            float* op = osrc + (size_t)np * 128;
            #pragma unroll
            for (int ot = 0; ot < 2; ++ot) {
                float4 o4;
                o4.x = lrelu(acc[ot][pt][0]); o4.y = lrelu(acc[ot][pt][1]);
                o4.z = lrelu(acc[ot][pt][2]); o4.w = lrelu(acc[ot][pt][3]);
                *(float4*)(op + o0 + ot * 16 + g * 4) = o4;
            }
        }
    }
}

// ============================================================================
// k1b (R25): main GEMM (x2 = lrelu(Wcl21@x)) converted to 4-TERM bf16 hi/lo
// MFMA (same verified staging/swizzles as k_fused1 y0/y1, PX=64). B-phase
// (cl1 = Wcl31@x2 + argmax) stays fp32, single 128-channel pass through
// x2t[128][68]. LDS 51712B -> still 3 blocks/CU. Precision: x2's path to
// argmax (one fp32 GEMM) is SHORTER than x_t's (R24-verified, absmax
// unchanged). Pre-registered failure: absmax >= 0.03 -> revert to R16 k1b.
// ============================================================================
__global__ __launch_bounds__(256, 3) void k1b(
    const float* __restrict__ x_t,
    const float* __restrict__ Wcl21, const float* __restrict__ bcl21,
    const float* __restrict__ Wcl31, const float* __restrict__ bcl31,
    int* __restrict__ inds1_q)
{
    __shared__ float smem[12928];                       // 51712 B
    // GEMM-phase tiles (alias x2t region; dead before x2t writes):
    unsigned short* Whi  = (unsigned short*)smem;       // [128][40]
    unsigned short* Wlo  = Whi + 5120;                  // [128][40]
    unsigned short* Xthi = Wlo + 5120;                  // [64][40]
    unsigned short* Xtlo = Xthi + 2560;                 // [64][40]  (30720 B total)
    // post-GEMM:
    float (*x2t)[68]    = (float(*)[68])smem;           // [128][68] = 34816 B
    float (*W31)[132]   = (float(*)[132])(smem + 8704); // [32][132] = 16896 B
    float (*cl1buf)[33] = (float(*)[33])(smem + 8704);  // aliases W31 post B-phase

    const int tid = threadIdx.x;
    const int n0  = blockIdx.x * 64;
    const int l = tid & 63, w = tid >> 6;
    const int c = l & 15, g = l >> 4;
    const int o0 = w * 32;

    // ---- GEMM: x2 = lrelu(Wcl21 @ x), 64 px x 128 out, 4-term MFMA ----
    float bv[2][4];
    #pragma unroll
    for (int ot = 0; ot < 2; ++ot)
        #pragma unroll
        for (int r = 0; r < 4; ++r)
            bv[ot][r] = bcl21[o0 + ot * 16 + g * 4 + r];

    f32x4 acc[2][4];
    #pragma unroll
    for (int ot = 0; ot < 2; ++ot)
        #pragma unroll
        for (int pt = 0; pt < 4; ++pt) {
            acc[ot][pt][0] = bv[ot][0]; acc[ot][pt][1] = bv[ot][1];
            acc[ot][pt][2] = bv[ot][2]; acc[ot][pt][3] = bv[ot][3];
        }

    const int sx_px = tid & 63;             // pixel row
    const int sx_kh = (tid >> 6) * 8;       // 8-k group: 0,8,16,24
    const float* Xp = x_t + (size_t)(n0 + sx_px) * 128 + sx_kh;

    for (int k0 = 0; k0 < 128; k0 += 32) {
        // stage X tile: 1 px x 8 consecutive k per thread (2 coalesced float4)
        {
            float4 v0 = *(const float4*)(Xp + k0);
            float4 v1 = *(const float4*)(Xp + k0 + 4);
            float xv[8] = {v0.x,v0.y,v0.z,v0.w,v1.x,v1.y,v1.z,v1.w};
            short8v hv, lv;
            #pragma unroll
            for (int i = 0; i < 8; ++i) {
                unsigned short h = bfhi(xv[i]);
                hv[i] = (short)h;
                lv[i] = (short)bfhi(xv[i] - bff(h));
            }
            int gg = sx_kh >> 3;                    // k-group 0..3
            int gs = gg ^ ((sx_px >> 3) & 3);       // verified swizzle
            *(short8v*)(Xthi + sx_px * 40 + gs * 8) = hv;
            *(short8v*)(Xtlo + sx_px * 40 + gs * 8) = lv;
        }
        // stage Wcl21 tile: verbatim verified pattern
        #pragma unroll
        for (int p = 0; p < 4; ++p) {
            int lin = p * 1024 + tid * 4;
            int o = lin >> 5, kc = lin & 31;
            float4 v = *(const float4*)(Wcl21 + o * 128 + k0 + kc);
            float wv[4] = {v.x, v.y, v.z, v.w};
            short4v hv, lv;
            #pragma unroll
            for (int i = 0; i < 4; ++i) {
                unsigned short h = bfhi(wv[i]);
                hv[i] = (short)h;
                lv[i] = (short)bfhi(wv[i] - bff(h));
            }
            int gg = kc >> 3;
            int gs = gg ^ (o & 3);
            int addr = o * 40 + gs * 8 + (kc & 7);
            *(short4v*)(Whi + addr) = hv;
            *(short4v*)(Wlo + addr) = lv;
        }
        __syncthreads();

        short8v ahi[2], alo[2];
        #pragma unroll
        for (int ot = 0; ot < 2; ++ot) {
            int row = o0 + ot * 16 + c;
            int ao = row * 40 + (g ^ (row & 3)) * 8;
            ahi[ot] = *(const short8v*)(Whi + ao);
            alo[ot] = *(const short8v*)(Wlo + ao);
        }
        #pragma unroll
        for (int pt = 0; pt < 4; ++pt) {
            int row = pt * 16 + c;
            int bo = row * 40 + (g ^ ((row >> 3) & 3)) * 8;
            short8v bhi = *(const short8v*)(Xthi + bo);
            short8v blo = *(const short8v*)(Xtlo + bo);
            #pragma unroll
            for (int ot = 0; ot < 2; ++ot) {
                acc[ot][pt] = __builtin_amdgcn_mfma_f32_16x16x32_bf16(
                    ahi[ot], bhi, acc[ot][pt], 0, 0, 0);
                acc[ot][pt] = __builtin_amdgcn_mfma_f32_16x16x32_bf16(
                    ahi[ot], blo, acc[ot][pt], 0, 0, 0);
                acc[ot][pt] = __builtin_amdgcn_mfma_f32_16x16x32_bf16(
                    alo[ot], bhi, acc[ot][pt], 0, 0, 0);
                acc[ot][pt] = __builtin_amdgcn_mfma_f32_16x16x32_bf16(
                    alo[ot], blo, acc[ot][pt], 0, 0, 0);
            }
        }
        __syncthreads();
    }

    // write x2 fragments (lrelu) -> x2t[ch][px]; stage W31 (disjoint region)
    #pragma unroll
    for (int pt = 0; pt < 4; ++pt) {
        int px = pt * 16 + c;
        #pragma unroll
        for (int ot = 0; ot < 2; ++ot)
            #pragma unroll
            for (int r = 0; r < 4; ++r)
                x2t[o0 + ot * 16 + g * 4 + r][px] = lrelu(acc[ot][pt][r]);
    }
    #pragma unroll
    for (int p = 0; p < 4; ++p) {
        int lin = p * 1024 + tid * 4;
        int row = lin >> 7, kc = lin & 127;
        *(float4*)(&W31[row][kc]) = *(const float4*)(Wcl31 + row * 128 + kc);
    }
    __syncthreads();

    // ---- B-phase: cl1 = Wcl31 @ x2 (+argmax), single 128-channel pass ----
    const int tcB = tid & 15;
    const int trB = tid >> 4;
    float accB[4][2];
    #pragma unroll
    for (int i = 0; i < 4; ++i)
        #pragma unroll
        for (int j = 0; j < 2; ++j)
            accB[i][j] = bcl31[trB * 2 + j];

    for (int k = 0; k < 128; ++k) {
        float4 a = *(const float4*)(&x2t[k][tcB * 4]);
        float av[4] = {a.x,a.y,a.z,a.w};
        float w0 = W31[trB * 2 + 0][k];
        float w1 = W31[trB * 2 + 1][k];
        #pragma unroll
        for (int i = 0; i < 4; ++i) {
            accB[i][0] = fmaf(av[i], w0, accB[i][0]);
            accB[i][1] = fmaf(av[i], w1, accB[i][1]);
        }
    }
    __syncthreads();

    #pragma unroll
    for (int i = 0; i < 4; ++i)
        #pragma unroll
        for (int j = 0; j < 2; ++j)
            cl1buf[tcB * 4 + i][trB * 2 + j] = accB[i][j];
    __syncthreads();
    if (tid < 64) {
        float bvv = cl1buf[tid][0]; int bi = 0;
        #pragma unroll
        for (int cc = 1; cc < 32; ++cc) {
            float v = cl1buf[tid][cc];
            if (v > bvv) { bvv = v; bi = cc; }
        }
        int n = n0 + tid;
        int ww = n / 192, hh = n - ww * 192;
        inds1_q[hh * 256 + ww] = bi;
    }
}

// ============================================================================
// k_hist / k_scanA / k_scatter2 (R0 text)
// ============================================================================
__global__ void k_hist(const int* __restrict__ inds1_q, int* __restrict__ bh) {
    int tid = threadIdx.x;
    int n = blockIdx.x * 256 + tid;
    int key = inds1_q[n];
    int lane = tid & 63;
    int cnt = 0;
    for (int k = 0; k < 32; ++k) {
        unsigned long long m = __ballot(key == k);
        if (lane == k) cnt = __popcll(m);
    }
    if (lane < 32) bh[(n >> 6) * 32 + lane] = cnt;
}

__global__ void k_scanA(const int* __restrict__ bh, int* __restrict__ ebb,
                        int* __restrict__ total) {
    __shared__ int s[256];
    const int k = blockIdx.x, t = threadIdx.x;
    int v0 = bh[(t * 3 + 0) * 32 + k];
    int v1 = bh[(t * 3 + 1) * 32 + k];
    int v2 = bh[(t * 3 + 2) * 32 + k];
    int sum = v0 + v1 + v2;
    s[t] = sum; __syncthreads();
    for (int d = 1; d < 256; d <<= 1) {
        int x = (t >= d) ? s[t - d] : 0;
        __syncthreads();
        s[t] += x;
        __syncthreads();
    }
    int ex = s[t] - sum;
    ebb[(t * 3 + 0) * 32 + k] = ex;
    ebb[(t * 3 + 1) * 32 + k] = ex + v0;
    ebb[(t * 3 + 2) * 32 + k] = ex + v0 + v1;
    if (t == 255) total[k] = s[255];
}

__global__ void k_scatter2(const int* __restrict__ inds1_q,
                           const int* __restrict__ ebb,
                           const int* __restrict__ total,
                           int* __restrict__ order)
{
    __shared__ int ttot[32];
    const int tid = threadIdx.x;
    if (tid < 32) ttot[tid] = total[tid];
    __syncthreads();
    int n = blockIdx.x * 256 + tid;
    int key = inds1_q[n];
    int lane = tid & 63;
    unsigned long long peers = 0;
    for (int k = 0; k < 32; ++k) {
        unsigned long long m = __ballot(key == k);
        if (key == k) peers = m;
    }
    int rank = __popcll(peers & ((1ull << lane) - 1ull));
    int cbase = 0;
    #pragma unroll
    for (int k = 0; k < 32; ++k) cbase += (k < key) ? ttot[k] : 0;
    order[cbase + ebb[(n >> 6) * 32 + key] + rank] = n;
}

// ============================================================================
// k2h: stage-2 first half (R0 text — CLOSED: R15/R17/R18 all regressed)
// ============================================================================
__global__ __launch_bounds__(256, 4) void k2h(
    const float* __restrict__ x_t,
    const float* __restrict__ Wcl22, const float* __restrict__ bcl22,
    const float* __restrict__ Wcl32, const float* __restrict__ bcl32,
    const int* __restrict__ total, const int* __restrict__ order,
    int* __restrict__ ind_ord)
{
    __shared__ float Was[4096];
    __shared__ float Wbs[1024];
    __shared__ int cpre[33];
    __shared__ int cbase[33];
    __shared__ int ttot[32];

    const int tid = threadIdx.x;
    if (tid < 32) ttot[tid] = total[tid];
    __syncthreads();
    if (tid == 0) {
        int s = 0, cb = 0;
        for (int k = 0; k < 32; ++k) {
            cpre[k] = s; cbase[k] = cb;
            int c = ttot[k];
            s += (c + 255) >> 8;
            cb += c;
        }
        cpre[32] = s; cbase[32] = cb;
    }
    __syncthreads();
    const int ci = blockIdx.x;
    if (ci >= cpre[32]) return;
    int cls = 0;
    while (cpre[cls + 1] <= ci) ++cls;
    const int st   = (ci - cpre[cls]) * 256;
    const int npx  = min(256, ttot[cls] - st);
    const int base = cbase[cls] + st;

    {
        const float4* ws = (const float4*)(Wcl22 + cls * 4096);
        #pragma unroll
        for (int j = 0; j < 4; ++j) ((float4*)Was)[j * 256 + tid] = ws[j * 256 + tid];
        ((float4*)Wbs)[tid] = ((const float4*)(Wcl32 + cls * 1024))[tid];
    }
    __syncthreads();

    const int m = order[base + min(tid, npx - 1)];
    const float4* xp = (const float4*)(x_t + (size_t)m * 128);

    float h[32];
    #pragma unroll
    for (int j = 0; j < 32; ++j) h[j] = bcl22[cls * 32 + j];
    #pragma unroll 2
    for (int c4 = 0; c4 < 32; ++c4) {
        float4 xv = xp[c4];
        float xa[4] = {xv.x, xv.y, xv.z, xv.w};
        #pragma unroll
        for (int cc = 0; cc < 4; ++cc) {
            const float* wr = &Was[(c4 * 4 + cc) * 32];
            #pragma unroll
            for (int j = 0; j < 32; ++j) h[j] = fmaf(xa[cc], wr[j], h[j]);
        }
    }
    #pragma unroll
    for (int j = 0; j < 32; ++j) h[j] = lrelu(h[j]);

    float g[32];
    #pragma unroll
    for (int j = 0; j < 32; ++j) g[j] = bcl32[cls * 32 + j];
    #pragma unroll 2
    for (int c = 0; c < 32; ++c) {
        float hv = h[c];
        const float* wr = &Wbs[c * 32];
        #pragma unroll
        for (int j = 0; j < 32; ++j) g[j] = fmaf(hv, wr[j], g[j]);
    }
    float bv = g[0]; int bi = 0;
    #pragma unroll
    for (int j = 1; j < 32; ++j)
        if (g[j] > bv) { bv = g[j]; bi = j; }     // strict > = first-max (np.argmax)
    if (tid < npx) ind_ord[base + tid] = cls * 32 + bi;
}

// ============================================================================
// k2r: stage-2 second half (R0 text)
// ============================================================================
__global__ __launch_bounds__(256, 4) void k2r(
    const float* __restrict__ r_t,
    const float* __restrict__ Wr2,  const float* __restrict__ br2,
    const float* __restrict__ Wr3,  const float* __restrict__ br3,
    const int* __restrict__ total, const int* __restrict__ order,
    const int* __restrict__ ind_ord,
    float* __restrict__ out)
{
    __shared__ float Wcs[4096];
    __shared__ int cpre[33];
    __shared__ int cbase[33];
    __shared__ int ttot[32];

    const int tid = threadIdx.x;
    if (tid < 32) ttot[tid] = total[tid];
    __syncthreads();
    if (tid == 0) {
        int s = 0, cb = 0;
        for (int k = 0; k < 32; ++k) {
            cpre[k] = s; cbase[k] = cb;
            int c = ttot[k];
            s += (c + 255) >> 8;
            cb += c;
        }
        cpre[32] = s; cbase[32] = cb;
    }
    __syncthreads();
    const int ci = blockIdx.x;
    if (ci >= cpre[32]) return;
    int cls = 0;
    while (cpre[cls + 1] <= ci) ++cls;
    const int st   = (ci - cpre[cls]) * 256;
    const int npx  = min(256, ttot[cls] - st);
    const int base = cbase[cls] + st;
    const int sup  = cls >> 2;

    {
        const float4* ws = (const float4*)(Wr2 + sup * 4096);
        #pragma unroll
        for (int j = 0; j < 4; ++j) ((float4*)Wcs)[j * 256 + tid] = ws[j * 256 + tid];
    }
    __syncthreads();

    const int li  = min(tid, npx - 1);
    const int m   = order[base + li];
    const int ind = ind_ord[base + li];
    const float4* rp = (const float4*)(r_t + (size_t)m * 128);

    float r2[32];
    #pragma unroll
    for (int j = 0; j < 32; ++j) r2[j] = br2[sup * 32 + j];
    #pragma unroll 2
    for (int c4 = 0; c4 < 32; ++c4) {
        float4 rv = rp[c4];
        float ra[4] = {rv.x, rv.y, rv.z, rv.w};
        #pragma unroll
        for (int cc = 0; cc < 4; ++cc) {
            const float* wr = &Wcs[(c4 * 4 + cc) * 32];
            #pragma unroll
            for (int j = 0; j < 32; ++j) r2[j] = fmaf(ra[cc], wr[j], r2[j]);
        }
    }

    float reg = br3[ind];
    const float* __restrict__ w3 = Wr3 + ind * 32;
    #pragma unroll
    for (int j = 0; j < 32; ++j) reg = fmaf(lrelu(r2[j]), w3[j], reg);

    if (tid < npx) out[m] = ((float)ind + reg) * (1.0f / 1024.0f);
}

extern "C" void kernel_launch(void* const* d_in, const int* in_sizes, int n_in,
                              void* d_out, int out_size, void* d_ws, size_t ws_size,
                              hipStream_t stream)
{
    const float* X     = (const float*)d_in[0];
    const float* Wm1   = (const float*)d_in[1];
    const float* bm1   = (const float*)d_in[2];
    const float* Wm2   = (const float*)d_in[3];
    const float* bm2   = (const float*)d_in[4];
    const float* Wm3   = (const float*)d_in[5];
    const float* bm3   = (const float*)d_in[6];
    const float* Wcl1  = (const float*)d_in[7];
    const float* bcl1  = (const float*)d_in[8];
    const float* Wcl21 = (const float*)d_in[9];
    const float* bcl21 = (const float*)d_in[10];
    const float* Wcl31 = (const float*)d_in[11];
    const float* bcl31 = (const float*)d_in[12];
    const float* Wcl22 = (const float*)d_in[13];
    const float* bcl22 = (const float*)d_in[14];
    const float* Wcl32 = (const float*)d_in[15];
    const float* bcl32 = (const float*)d_in[16];
    const float* Wr1   = (const float*)d_in[17];
    const float* br1   = (const float*)d_in[18];
    const float* Wr2   = (const float*)d_in[19];
    const float* br2   = (const float*)d_in[20];
    const float* Wr3   = (const float*)d_in[21];
    const float* br3   = (const float*)d_in[22];
    float* out = (float*)d_out;

    float* x_t   = (float*)d_ws;
    float* r_t   = x_t + (size_t)NPIX * 128;
    int* inds1_q = (int*)(r_t + (size_t)NPIX * 128);
    int* order   = inds1_q + NPIX;
    int* ind_ord = order + NPIX;
    int* bh      = ind_ord + NPIX;      // [768][32]
    int* ebb     = bh + NSEG * 32;      // [768][32]
    int* total   = ebb + NSEG * 32;     // [32]

    k_fused1<<<dim3(NPIX / 128, 3), 256, 0, stream>>>(X, Wcl1, bcl1, Wr1, br1,
                                                      Wm1, bm1, Wm2, bm2, Wm3, bm3,
                                                      x_t, r_t, out);
    k1b<<<NPIX / 64, 256, 0, stream>>>(x_t, Wcl21, bcl21, Wcl31, bcl31, inds1_q);
    k_hist<<<NPIX / 256, 256, 0, stream>>>(inds1_q, bh);
    k_scanA<<<32, 256, 0, stream>>>(bh, ebb, total);
    k_scatter2<<<NPIX / 256, 256, 0, stream>>>(inds1_q, ebb, total, order);
    // 256-px chunks: worst case sum ceil = 192 + 31 = 223 -> grid 224 covers all
    k2h<<<224, 256, 0, stream>>>(x_t, Wcl22, bcl22, Wcl32, bcl32, total, order, ind_ord);
    k2r<<<224, 256, 0, stream>>>(r_t, Wr2, br2, Wr3, br3, total, order, ind_ord, out);
}